// Round 14
// baseline (1717.097 us; speedup 1.0000x reference)
//
#include <hip/hip_runtime.h>
#include <cstdio>
#include <type_traits>

#define NQ 10000
#define NT 50000
#define NA 50000
#define E_GR 50000
#define E_LT 50000
#define E_SIM 80000
#define E_COMP 100000
#define E_GEN 50000
#define MAXE 100000
#define NEG_SLOPE 0.2f

typedef unsigned short bf16_t;
typedef unsigned int u32;
typedef __attribute__((ext_vector_type(8))) short short8v;
typedef __attribute__((ext_vector_type(4))) float f32x4;

__device__ __forceinline__ float bf2f(u32 bits) { return __uint_as_float(bits << 16); }
__device__ __forceinline__ u32 f2bf(float f) {
  u32 u = __float_as_uint(f);
  return (u + 0x7FFFu + ((u >> 16) & 1u)) >> 16;   // RTNE
}
__device__ __forceinline__ u32 pack2(float a, float b) { return f2bf(a) | (f2bf(b) << 16); }
__device__ __forceinline__ void unpack8(uint4 u, float* f) {
  f[0] = bf2f(u.x & 0xffffu); f[1] = bf2f(u.x >> 16);
  f[2] = bf2f(u.y & 0xffffu); f[3] = bf2f(u.y >> 16);
  f[4] = bf2f(u.z & 0xffffu); f[5] = bf2f(u.z >> 16);
  f[6] = bf2f(u.w & 0xffffu); f[7] = bf2f(u.w >> 16);
}

// async global->LDS, 16B per lane; LDS dest = wave-uniform base + lane*16.
__device__ __forceinline__ void gload16(const void* g, void* l) {
  __builtin_amdgcn_global_load_lds(
      (const __attribute__((address_space(1))) void*)g,
      (__attribute__((address_space(3))) void*)l, 16, 0, 0);
}

// ---------------------------------------------------------------------------
// MFMA bf16 GEMM, z-paired. For z in {0,1}: C_z = A_z @ Bt_z^T (+bias|+=C).
// 128x256 tile, BK=32, 512 threads = 8 waves (2x4), wave tile 64x64,
// acc[4][4]. FOUR 24KB LDS buffers (96KB, 1 blk/CU), 2-DEEP prefetch,
// rotation s%4, ONE barrier per K-step:
//   stage buf[(s+2)%4] ; vmcnt(6) [two future stages stay in flight] ;
//   barrier ; ds_read buf[s%4] + 16 MFMA (setprio) ; (no trailing barrier)
// Latency: each buffer's loads get ~2 full steps of flight -> zero exposed
// HBM latency at BK=32 (the r12 dilemma resolved without losing short steps).
// Race proof (1 barrier/step): writes at step s -> buf[(s+2)%4]; pending
// reads belong to steps >= s-1 -> buf[(s-1)%4] or buf[s%4]; diffs 3,2 mod 4
// != 0. A laggard's reads are consumed (lgkm-waited by its MFMAs) before it
// arrives at barrier(s); a writer passes barrier(s),(s+1) first.
// vmcnt: steady 6 (=2 stages x 3 loads), tail 3 -> 0.
// Both-sides octet XOR (rule #21): store oct=(c&3)^((row>>1)&3) via
// pre-swizzled global k-octet; read oct=fg^((fr>>1)&3) -> exact 2-way bank
// aliasing (free, m136).
// XCD-grouped band swizzle per z; optional ridx A-row indirection.
// M%256==0, K%32==0; N guarded; early exit uniform (before any barrier).
// ---------------------------------------------------------------------------
template <typename CT>
__global__ __launch_bounds__(512, 1) void bgemm(
    const bf16_t* __restrict__ A0, const bf16_t* __restrict__ Bt0,
    const float* __restrict__ bias0, CT* __restrict__ C0,
    const int* __restrict__ ridx0, int N0,
    const bf16_t* __restrict__ A1, const bf16_t* __restrict__ Bt1,
    const float* __restrict__ bias1, CT* __restrict__ C1,
    const int* __restrict__ ridx1, int N1,
    int K, int M, int accumulate)
{
  __shared__ short lds[4][12288];   // [buf][A: 0..4095 | B: 4096..12287]
  const int z = blockIdx.z;
  const bf16_t* A   = z ? A1 : A0;
  const bf16_t* Bt  = z ? Bt1 : Bt0;
  const float* bias = z ? bias1 : bias0;
  CT* C             = z ? C1 : C0;
  const int* ridx   = z ? ridx1 : ridx0;
  const int N       = z ? N1 : N0;

  const int tid = threadIdx.x;
  const int ncol = gridDim.x;
  const int nband = (N + 127) >> 7;         // per-z band count
  int lin = blockIdx.y * ncol + blockIdx.x;
  if (lin >= ncol * nband) return;          // uniform exit, before barriers

  // XCD-grouping swizzle (wg->XCD = id%8). Bijective incl. tail bands.
  int band, col;
  const int full = (nband >> 3) * 8 * ncol;
  if (lin < full) {
    int g = lin >> 3, x = lin & 7;
    band = x + 8 * (g / ncol);
    col  = g % ncol;
  } else {
    int r = lin - full;
    band = (nband & ~7) + r / ncol;
    col  = r % ncol;
  }
  const int bm = band * 128, bn = col * 256;

  const int lane = tid & 63;
  const int w = tid >> 6;          // 8 waves
  const int wr = w >> 2, wc = w & 3;
  const int fr = lane & 15, fg = lane >> 4;

  // staging: A 512 chunks (1/thread), B 1024 chunks (2/thread).
  // chunk c: row=c>>2, oct=c&3; global k-octet pre-swizzled (rule #21).
  const int kg = (((tid & 3) ^ ((tid >> 3) & 3)) << 3);
  const int rr = tid >> 2;
  int ra = min(bm + rr, N - 1);
  const bf16_t* gA0 = A + (size_t)(ridx ? ridx[ra] : ra) * K + kg;
  const bf16_t* gB0 = Bt + (size_t)(bn + rr) * K + kg;
  const bf16_t* gB1 = Bt + (size_t)(bn + 128 + rr) * K + kg;
  const int wb = w << 9;   // wave-uniform LDS short offset (64 chunks * 8)

  f32x4 acc[4][4];
#pragma unroll
  for (int i = 0; i < 4; ++i)
#pragma unroll
    for (int j = 0; j < 4; ++j) acc[i][j] = (f32x4){0.f, 0.f, 0.f, 0.f};

  auto stage = [&](int buf, int k0) {
    short* base = &lds[buf][0];
    gload16(gA0 + k0, base + wb);                  // A chunk t
    gload16(gB0 + k0, base + 4096 + wb);           // B chunk t
    gload16(gB1 + k0, base + 8192 + wb);           // B chunk t+512
  };

  const int nsteps = K >> 5;
  stage(0, 0);
  if (nsteps > 1) stage(1, 32);
  const int co = (fg ^ ((fr >> 1) & 3)) << 3;   // read-side XOR octet
  for (int s = 0; s < nsteps; ++s) {
    const int cur = s & 3;
    if (s + 2 < nsteps) {
      stage((s + 2) & 3, (s + 2) << 5);
      asm volatile("s_waitcnt vmcnt(6)" ::: "memory");  // buf[cur] retired
    } else if (s + 1 < nsteps) {
      asm volatile("s_waitcnt vmcnt(3)" ::: "memory");
    } else {
      asm volatile("s_waitcnt vmcnt(0)" ::: "memory");
    }
    __builtin_amdgcn_s_barrier();            // publish buf[cur]
    asm volatile("" ::: "memory");
    const short* LA = &lds[cur][0];
    const short* LB = &lds[cur][4096];
    short8v b[4];
#pragma unroll
    for (int j = 0; j < 4; ++j) {
      int R = wc * 64 + j * 16 + fr;
      b[j] = *(const short8v*)&LB[R * 32 + co];
    }
    short8v a[4];
#pragma unroll
    for (int i = 0; i < 4; ++i) {
      int R = wr * 64 + i * 16 + fr;
      a[i] = *(const short8v*)&LA[R * 32 + co];
    }
    __builtin_amdgcn_s_setprio(1);
#pragma unroll
    for (int i = 0; i < 4; ++i)
#pragma unroll
      for (int j = 0; j < 4; ++j)
        acc[i][j] = __builtin_amdgcn_mfma_f32_16x16x32_bf16(b[j], a[i],
                                                            acc[i][j], 0, 0, 0);
    __builtin_amdgcn_s_setprio(0);
    asm volatile("" ::: "memory");
    // no trailing barrier: 4-buffer 2-deep rotation (see header)
  }

  // epilogue: D cols (fr) = A rows; D row quad (fg*4+q) = C cols.
  float4 bv[4];
#pragma unroll
  for (int j = 0; j < 4; ++j) {
    bv[j] = make_float4(0.f, 0.f, 0.f, 0.f);
    if (!accumulate && bias)
      bv[j] = *(const float4*)(bias + bn + wc * 64 + j * 16 + fg * 4);
  }
#pragma unroll
  for (int i = 0; i < 4; ++i) {
    const int n = bm + wr * 64 + i * 16 + fr;
    if (n >= N) continue;
#pragma unroll
    for (int j = 0; j < 4; ++j) {
      const int m0 = bn + wc * 64 + j * 16 + fg * 4;
      f32x4 v = acc[i][j];
      if constexpr (std::is_same<CT, float>::value) {
        float* p = C + (size_t)n * M + m0;
        if (accumulate) {
          float4 o = *(float4*)p;
          o.x += v[0]; o.y += v[1]; o.z += v[2]; o.w += v[3];
          *(float4*)p = o;
        } else {
          *(float4*)p = make_float4(v[0] + bv[j].x, v[1] + bv[j].y,
                                    v[2] + bv[j].z, v[3] + bv[j].w);
        }
      } else {
        uint2 o;
        o.x = pack2(v[0] + bv[j].x, v[1] + bv[j].y);
        o.y = pack2(v[2] + bv[j].z, v[3] + bv[j].w);
        *(uint2*)(C + (size_t)n * M + m0) = o;
      }
    }
  }
}

// fp32 W[K][M] -> bf16 Wt[M][K] (transpose), 32x32 LDS tiles, z-batched.
__global__ __launch_bounds__(256) void convert_wT(
    const float* __restrict__ W, bf16_t* __restrict__ Wt, int K, int M)
{
  __shared__ float sm[32][33];
  W  += (size_t)blockIdx.z * K * M;
  Wt += (size_t)blockIdx.z * K * M;
  int mb = blockIdx.x * 32, kb = blockIdx.y * 32;
  int tx = threadIdx.x & 31, ty = threadIdx.x >> 5;
#pragma unroll
  for (int i = 0; i < 4; ++i)
    sm[ty + i * 8][tx] = W[(size_t)(kb + ty + i * 8) * M + mb + tx];
  __syncthreads();
#pragma unroll
  for (int i = 0; i < 4; ++i)
    Wt[(size_t)(mb + ty + i * 8) * K + kb + tx] = (bf16_t)f2bf(sm[tx][ty + i * 8]);
}

// fp32 -> bf16 flat cast, 4 elems/thread
__global__ __launch_bounds__(256) void f2bf_vec(
    const float* __restrict__ in, bf16_t* __restrict__ out, long n4)
{
  long t = (long)blockIdx.x * 256 + threadIdx.x;
  if (t >= n4) return;
  float4 v = ((const float4*)in)[t];
  uint2 o;
  o.x = pack2(v.x, v.y);
  o.y = pack2(v.z, v.w);
  ((uint2*)out)[t] = o;
}

// all six combined bias vectors in one launch.
// bcAll[l*3+0]=bc_t, +1=bc_q, +2=bc_a for layer l. conv_bias is [12][512].
__global__ __launch_bounds__(256) void combine_bias6(
    const float* __restrict__ cb, float* __restrict__ bcAll)
{
  int g = blockIdx.x * 256 + threadIdx.x;
  if (g >= 6 * 512) return;
  int row = g >> 9, j = g & 511;
  int l = row / 3, kind = row % 3;
  const float* b = cb + (size_t)l * 6 * 512;
  float v;
  if (kind == 0)      v = (b[0 * 512 + j] + b[3 * 512 + j] + b[5 * 512 + j]) / 3.f;
  else if (kind == 1) v = (b[1 * 512 + j] + b[4 * 512 + j]) * 0.5f;
  else                v = b[2 * 512 + j];
  bcAll[(size_t)row * 512 + j] = v;
}

// ---------------------------------------------------------------------------
// CSR build: histogram w/ slot assignment, 3-kernel exclusive scan, scatter.
// ---------------------------------------------------------------------------
__global__ __launch_bounds__(256) void csr_hist(
    const int* __restrict__ dst, int* __restrict__ deg, int* __restrict__ pos, int E)
{
  int e = blockIdx.x * 256 + threadIdx.x;
  if (e >= E) return;
  pos[e] = atomicAdd(&deg[dst[e]], 1);
}

__global__ __launch_bounds__(256) void scan1(
    const int* __restrict__ in, int* __restrict__ out, int* __restrict__ bsum, int n)
{
  __shared__ int sm[256];
  int t = threadIdx.x;
  int base = blockIdx.x * 1024 + t * 4;
  int v[4], sum = 0;
#pragma unroll
  for (int k = 0; k < 4; ++k) { v[k] = (base + k < n) ? in[base + k] : 0; sum += v[k]; }
  sm[t] = sum;
  __syncthreads();
  for (int off = 1; off < 256; off <<= 1) {
    int x = (t >= off) ? sm[t - off] : 0;
    __syncthreads();
    sm[t] += x;
    __syncthreads();
  }
  int run = (t > 0) ? sm[t - 1] : 0;
  if (t == 255) bsum[blockIdx.x] = sm[255];
#pragma unroll
  for (int k = 0; k < 4; ++k) {
    if (base + k < n) out[base + k] = run;
    run += v[k];
  }
}

__global__ __launch_bounds__(64) void scan2(int* __restrict__ bsum, int nb)
{
  __shared__ int sm[64];
  int t = threadIdx.x;
  int v = (t < nb) ? bsum[t] : 0;
  sm[t] = v;
  __syncthreads();
  for (int off = 1; off < 64; off <<= 1) {
    int x = (t >= off) ? sm[t - off] : 0;
    __syncthreads();
    sm[t] += x;
    __syncthreads();
  }
  if (t < nb) bsum[t] = sm[t] - v;   // exclusive
}

__global__ __launch_bounds__(256) void scan3(
    int* __restrict__ out, const int* __restrict__ bsum, int n)
{
  int g = blockIdx.x * 256 + threadIdx.x;
  if (g < n) out[g] += bsum[g >> 10];
}

__global__ __launch_bounds__(256) void csr_scatter(
    const int* __restrict__ dst, const int* __restrict__ start,
    const int* __restrict__ pos, int* __restrict__ eidx, int E)
{
  int e = blockIdx.x * 256 + threadIdx.x;
  if (e >= E) return;
  eidx[start[dst[e]] + pos[e]] = e;
}

// ---------------------------------------------------------------------------
// Fused GATv2 message+softmax+aggregate, one wave per dst node, no atomics.
// If bc != nullptr: also applies HeteroConv-mean + bias + relu (final
// relation for this node type) and writes the NEW h in place of acc.
// ---------------------------------------------------------------------------
__global__ __launch_bounds__(256) void gat_fused(
    const bf16_t* __restrict__ xl, const bf16_t* __restrict__ xr,
    const int* __restrict__ srcArr, const int* __restrict__ start,
    const int* __restrict__ deg, const int* __restrict__ eidx,
    const float* __restrict__ att, bf16_t* __restrict__ acc,
    int Nd, int accumulate, const float* __restrict__ bc, float inv_div)
{
  int d = blockIdx.x * 4 + (threadIdx.x >> 6);
  if (d >= Nd) return;
  int lane = threadIdx.x & 63;

  float xrr[8];
  unpack8(*(const uint4*)(xr + (size_t)d * 512 + lane * 8), xrr);
  float at[8];
  *(float4*)(at)     = *(const float4*)(att + lane * 8);
  *(float4*)(at + 4) = *(const float4*)(att + lane * 8 + 4);

  float acc8[8] = {0.f, 0.f, 0.f, 0.f, 0.f, 0.f, 0.f, 0.f};
  float den = 0.f;
  int n = deg[d], s0 = start[d];
  for (int i = 0; i < n; ++i) {
    int e = eidx[s0 + i];
    int s = srcArr[e];
    float f[8];
    unpack8(*(const uint4*)(xl + (size_t)s * 512 + lane * 8), f);
    float p = 0.f;
#pragma unroll
    for (int k = 0; k < 8; ++k) {
      float x = f[k] + xrr[k];
      p = fmaf(at[k], x >= 0.f ? x : NEG_SLOPE * x, p);
    }
#pragma unroll
    for (int m = 8; m >= 1; m >>= 1) p += __shfl_xor(p, m);  // 16-lane group = head
    float ex = __expf(p);
    den += ex;
#pragma unroll
    for (int k = 0; k < 8; ++k) acc8[k] = fmaf(ex, f[k], acc8[k]);
  }
  float inv = 1.f / (den + 1e-16f);
#pragma unroll
  for (int k = 0; k < 8; ++k) acc8[k] *= inv;

  bf16_t* out = acc + (size_t)d * 512 + lane * 8;
  if (accumulate) {
    float old[8];
    unpack8(*(const uint4*)out, old);
#pragma unroll
    for (int k = 0; k < 8; ++k) acc8[k] += old[k];
  }
  if (bc) {   // finalize: mean + combined bias + relu
    float bcv[8];
    *(float4*)(bcv)     = *(const float4*)(bc + lane * 8);
    *(float4*)(bcv + 4) = *(const float4*)(bc + lane * 8 + 4);
#pragma unroll
    for (int k = 0; k < 8; ++k)
      acc8[k] = fmaxf(fmaf(acc8[k], inv_div, bcv[k]), 0.f);
  }
  uint4 s;
  s.x = pack2(acc8[0], acc8[1]); s.y = pack2(acc8[2], acc8[3]);
  s.z = pack2(acc8[4], acc8[5]); s.w = pack2(acc8[6], acc8[7]);
  *(uint4*)out = s;
}

// afh = relu(answer_features @ W1 + b1) -> bf16, K=6, M=64
__global__ __launch_bounds__(256) void af_hidden(
    const float* __restrict__ af, const float* __restrict__ W1,
    const float* __restrict__ b1, bf16_t* __restrict__ out, int n)
{
  int t = blockIdx.x * blockDim.x + threadIdx.x;
  if (t >= n * 64) return;
  int i = t >> 6, j = t & 63;
  const float* a = af + (size_t)i * 6;
  float s = b1[j];
#pragma unroll
  for (int k = 0; k < 6; ++k) s = fmaf(a[k], W1[k * 64 + j], s);
  out[t] = (bf16_t)f2bf(fmaxf(s, 0.f));
}

__global__ __launch_bounds__(256) void build_sim(
    const int* __restrict__ ei, int* __restrict__ ss, int* __restrict__ sd)
{
  int t = blockIdx.x * blockDim.x + threadIdx.x;
  if (t >= E_SIM + NQ) return;
  if (t < E_SIM) { ss[t] = ei[t]; sd[t] = ei[E_SIM + t]; }
  else           { ss[t] = t - E_SIM; sd[t] = t - E_SIM; }
}

__global__ __launch_bounds__(256) void head_final(
    const float* __restrict__ qpre, const float* __restrict__ rpre,
    const float* __restrict__ qg, const float* __restrict__ qb,
    const float* __restrict__ rg, const float* __restrict__ rb,
    const float* __restrict__ score_bias, float* __restrict__ out, int E)
{
  int e = blockIdx.x * 4 + (threadIdx.x >> 6);
  if (e >= E) return;
  int lane = threadIdx.x & 63;

  float4 q = *(const float4*)(qpre + (size_t)e * 256 + lane * 4);
  float s = q.x + q.y + q.z + q.w;
#pragma unroll
  for (int m = 32; m >= 1; m >>= 1) s += __shfl_xor(s, m);
  float mu = s * (1.f / 256.f);
  float dq0 = q.x - mu, dq1 = q.y - mu, dq2 = q.z - mu, dq3 = q.w - mu;
  float v = dq0 * dq0 + dq1 * dq1 + dq2 * dq2 + dq3 * dq3;
#pragma unroll
  for (int m = 32; m >= 1; m >>= 1) v += __shfl_xor(v, m);
  float rstd = rsqrtf(v * (1.f / 256.f) + 1e-5f);
  float4 g4 = *(const float4*)(qg + lane * 4);
  float4 b4 = *(const float4*)(qb + lane * 4);
  float qn0 = dq0 * rstd * g4.x + b4.x, qn1 = dq1 * rstd * g4.y + b4.y;
  float qn2 = dq2 * rstd * g4.z + b4.z, qn3 = dq3 * rstd * g4.w + b4.w;

  float4 r = *(const float4*)(rpre + (size_t)e * 256 + lane * 4);
  s = r.x + r.y + r.z + r.w;
#pragma unroll
  for (int m = 32; m >= 1; m >>= 1) s += __shfl_xor(s, m);
  mu = s * (1.f / 256.f);
  float dr0 = r.x - mu, dr1 = r.y - mu, dr2 = r.z - mu, dr3 = r.w - mu;
  v = dr0 * dr0 + dr1 * dr1 + dr2 * dr2 + dr3 * dr3;
#pragma unroll
  for (int m = 32; m >= 1; m >>= 1) v += __shfl_xor(v, m);
  rstd = rsqrtf(v * (1.f / 256.f) + 1e-5f);
  g4 = *(const float4*)(rg + lane * 4);
  b4 = *(const float4*)(rb + lane * 4);
  float rn0 = dr0 * rstd * g4.x + b4.x, rn1 = dr1 * rstd * g4.y + b4.y;
  float rn2 = dr2 * rstd * g4.z + b4.z, rn3 = dr3 * rstd * g4.w + b4.w;

  float d = qn0 * rn0 + qn1 * rn1 + qn2 * rn2 + qn3 * rn3;
#pragma unroll
  for (int m = 32; m >= 1; m >>= 1) d += __shfl_xor(d, m);
  if (lane == 0) out[e] = d * 0.0625f + score_bias[0];
}

// ---------------------------------------------------------------------------
extern "C" void kernel_launch(void* const* d_in, const int* in_sizes, int n_in,
                              void* d_out, int out_size, void* d_ws, size_t ws_size,
                              hipStream_t stream) {
  (void)in_sizes; (void)n_in; (void)out_size;
  const float* xq      = (const float*)d_in[0];
  const float* xt      = (const float*)d_in[1];
  const float* xa      = (const float*)d_in[2];
  const float* af      = (const float*)d_in[3];
  const float* qp_W    = (const float*)d_in[4];
  const float* qp_b    = (const float*)d_in[5];
  const float* tp_W    = (const float*)d_in[6];
  const float* tp_b    = (const float*)d_in[7];
  const float* ap_W    = (const float*)d_in[8];
  const float* ap_b    = (const float*)d_in[9];
  const float* afp_W1  = (const float*)d_in[10];
  const float* afp_b1  = (const float*)d_in[11];
  const float* afp_W2  = (const float*)d_in[12];
  const float* afp_b2  = (const float*)d_in[13];
  const float* conv_Wl = (const float*)d_in[14];
  const float* conv_bl = (const float*)d_in[15];
  const float* conv_Wr = (const float*)d_in[16];
  const float* conv_br = (const float*)d_in[17];
  const float* conv_att  = (const float*)d_in[18];
  const float* conv_bias = (const float*)d_in[19];
  const float* qh_W    = (const float*)d_in[20];
  const float* qh_b    = (const float*)d_in[21];
  const float* qh_g    = (const float*)d_in[22];
  const float* qh_beta = (const float*)d_in[23];
  const float* rh_W    = (const float*)d_in[24];
  const float* rh_b    = (const float*)d_in[25];
  const float* rh_g    = (const float*)d_in[26];
  const float* rh_beta = (const float*)d_in[27];
  const float* score_b = (const float*)d_in[28];
  const int* ei_gr   = (const int*)d_in[29];
  const int* ei_lt   = (const int*)d_in[30];
  const int* ei_sim  = (const int*)d_in[31];
  const int* ei_comp = (const int*)d_in[32];
  const int* ei_gen  = (const int*)d_in[33];

  char* base = (char*)d_ws;
  size_t off = 0;
  auto alloc = [&](size_t bytes) {
    void* p = base + off;
    off = (off + bytes + 255) & ~(size_t)255;
    return p;
  };
  bf16_t* hq   = (bf16_t*)alloc((size_t)NQ * 512 * 2);
  bf16_t* ht   = (bf16_t*)alloc((size_t)NT * 512 * 2);
  bf16_t* ha   = (bf16_t*)alloc((size_t)NA * 512 * 2);
  bf16_t* acct = (bf16_t*)alloc((size_t)NT * 512 * 2);   // ht ping-pong; qpre f32
  bf16_t* accq = (bf16_t*)alloc((size_t)NQ * 512 * 2);   // hq ping-pong; afh bf16
  bf16_t* xlb  = (bf16_t*)alloc((size_t)50000 * 512 * 2);// staging/af_emb
  bf16_t* xrb  = (bf16_t*)alloc((size_t)50000 * 512 * 2);// also rpre f32
  int* simsrc  = (int*)alloc((size_t)(E_SIM + NQ) * 4);
  int* simdst  = (int*)alloc((size_t)(E_SIM + NQ) * 4);

  // bf16-transposed weights
  bf16_t* wqp  = (bf16_t*)alloc((size_t)512 * 384 * 2);
  bf16_t* wtp  = (bf16_t*)alloc((size_t)512 * 384 * 2);
  bf16_t* wap  = (bf16_t*)alloc((size_t)512 * 384 * 2);
  bf16_t* wl   = (bf16_t*)alloc((size_t)12 * 512 * 512 * 2);
  bf16_t* wr   = (bf16_t*)alloc((size_t)12 * 512 * 512 * 2);
  bf16_t* wafp2 = (bf16_t*)alloc((size_t)512 * 64 * 2);
  bf16_t* wqh  = (bf16_t*)alloc((size_t)256 * 512 * 2);
  bf16_t* wrh0 = (bf16_t*)alloc((size_t)256 * 512 * 2);
  bf16_t* wrh1 = (bf16_t*)alloc((size_t)256 * 512 * 2);
  bf16_t* wrh2 = (bf16_t*)alloc((size_t)256 * 512 * 2);
  float* bcAll = (float*)alloc(6 * 512 * 4);   // [l*3+{t,q,a}][512]

  // CSR topology. Order: 0=gr 1=rgr 2=rlt 3=sim 4=comp 5=lt (lt LAST)
  struct Topo { const int* src; const int* dst; int Nd, E; };
  Topo topo[6] = {
    {ei_gr,        ei_gr + E_GR,     NT, E_GR},
    {ei_gr + E_GR, ei_gr,            NQ, E_GR},
    {ei_lt + E_LT, ei_lt,            NT, E_LT},
    {simsrc,       simdst,           NQ, E_SIM + NQ},
    {ei_comp,      ei_comp + E_COMP, NT, E_COMP},
    {ei_lt,        ei_lt + E_LT,     NA, E_LT},
  };
  int *deg[6], *startp[6], *eidx[6];
  for (int r = 0; r < 6; ++r) {
    deg[r]    = (int*)alloc((size_t)topo[r].Nd * 4);
    startp[r] = (int*)alloc((size_t)topo[r].Nd * 4);
    eidx[r]   = (int*)alloc((size_t)topo[r].E * 4);
  }
  int* posb = (int*)alloc((size_t)MAXE * 4);
  int* bsum = (int*)alloc(64 * 4);
  if (off > ws_size) {
    fprintf(stderr, "kernel_launch: ws too small, need %zu have %zu\n", off, ws_size);
    return;
  }

  // --- weight conversion (fp32 [K][M] -> bf16 [M][K]) ---
  convert_wT<<<dim3(512 / 32, 512 / 32, 12), 256, 0, stream>>>(conv_Wl, wl, 512, 512);
  convert_wT<<<dim3(512 / 32, 512 / 32, 12), 256, 0, stream>>>(conv_Wr, wr, 512, 512);
  convert_wT<<<dim3(512 / 32, 384 / 32, 1), 256, 0, stream>>>(qp_W, wqp, 384, 512);
  convert_wT<<<dim3(512 / 32, 384 / 32, 1), 256, 0, stream>>>(tp_W, wtp, 384, 512);
  convert_wT<<<dim3(512 / 32, 384 / 32, 1), 256, 0, stream>>>(ap_W, wap, 384, 512);
  convert_wT<<<dim3(512 / 32, 64 / 32, 1), 256, 0, stream>>>(afp_W2, wafp2, 64, 512);
  convert_wT<<<dim3(256 / 32, 512 / 32, 1), 256, 0, stream>>>(qh_W, wqh, 512, 256);
  convert_wT<<<dim3(256 / 32, 512 / 32, 1), 256, 0, stream>>>(rh_W, wrh0, 512, 256);
  convert_wT<<<dim3(256 / 32, 512 / 32, 1), 256, 0, stream>>>(rh_W + 512 * 256, wrh1, 512, 256);
  convert_wT<<<dim3(256 / 32, 512 / 32, 1), 256, 0, stream>>>(rh_W + 1024 * 256, wrh2, 512, 256);
  combine_bias6<<<(6 * 512 + 255) / 256, 256, 0, stream>>>(conv_bias, bcAll);

  build_sim<<<(E_SIM + NQ + 255) / 256, 256, 0, stream>>>(ei_sim, simsrc, simdst);
  for (int r = 0; r < 6; ++r) {
    const Topo& T = topo[r];
    hipMemsetAsync(deg[r], 0, (size_t)T.Nd * 4, stream);
    csr_hist<<<(T.E + 255) / 256, 256, 0, stream>>>(T.dst, deg[r], posb, T.E);
    int nb = (T.Nd + 1023) / 1024;
    scan1<<<nb, 256, 0, stream>>>(deg[r], startp[r], bsum, T.Nd);
    scan2<<<1, 64, 0, stream>>>(bsum, nb);
    scan3<<<(T.Nd + 255) / 256, 256, 0, stream>>>(startp[r], bsum, T.Nd);
    csr_scatter<<<(T.E + 255) / 256, 256, 0, stream>>>(T.dst, startp[r], posb,
                                                       eidx[r], T.E);
  }

  // single-z launches
  auto gemm1 = [&](const bf16_t* A, const bf16_t* Bt, const float* bias, bf16_t* C,
                   int N_, int K_, int M_, const int* ridx = nullptr) {
    dim3 g(M_ / 256, (N_ + 127) / 128, 1);
    bgemm<bf16_t><<<g, 512, 0, stream>>>(A, Bt, bias, C, ridx, N_,
                                         A, Bt, bias, C, ridx, N_, K_, M_, 0);
  };
  auto gemmf1 = [&](const bf16_t* A, const bf16_t* Bt, const float* bias, float* C,
                    int N_, int K_, int M_, int acc_, const int* ridx = nullptr) {
    dim3 g(M_ / 256, (N_ + 127) / 128, 1);
    bgemm<float><<<g, 512, 0, stream>>>(A, Bt, bias, C, ridx, N_,
                                        A, Bt, bias, C, ridx, N_, K_, M_, acc_);
  };
  // z-paired launches (two independent GEMMs, same K/M/accum/CT)
  auto gemm2 = [&](const bf16_t* A0, const bf16_t* B0, const float* b0, bf16_t* C0, int N0_,
                   const bf16_t* A1, const bf16_t* B1, const float* b1, bf16_t* C1, int N1_,
                   int K_, int M_) {
    int nb0 = (N0_ + 127) / 128, nb1 = (N1_ + 127) / 128;
    dim3 g(M_ / 256, nb0 > nb1 ? nb0 : nb1, 2);
    bgemm<bf16_t><<<g, 512, 0, stream>>>(A0, B0, b0, C0, nullptr, N0_,
                                         A1, B1, b1, C1, nullptr, N1_, K_, M_, 0);
  };
  auto gemmf2 = [&](const bf16_t* A0, const bf16_t* B0, const float* b0, float* C0,
                    const int* r0, int N0_,
                    const bf16_t* A1, const bf16_t* B1, const float* b1, float* C1,
                    const int* r1, int N1_, int K_, int M_) {
    int nb0 = (N0_ + 127) / 128, nb1 = (N1_ + 127) / 128;
    dim3 g(M_ / 256, nb0 > nb1 ? nb0 : nb1, 2);
    bgemm<float><<<g, 512, 0, stream>>>(A0, B0, b0, C0, r0, N0_,
                                        A1, B1, b1, C1, r1, N1_, K_, M_, 0);
  };

  // Input projections: xq separate; xt/xa z-paired (xt->xlb, xa->xrb casts).
  f2bf_vec<<<((long)NQ * 96 + 255) / 256, 256, 0, stream>>>(xq, xlb, (long)NQ * 96);
  gemm1(xlb, wqp, qp_b, hq, NQ, 384, 512);
  f2bf_vec<<<((long)NT * 96 + 255) / 256, 256, 0, stream>>>(xt, xlb, (long)NT * 96);
  f2bf_vec<<<((long)NA * 96 + 255) / 256, 256, 0, stream>>>(xa, xrb, (long)NA * 96);
  gemm2(xlb, wtp, tp_b, ht, NT, xrb, wap, ap_b, ha, NA, 384, 512);

  // Layer loop with ping-pong h buffers; last relation per dst type carries
  // the fused mean+bias+relu (bc != null) and produces the new h in acc.
  bf16_t *hq_i = hq, *ht_i = ht, *hq_o = accq, *ht_o = acct;
  for (int l = 0; l < 2; ++l) {
    const float* bc_t = bcAll + (size_t)(l * 3 + 0) * 512;
    const float* bc_q = bcAll + (size_t)(l * 3 + 1) * 512;
    const float* bc_a = bcAll + (size_t)(l * 3 + 2) * 512;

    struct Rel { const bf16_t* xs; const bf16_t* xd; int Ns, po; bf16_t* acc;
                 int accum; const float* bc; float inv; };
    Rel rels[6] = {
      {hq_i, ht_i, NQ, 0, ht_o, 0, nullptr, 0.f},      // gr
      {ht_i, hq_i, NT, 1, hq_o, 0, nullptr, 0.f},      // rgr
      {ha,   ht_i, NA, 3, ht_o, 1, nullptr, 0.f},      // rlt
      {hq_i, hq_i, NQ, 4, hq_o, 1, bc_q, 0.5f},        // sim (final for q)
      {ht_i, ht_i, NT, 5, ht_o, 1, bc_t, 1.f / 3.f},   // comp (final for t)
      {ht_i, ha,   NT, 2, ha,   0, bc_a, 1.f},         // lt (final for a, in-place)
    };
    for (int r = 0; r < 6; ++r) {
      const Rel& R = rels[r];
      const Topo& T = topo[r];
      size_t po = (size_t)l * 6 + R.po;
      // z-paired: xs@Wl -> xlb  and  xd@Wr -> xrb in one dispatch
      gemm2(R.xs, wl + po * 512 * 512, conv_bl + po * 512, xlb, R.Ns,
            R.xd, wr + po * 512 * 512, conv_br + po * 512, xrb, T.Nd, 512, 512);
      int gb = (T.Nd + 3) / 4;
      gat_fused<<<gb, 256, 0, stream>>>(xlb, xrb, T.src, startp[r], deg[r],
                                        eidx[r], conv_att + po * 512, R.acc,
                                        T.Nd, R.accum, R.bc, R.inv);
    }
    bf16_t* t;
    t = hq_i; hq_i = hq_o; hq_o = t;
    t = ht_i; ht_i = ht_o; ht_o = t;
  }
  // after 2 swaps: hq_i==hq, ht_i==ht; scratch acct/accq free again.

  // Head: gathers fused via ridx; qpre/rpre-first z-paired.
  float* qpre = (float*)acct;
  float* rpre = (float*)xrb;
  bf16_t* afh = accq;
  const int* gsrc = ei_gen;
  const int* gdst = ei_gen + E_GEN;

  gemmf2(hq_i, wqh, qh_b, qpre, gsrc, E_GEN,
         ht_i, wrh0, rh_b, rpre, gdst, E_GEN, 512, 256);    // q_emb | t_emb
  gemmf1(ha, wrh1, nullptr, rpre, E_GEN, 512, 256, 1, gdst); // + a_emb @ rh_W[1]
  af_hidden<<<(E_GEN * 64 + 255) / 256, 256, 0, stream>>>(af, afp_W1, afp_b1,
                                                          afh, E_GEN);
  gemm1(afh, wafp2, afp_b2, xlb, E_GEN, 64, 512);            // af_emb
  gemmf1(xlb, wrh2, nullptr, rpre, E_GEN, 512, 256, 1);      // + af_emb @ rh_W[2]
  head_final<<<(E_GEN + 3) / 4, 256, 0, stream>>>(
      qpre, rpre, qh_g, qh_beta, rh_g, rh_beta, score_b, (float*)d_out, E_GEN);
}

// Round 15
// 1608.414 us; speedup vs baseline: 1.0676x; 1.0676x over previous
//
#include <hip/hip_runtime.h>
#include <cstdio>
#include <type_traits>

#define NQ 10000
#define NT 50000
#define NA 50000
#define E_GR 50000
#define E_LT 50000
#define E_SIM 80000
#define E_COMP 100000
#define E_GEN 50000
#define MAXE 100000
#define NEG_SLOPE 0.2f

typedef unsigned short bf16_t;
typedef unsigned int u32;
typedef __attribute__((ext_vector_type(8))) short short8v;
typedef __attribute__((ext_vector_type(4))) float f32x4;

__device__ __forceinline__ float bf2f(u32 bits) { return __uint_as_float(bits << 16); }
__device__ __forceinline__ u32 f2bf(float f) {
  u32 u = __float_as_uint(f);
  return (u + 0x7FFFu + ((u >> 16) & 1u)) >> 16;   // RTNE
}
__device__ __forceinline__ u32 pack2(float a, float b) { return f2bf(a) | (f2bf(b) << 16); }
__device__ __forceinline__ void unpack8(uint4 u, float* f) {
  f[0] = bf2f(u.x & 0xffffu); f[1] = bf2f(u.x >> 16);
  f[2] = bf2f(u.y & 0xffffu); f[3] = bf2f(u.y >> 16);
  f[4] = bf2f(u.z & 0xffffu); f[5] = bf2f(u.z >> 16);
  f[6] = bf2f(u.w & 0xffffu); f[7] = bf2f(u.w >> 16);
}

// async global->LDS, 16B per lane; LDS dest = wave-uniform base + lane*16.
__device__ __forceinline__ void gload16(const void* g, void* l) {
  __builtin_amdgcn_global_load_lds(
      (const __attribute__((address_space(1))) void*)g,
      (__attribute__((address_space(3))) void*)l, 16, 0, 0);
}

// ---------------------------------------------------------------------------
// MFMA bf16 GEMM, z-paired. For z in {0,1}: C_z = A_z @ Bt_z^T (+bias|+=C).
// 128x256 tile, BK=32, 256 threads = 4 waves (2x2), wave tile 64x128,
// acc[4][8] (~200 regs -> 2 waves/SIMD). LDS-port model: traffic/step =
// A 128x32x2B x Wc(2) + B 256x32x2B x Wr(2) = 48KB (vs 64KB at the r12
// (2,4) mapping) -> MfmaUtil ceiling ~42% (was ~31%).
// THREE 24KB buffers (72KB -> 2 blocks/CU), rotation s%3, ONE barrier/step:
//   stage buf[(s+1)%3] [6 loads/thr] ; vmcnt(6) [drain buf[s] only] ;
//   barrier ; ds_read buf[s] + 32 MFMA (setprio) ; (no trailing barrier)
// Race safety: writes at step s hit buf[(s+1)%3]; laggard reads from step
// s-1 hit buf[(s-1)%3]; diff 2 mod 3 != 0; rewrite of a buffer happens two
// steps later behind an intervening barrier.
// Both-sides octet XOR (rule #21): store oct=(c&3)^((row>>1)&3) via
// pre-swizzled global k-octet (row deltas multiples of 64 -> same kg per
// thread); read oct=fg^((fr>>1)&3) -> exact 2-way bank aliasing (free).
// XCD-grouped band swizzle per z; optional ridx A-row indirection.
// M%256==0, K%32==0; N guarded; early exit uniform (before any barrier).
// ---------------------------------------------------------------------------
template <typename CT>
__global__ __launch_bounds__(256, 2) void bgemm(
    const bf16_t* __restrict__ A0, const bf16_t* __restrict__ Bt0,
    const float* __restrict__ bias0, CT* __restrict__ C0,
    const int* __restrict__ ridx0, int N0,
    const bf16_t* __restrict__ A1, const bf16_t* __restrict__ Bt1,
    const float* __restrict__ bias1, CT* __restrict__ C1,
    const int* __restrict__ ridx1, int N1,
    int K, int M, int accumulate)
{
  __shared__ short lds[3][12288];   // [buf][A: 0..4095 | B: 4096..12287]
  const int z = blockIdx.z;
  const bf16_t* A   = z ? A1 : A0;
  const bf16_t* Bt  = z ? Bt1 : Bt0;
  const float* bias = z ? bias1 : bias0;
  CT* C             = z ? C1 : C0;
  const int* ridx   = z ? ridx1 : ridx0;
  const int N       = z ? N1 : N0;

  const int tid = threadIdx.x;
  const int ncol = gridDim.x;
  const int nband = (N + 127) >> 7;         // per-z band count
  int lin = blockIdx.y * ncol + blockIdx.x;
  if (lin >= ncol * nband) return;          // uniform exit, before barriers

  // XCD-grouping swizzle (wg->XCD = id%8). Bijective incl. tail bands.
  int band, col;
  const int full = (nband >> 3) * 8 * ncol;
  if (lin < full) {
    int g = lin >> 3, x = lin & 7;
    band = x + 8 * (g / ncol);
    col  = g % ncol;
  } else {
    int r = lin - full;
    band = (nband & ~7) + r / ncol;
    col  = r % ncol;
  }
  const int bm = band * 128, bn = col * 256;

  const int lane = tid & 63;
  const int w = tid >> 6;          // 4 waves (2 row x 2 col)
  const int wr = w >> 1, wc = w & 1;
  const int fr = lane & 15, fg = lane >> 4;

  // staging: A 512 chunks (2/thread: c=t, t+256), B 1024 chunks
  // (4/thread: c=t+256r). chunk c: row=c>>2, oct=c&3; row deltas are
  // multiples of 64 -> (row>>1)&3 identical -> one pre-swizzled kg.
  const int kg = (((tid & 3) ^ ((tid >> 3) & 3)) << 3);
  const int rr = tid >> 2;          // 0..63
  int raw0 = min(bm + rr, N - 1);
  int raw1 = min(bm + rr + 64, N - 1);
  const bf16_t* gA0 = A + (size_t)(ridx ? ridx[raw0] : raw0) * K + kg;
  const bf16_t* gA1 = A + (size_t)(ridx ? ridx[raw1] : raw1) * K + kg;
  const bf16_t* gB[4];
#pragma unroll
  for (int r = 0; r < 4; ++r)
    gB[r] = Bt + (size_t)(bn + rr + 64 * r) * K + kg;
  const int wb = w << 9;   // wave-uniform LDS short offset (64 chunks * 8)

  f32x4 acc[4][8];
#pragma unroll
  for (int i = 0; i < 4; ++i)
#pragma unroll
    for (int j = 0; j < 8; ++j) acc[i][j] = (f32x4){0.f, 0.f, 0.f, 0.f};

  auto stage = [&](int buf, int k0) {
    short* base = &lds[buf][0];
    gload16(gA0 + k0, base + wb);                    // A chunks 0..255
    gload16(gA1 + k0, base + 2048 + wb);             // A chunks 256..511
#pragma unroll
    for (int r = 0; r < 4; ++r)
      gload16(gB[r] + k0, base + 4096 + r * 2048 + wb);  // B chunks
  };

  const int nsteps = K >> 5;
  stage(0, 0);
  const int co = (fg ^ ((fr >> 1) & 3)) << 3;   // read-side XOR octet
  for (int s = 0; s < nsteps; ++s) {
    const int cur = s % 3;
    if (s + 1 < nsteps) {
      stage((s + 1) % 3, (s + 1) << 5);
      asm volatile("s_waitcnt vmcnt(6)" ::: "memory");  // drain buf[cur] only
    } else {
      asm volatile("s_waitcnt vmcnt(0)" ::: "memory");
    }
    __builtin_amdgcn_s_barrier();            // publish buf[cur]
    asm volatile("" ::: "memory");
    const short* LA = &lds[cur][0];
    const short* LB = &lds[cur][4096];
    short8v a[4];
#pragma unroll
    for (int i = 0; i < 4; ++i) {
      int R = wr * 64 + i * 16 + fr;
      a[i] = *(const short8v*)&LA[R * 32 + co];
    }
    short8v b[8];
#pragma unroll
    for (int j = 0; j < 8; ++j) {
      int R = wc * 128 + j * 16 + fr;
      b[j] = *(const short8v*)&LB[R * 32 + co];
    }
    __builtin_amdgcn_s_setprio(1);
#pragma unroll
    for (int i = 0; i < 4; ++i)
#pragma unroll
      for (int j = 0; j < 8; ++j)
        acc[i][j] = __builtin_amdgcn_mfma_f32_16x16x32_bf16(b[j], a[i],
                                                            acc[i][j], 0, 0, 0);
    __builtin_amdgcn_s_setprio(0);
    asm volatile("" ::: "memory");
    // no trailing barrier: 3-buffer rotation (see header)
  }

  // epilogue: D cols (fr) = A rows; D row quad (fg*4+q) = C cols.
  float4 bv[8];
#pragma unroll
  for (int j = 0; j < 8; ++j) {
    bv[j] = make_float4(0.f, 0.f, 0.f, 0.f);
    if (!accumulate && bias)
      bv[j] = *(const float4*)(bias + bn + wc * 128 + j * 16 + fg * 4);
  }
#pragma unroll
  for (int i = 0; i < 4; ++i) {
    const int n = bm + wr * 64 + i * 16 + fr;
    if (n >= N) continue;
#pragma unroll
    for (int j = 0; j < 8; ++j) {
      const int m0 = bn + wc * 128 + j * 16 + fg * 4;
      f32x4 v = acc[i][j];
      if constexpr (std::is_same<CT, float>::value) {
        float* p = C + (size_t)n * M + m0;
        if (accumulate) {
          float4 o = *(float4*)p;
          o.x += v[0]; o.y += v[1]; o.z += v[2]; o.w += v[3];
          *(float4*)p = o;
        } else {
          *(float4*)p = make_float4(v[0] + bv[j].x, v[1] + bv[j].y,
                                    v[2] + bv[j].z, v[3] + bv[j].w);
        }
      } else {
        uint2 o;
        o.x = pack2(v[0] + bv[j].x, v[1] + bv[j].y);
        o.y = pack2(v[2] + bv[j].z, v[3] + bv[j].w);
        *(uint2*)(C + (size_t)n * M + m0) = o;
      }
    }
  }
}

// fp32 W[K][M] -> bf16 Wt[M][K] (transpose), 32x32 LDS tiles, z-batched.
__global__ __launch_bounds__(256) void convert_wT(
    const float* __restrict__ W, bf16_t* __restrict__ Wt, int K, int M)
{
  __shared__ float sm[32][33];
  W  += (size_t)blockIdx.z * K * M;
  Wt += (size_t)blockIdx.z * K * M;
  int mb = blockIdx.x * 32, kb = blockIdx.y * 32;
  int tx = threadIdx.x & 31, ty = threadIdx.x >> 5;
#pragma unroll
  for (int i = 0; i < 4; ++i)
    sm[ty + i * 8][tx] = W[(size_t)(kb + ty + i * 8) * M + mb + tx];
  __syncthreads();
#pragma unroll
  for (int i = 0; i < 4; ++i)
    Wt[(size_t)(mb + ty + i * 8) * K + kb + tx] = (bf16_t)f2bf(sm[tx][ty + i * 8]);
}

// fp32 -> bf16 flat cast, 4 elems/thread
__global__ __launch_bounds__(256) void f2bf_vec(
    const float* __restrict__ in, bf16_t* __restrict__ out, long n4)
{
  long t = (long)blockIdx.x * 256 + threadIdx.x;
  if (t >= n4) return;
  float4 v = ((const float4*)in)[t];
  uint2 o;
  o.x = pack2(v.x, v.y);
  o.y = pack2(v.z, v.w);
  ((uint2*)out)[t] = o;
}

// all six combined bias vectors in one launch.
// bcAll[l*3+0]=bc_t, +1=bc_q, +2=bc_a for layer l. conv_bias is [12][512].
__global__ __launch_bounds__(256) void combine_bias6(
    const float* __restrict__ cb, float* __restrict__ bcAll)
{
  int g = blockIdx.x * 256 + threadIdx.x;
  if (g >= 6 * 512) return;
  int row = g >> 9, j = g & 511;
  int l = row / 3, kind = row % 3;
  const float* b = cb + (size_t)l * 6 * 512;
  float v;
  if (kind == 0)      v = (b[0 * 512 + j] + b[3 * 512 + j] + b[5 * 512 + j]) / 3.f;
  else if (kind == 1) v = (b[1 * 512 + j] + b[4 * 512 + j]) * 0.5f;
  else                v = b[2 * 512 + j];
  bcAll[(size_t)row * 512 + j] = v;
}

// ---------------------------------------------------------------------------
// CSR build: histogram w/ slot assignment, 3-kernel exclusive scan, scatter.
// ---------------------------------------------------------------------------
__global__ __launch_bounds__(256) void csr_hist(
    const int* __restrict__ dst, int* __restrict__ deg, int* __restrict__ pos, int E)
{
  int e = blockIdx.x * 256 + threadIdx.x;
  if (e >= E) return;
  pos[e] = atomicAdd(&deg[dst[e]], 1);
}

__global__ __launch_bounds__(256) void scan1(
    const int* __restrict__ in, int* __restrict__ out, int* __restrict__ bsum, int n)
{
  __shared__ int sm[256];
  int t = threadIdx.x;
  int base = blockIdx.x * 1024 + t * 4;
  int v[4], sum = 0;
#pragma unroll
  for (int k = 0; k < 4; ++k) { v[k] = (base + k < n) ? in[base + k] : 0; sum += v[k]; }
  sm[t] = sum;
  __syncthreads();
  for (int off = 1; off < 256; off <<= 1) {
    int x = (t >= off) ? sm[t - off] : 0;
    __syncthreads();
    sm[t] += x;
    __syncthreads();
  }
  int run = (t > 0) ? sm[t - 1] : 0;
  if (t == 255) bsum[blockIdx.x] = sm[255];
#pragma unroll
  for (int k = 0; k < 4; ++k) {
    if (base + k < n) out[base + k] = run;
    run += v[k];
  }
}

__global__ __launch_bounds__(64) void scan2(int* __restrict__ bsum, int nb)
{
  __shared__ int sm[64];
  int t = threadIdx.x;
  int v = (t < nb) ? bsum[t] : 0;
  sm[t] = v;
  __syncthreads();
  for (int off = 1; off < 64; off <<= 1) {
    int x = (t >= off) ? sm[t - off] : 0;
    __syncthreads();
    sm[t] += x;
    __syncthreads();
  }
  if (t < nb) bsum[t] = sm[t] - v;   // exclusive
}

__global__ __launch_bounds__(256) void scan3(
    int* __restrict__ out, const int* __restrict__ bsum, int n)
{
  int g = blockIdx.x * 256 + threadIdx.x;
  if (g < n) out[g] += bsum[g >> 10];
}

__global__ __launch_bounds__(256) void csr_scatter(
    const int* __restrict__ dst, const int* __restrict__ start,
    const int* __restrict__ pos, int* __restrict__ eidx, int E)
{
  int e = blockIdx.x * 256 + threadIdx.x;
  if (e >= E) return;
  eidx[start[dst[e]] + pos[e]] = e;
}

// ---------------------------------------------------------------------------
// Fused GATv2 message+softmax+aggregate, one wave per dst node, no atomics.
// If bc != nullptr: also applies HeteroConv-mean + bias + relu (final
// relation for this node type) and writes the NEW h in place of acc.
// ---------------------------------------------------------------------------
__global__ __launch_bounds__(256) void gat_fused(
    const bf16_t* __restrict__ xl, const bf16_t* __restrict__ xr,
    const int* __restrict__ srcArr, const int* __restrict__ start,
    const int* __restrict__ deg, const int* __restrict__ eidx,
    const float* __restrict__ att, bf16_t* __restrict__ acc,
    int Nd, int accumulate, const float* __restrict__ bc, float inv_div)
{
  int d = blockIdx.x * 4 + (threadIdx.x >> 6);
  if (d >= Nd) return;
  int lane = threadIdx.x & 63;

  float xrr[8];
  unpack8(*(const uint4*)(xr + (size_t)d * 512 + lane * 8), xrr);
  float at[8];
  *(float4*)(at)     = *(const float4*)(att + lane * 8);
  *(float4*)(at + 4) = *(const float4*)(att + lane * 8 + 4);

  float acc8[8] = {0.f, 0.f, 0.f, 0.f, 0.f, 0.f, 0.f, 0.f};
  float den = 0.f;
  int n = deg[d], s0 = start[d];
  for (int i = 0; i < n; ++i) {
    int e = eidx[s0 + i];
    int s = srcArr[e];
    float f[8];
    unpack8(*(const uint4*)(xl + (size_t)s * 512 + lane * 8), f);
    float p = 0.f;
#pragma unroll
    for (int k = 0; k < 8; ++k) {
      float x = f[k] + xrr[k];
      p = fmaf(at[k], x >= 0.f ? x : NEG_SLOPE * x, p);
    }
#pragma unroll
    for (int m = 8; m >= 1; m >>= 1) p += __shfl_xor(p, m);  // 16-lane group = head
    float ex = __expf(p);
    den += ex;
#pragma unroll
    for (int k = 0; k < 8; ++k) acc8[k] = fmaf(ex, f[k], acc8[k]);
  }
  float inv = 1.f / (den + 1e-16f);
#pragma unroll
  for (int k = 0; k < 8; ++k) acc8[k] *= inv;

  bf16_t* out = acc + (size_t)d * 512 + lane * 8;
  if (accumulate) {
    float old[8];
    unpack8(*(const uint4*)out, old);
#pragma unroll
    for (int k = 0; k < 8; ++k) acc8[k] += old[k];
  }
  if (bc) {   // finalize: mean + combined bias + relu
    float bcv[8];
    *(float4*)(bcv)     = *(const float4*)(bc + lane * 8);
    *(float4*)(bcv + 4) = *(const float4*)(bc + lane * 8 + 4);
#pragma unroll
    for (int k = 0; k < 8; ++k)
      acc8[k] = fmaxf(fmaf(acc8[k], inv_div, bcv[k]), 0.f);
  }
  uint4 s;
  s.x = pack2(acc8[0], acc8[1]); s.y = pack2(acc8[2], acc8[3]);
  s.z = pack2(acc8[4], acc8[5]); s.w = pack2(acc8[6], acc8[7]);
  *(uint4*)out = s;
}

// afh = relu(answer_features @ W1 + b1) -> bf16, K=6, M=64
__global__ __launch_bounds__(256) void af_hidden(
    const float* __restrict__ af, const float* __restrict__ W1,
    const float* __restrict__ b1, bf16_t* __restrict__ out, int n)
{
  int t = blockIdx.x * blockDim.x + threadIdx.x;
  if (t >= n * 64) return;
  int i = t >> 6, j = t & 63;
  const float* a = af + (size_t)i * 6;
  float s = b1[j];
#pragma unroll
  for (int k = 0; k < 6; ++k) s = fmaf(a[k], W1[k * 64 + j], s);
  out[t] = (bf16_t)f2bf(fmaxf(s, 0.f));
}

__global__ __launch_bounds__(256) void build_sim(
    const int* __restrict__ ei, int* __restrict__ ss, int* __restrict__ sd)
{
  int t = blockIdx.x * blockDim.x + threadIdx.x;
  if (t >= E_SIM + NQ) return;
  if (t < E_SIM) { ss[t] = ei[t]; sd[t] = ei[E_SIM + t]; }
  else           { ss[t] = t - E_SIM; sd[t] = t - E_SIM; }
}

__global__ __launch_bounds__(256) void head_final(
    const float* __restrict__ qpre, const float* __restrict__ rpre,
    const float* __restrict__ qg, const float* __restrict__ qb,
    const float* __restrict__ rg, const float* __restrict__ rb,
    const float* __restrict__ score_bias, float* __restrict__ out, int E)
{
  int e = blockIdx.x * 4 + (threadIdx.x >> 6);
  if (e >= E) return;
  int lane = threadIdx.x & 63;

  float4 q = *(const float4*)(qpre + (size_t)e * 256 + lane * 4);
  float s = q.x + q.y + q.z + q.w;
#pragma unroll
  for (int m = 32; m >= 1; m >>= 1) s += __shfl_xor(s, m);
  float mu = s * (1.f / 256.f);
  float dq0 = q.x - mu, dq1 = q.y - mu, dq2 = q.z - mu, dq3 = q.w - mu;
  float v = dq0 * dq0 + dq1 * dq1 + dq2 * dq2 + dq3 * dq3;
#pragma unroll
  for (int m = 32; m >= 1; m >>= 1) v += __shfl_xor(v, m);
  float rstd = rsqrtf(v * (1.f / 256.f) + 1e-5f);
  float4 g4 = *(const float4*)(qg + lane * 4);
  float4 b4 = *(const float4*)(qb + lane * 4);
  float qn0 = dq0 * rstd * g4.x + b4.x, qn1 = dq1 * rstd * g4.y + b4.y;
  float qn2 = dq2 * rstd * g4.z + b4.z, qn3 = dq3 * rstd * g4.w + b4.w;

  float4 r = *(const float4*)(rpre + (size_t)e * 256 + lane * 4);
  s = r.x + r.y + r.z + r.w;
#pragma unroll
  for (int m = 32; m >= 1; m >>= 1) s += __shfl_xor(s, m);
  mu = s * (1.f / 256.f);
  float dr0 = r.x - mu, dr1 = r.y - mu, dr2 = r.z - mu, dr3 = r.w - mu;
  v = dr0 * dr0 + dr1 * dr1 + dr2 * dr2 + dr3 * dr3;
#pragma unroll
  for (int m = 32; m >= 1; m >>= 1) v += __shfl_xor(v, m);
  rstd = rsqrtf(v * (1.f / 256.f) + 1e-5f);
  g4 = *(const float4*)(rg + lane * 4);
  b4 = *(const float4*)(rb + lane * 4);
  float rn0 = dr0 * rstd * g4.x + b4.x, rn1 = dr1 * rstd * g4.y + b4.y;
  float rn2 = dr2 * rstd * g4.z + b4.z, rn3 = dr3 * rstd * g4.w + b4.w;

  float d = qn0 * rn0 + qn1 * rn1 + qn2 * rn2 + qn3 * rn3;
#pragma unroll
  for (int m = 32; m >= 1; m >>= 1) d += __shfl_xor(d, m);
  if (lane == 0) out[e] = d * 0.0625f + score_bias[0];
}

// ---------------------------------------------------------------------------
extern "C" void kernel_launch(void* const* d_in, const int* in_sizes, int n_in,
                              void* d_out, int out_size, void* d_ws, size_t ws_size,
                              hipStream_t stream) {
  (void)in_sizes; (void)n_in; (void)out_size;
  const float* xq      = (const float*)d_in[0];
  const float* xt      = (const float*)d_in[1];
  const float* xa      = (const float*)d_in[2];
  const float* af      = (const float*)d_in[3];
  const float* qp_W    = (const float*)d_in[4];
  const float* qp_b    = (const float*)d_in[5];
  const float* tp_W    = (const float*)d_in[6];
  const float* tp_b    = (const float*)d_in[7];
  const float* ap_W    = (const float*)d_in[8];
  const float* ap_b    = (const float*)d_in[9];
  const float* afp_W1  = (const float*)d_in[10];
  const float* afp_b1  = (const float*)d_in[11];
  const float* afp_W2  = (const float*)d_in[12];
  const float* afp_b2  = (const float*)d_in[13];
  const float* conv_Wl = (const float*)d_in[14];
  const float* conv_bl = (const float*)d_in[15];
  const float* conv_Wr = (const float*)d_in[16];
  const float* conv_br = (const float*)d_in[17];
  const float* conv_att  = (const float*)d_in[18];
  const float* conv_bias = (const float*)d_in[19];
  const float* qh_W    = (const float*)d_in[20];
  const float* qh_b    = (const float*)d_in[21];
  const float* qh_g    = (const float*)d_in[22];
  const float* qh_beta = (const float*)d_in[23];
  const float* rh_W    = (const float*)d_in[24];
  const float* rh_b    = (const float*)d_in[25];
  const float* rh_g    = (const float*)d_in[26];
  const float* rh_beta = (const float*)d_in[27];
  const float* score_b = (const float*)d_in[28];
  const int* ei_gr   = (const int*)d_in[29];
  const int* ei_lt   = (const int*)d_in[30];
  const int* ei_sim  = (const int*)d_in[31];
  const int* ei_comp = (const int*)d_in[32];
  const int* ei_gen  = (const int*)d_in[33];

  char* base = (char*)d_ws;
  size_t off = 0;
  auto alloc = [&](size_t bytes) {
    void* p = base + off;
    off = (off + bytes + 255) & ~(size_t)255;
    return p;
  };
  bf16_t* hq   = (bf16_t*)alloc((size_t)NQ * 512 * 2);
  bf16_t* ht   = (bf16_t*)alloc((size_t)NT * 512 * 2);
  bf16_t* ha   = (bf16_t*)alloc((size_t)NA * 512 * 2);
  bf16_t* acct = (bf16_t*)alloc((size_t)NT * 512 * 2);   // ht ping-pong; qpre f32
  bf16_t* accq = (bf16_t*)alloc((size_t)NQ * 512 * 2);   // hq ping-pong; afh bf16
  bf16_t* xlb  = (bf16_t*)alloc((size_t)50000 * 512 * 2);// staging/af_emb
  bf16_t* xrb  = (bf16_t*)alloc((size_t)50000 * 512 * 2);// also rpre f32
  int* simsrc  = (int*)alloc((size_t)(E_SIM + NQ) * 4);
  int* simdst  = (int*)alloc((size_t)(E_SIM + NQ) * 4);

  // bf16-transposed weights
  bf16_t* wqp  = (bf16_t*)alloc((size_t)512 * 384 * 2);
  bf16_t* wtp  = (bf16_t*)alloc((size_t)512 * 384 * 2);
  bf16_t* wap  = (bf16_t*)alloc((size_t)512 * 384 * 2);
  bf16_t* wl   = (bf16_t*)alloc((size_t)12 * 512 * 512 * 2);
  bf16_t* wr   = (bf16_t*)alloc((size_t)12 * 512 * 512 * 2);
  bf16_t* wafp2 = (bf16_t*)alloc((size_t)512 * 64 * 2);
  bf16_t* wqh  = (bf16_t*)alloc((size_t)256 * 512 * 2);
  bf16_t* wrh0 = (bf16_t*)alloc((size_t)256 * 512 * 2);
  bf16_t* wrh1 = (bf16_t*)alloc((size_t)256 * 512 * 2);
  bf16_t* wrh2 = (bf16_t*)alloc((size_t)256 * 512 * 2);
  float* bcAll = (float*)alloc(6 * 512 * 4);   // [l*3+{t,q,a}][512]

  // CSR topology. Order: 0=gr 1=rgr 2=rlt 3=sim 4=comp 5=lt (lt LAST)
  struct Topo { const int* src; const int* dst; int Nd, E; };
  Topo topo[6] = {
    {ei_gr,        ei_gr + E_GR,     NT, E_GR},
    {ei_gr + E_GR, ei_gr,            NQ, E_GR},
    {ei_lt + E_LT, ei_lt,            NT, E_LT},
    {simsrc,       simdst,           NQ, E_SIM + NQ},
    {ei_comp,      ei_comp + E_COMP, NT, E_COMP},
    {ei_lt,        ei_lt + E_LT,     NA, E_LT},
  };
  int *deg[6], *startp[6], *eidx[6];
  for (int r = 0; r < 6; ++r) {
    deg[r]    = (int*)alloc((size_t)topo[r].Nd * 4);
    startp[r] = (int*)alloc((size_t)topo[r].Nd * 4);
    eidx[r]   = (int*)alloc((size_t)topo[r].E * 4);
  }
  int* posb = (int*)alloc((size_t)MAXE * 4);
  int* bsum = (int*)alloc(64 * 4);
  if (off > ws_size) {
    fprintf(stderr, "kernel_launch: ws too small, need %zu have %zu\n", off, ws_size);
    return;
  }

  // --- weight conversion (fp32 [K][M] -> bf16 [M][K]) ---
  convert_wT<<<dim3(512 / 32, 512 / 32, 12), 256, 0, stream>>>(conv_Wl, wl, 512, 512);
  convert_wT<<<dim3(512 / 32, 512 / 32, 12), 256, 0, stream>>>(conv_Wr, wr, 512, 512);
  convert_wT<<<dim3(512 / 32, 384 / 32, 1), 256, 0, stream>>>(qp_W, wqp, 384, 512);
  convert_wT<<<dim3(512 / 32, 384 / 32, 1), 256, 0, stream>>>(tp_W, wtp, 384, 512);
  convert_wT<<<dim3(512 / 32, 384 / 32, 1), 256, 0, stream>>>(ap_W, wap, 384, 512);
  convert_wT<<<dim3(512 / 32, 64 / 32, 1), 256, 0, stream>>>(afp_W2, wafp2, 64, 512);
  convert_wT<<<dim3(256 / 32, 512 / 32, 1), 256, 0, stream>>>(qh_W, wqh, 512, 256);
  convert_wT<<<dim3(256 / 32, 512 / 32, 1), 256, 0, stream>>>(rh_W, wrh0, 512, 256);
  convert_wT<<<dim3(256 / 32, 512 / 32, 1), 256, 0, stream>>>(rh_W + 512 * 256, wrh1, 512, 256);
  convert_wT<<<dim3(256 / 32, 512 / 32, 1), 256, 0, stream>>>(rh_W + 1024 * 256, wrh2, 512, 256);
  combine_bias6<<<(6 * 512 + 255) / 256, 256, 0, stream>>>(conv_bias, bcAll);

  build_sim<<<(E_SIM + NQ + 255) / 256, 256, 0, stream>>>(ei_sim, simsrc, simdst);
  for (int r = 0; r < 6; ++r) {
    const Topo& T = topo[r];
    hipMemsetAsync(deg[r], 0, (size_t)T.Nd * 4, stream);
    csr_hist<<<(T.E + 255) / 256, 256, 0, stream>>>(T.dst, deg[r], posb, T.E);
    int nb = (T.Nd + 1023) / 1024;
    scan1<<<nb, 256, 0, stream>>>(deg[r], startp[r], bsum, T.Nd);
    scan2<<<1, 64, 0, stream>>>(bsum, nb);
    scan3<<<(T.Nd + 255) / 256, 256, 0, stream>>>(startp[r], bsum, T.Nd);
    csr_scatter<<<(T.E + 255) / 256, 256, 0, stream>>>(T.dst, startp[r], posb,
                                                       eidx[r], T.E);
  }

  // single-z launches
  auto gemm1 = [&](const bf16_t* A, const bf16_t* Bt, const float* bias, bf16_t* C,
                   int N_, int K_, int M_, const int* ridx = nullptr) {
    dim3 g(M_ / 256, (N_ + 127) / 128, 1);
    bgemm<bf16_t><<<g, 256, 0, stream>>>(A, Bt, bias, C, ridx, N_,
                                         A, Bt, bias, C, ridx, N_, K_, M_, 0);
  };
  auto gemmf1 = [&](const bf16_t* A, const bf16_t* Bt, const float* bias, float* C,
                    int N_, int K_, int M_, int acc_, const int* ridx = nullptr) {
    dim3 g(M_ / 256, (N_ + 127) / 128, 1);
    bgemm<float><<<g, 256, 0, stream>>>(A, Bt, bias, C, ridx, N_,
                                        A, Bt, bias, C, ridx, N_, K_, M_, acc_);
  };
  // z-paired launches (two independent GEMMs, same K/M/accum/CT)
  auto gemm2 = [&](const bf16_t* A0, const bf16_t* B0, const float* b0, bf16_t* C0, int N0_,
                   const bf16_t* A1, const bf16_t* B1, const float* b1, bf16_t* C1, int N1_,
                   int K_, int M_) {
    int nb0 = (N0_ + 127) / 128, nb1 = (N1_ + 127) / 128;
    dim3 g(M_ / 256, nb0 > nb1 ? nb0 : nb1, 2);
    bgemm<bf16_t><<<g, 256, 0, stream>>>(A0, B0, b0, C0, nullptr, N0_,
                                         A1, B1, b1, C1, nullptr, N1_, K_, M_, 0);
  };
  auto gemmf2 = [&](const bf16_t* A0, const bf16_t* B0, const float* b0, float* C0,
                    const int* r0, int N0_,
                    const bf16_t* A1, const bf16_t* B1, const float* b1, float* C1,
                    const int* r1, int N1_, int K_, int M_) {
    int nb0 = (N0_ + 127) / 128, nb1 = (N1_ + 127) / 128;
    dim3 g(M_ / 256, nb0 > nb1 ? nb0 : nb1, 2);
    bgemm<float><<<g, 256, 0, stream>>>(A0, B0, b0, C0, r0, N0_,
                                        A1, B1, b1, C1, r1, N1_, K_, M_, 0);
  };

  // Input projections: xq separate; xt/xa z-paired (xt->xlb, xa->xrb casts).
  f2bf_vec<<<((long)NQ * 96 + 255) / 256, 256, 0, stream>>>(xq, xlb, (long)NQ * 96);
  gemm1(xlb, wqp, qp_b, hq, NQ, 384, 512);
  f2bf_vec<<<((long)NT * 96 + 255) / 256, 256, 0, stream>>>(xt, xlb, (long)NT * 96);
  f2bf_vec<<<((long)NA * 96 + 255) / 256, 256, 0, stream>>>(xa, xrb, (long)NA * 96);
  gemm2(xlb, wtp, tp_b, ht, NT, xrb, wap, ap_b, ha, NA, 384, 512);

  // Layer loop with ping-pong h buffers; last relation per dst type carries
  // the fused mean+bias+relu (bc != null) and produces the new h in acc.
  bf16_t *hq_i = hq, *ht_i = ht, *hq_o = accq, *ht_o = acct;
  for (int l = 0; l < 2; ++l) {
    const float* bc_t = bcAll + (size_t)(l * 3 + 0) * 512;
    const float* bc_q = bcAll + (size_t)(l * 3 + 1) * 512;
    const float* bc_a = bcAll + (size_t)(l * 3 + 2) * 512;

    struct Rel { const bf16_t* xs; const bf16_t* xd; int Ns, po; bf16_t* acc;
                 int accum; const float* bc; float inv; };
    Rel rels[6] = {
      {hq_i, ht_i, NQ, 0, ht_o, 0, nullptr, 0.f},      // gr
      {ht_i, hq_i, NT, 1, hq_o, 0, nullptr, 0.f},      // rgr
      {ha,   ht_i, NA, 3, ht_o, 1, nullptr, 0.f},      // rlt
      {hq_i, hq_i, NQ, 4, hq_o, 1, bc_q, 0.5f},        // sim (final for q)
      {ht_i, ht_i, NT, 5, ht_o, 1, bc_t, 1.f / 3.f},   // comp (final for t)
      {ht_i, ha,   NT, 2, ha,   0, bc_a, 1.f},         // lt (final for a, in-place)
    };
    for (int r = 0; r < 6; ++r) {
      const Rel& R = rels[r];
      const Topo& T = topo[r];
      size_t po = (size_t)l * 6 + R.po;
      // z-paired: xs@Wl -> xlb  and  xd@Wr -> xrb in one dispatch
      gemm2(R.xs, wl + po * 512 * 512, conv_bl + po * 512, xlb, R.Ns,
            R.xd, wr + po * 512 * 512, conv_br + po * 512, xrb, T.Nd, 512, 512);
      int gb = (T.Nd + 3) / 4;
      gat_fused<<<gb, 256, 0, stream>>>(xlb, xrb, T.src, startp[r], deg[r],
                                        eidx[r], conv_att + po * 512, R.acc,
                                        T.Nd, R.accum, R.bc, R.inv);
    }
    bf16_t* t;
    t = hq_i; hq_i = hq_o; hq_o = t;
    t = ht_i; ht_i = ht_o; ht_o = t;
  }
  // after 2 swaps: hq_i==hq, ht_i==ht; scratch acct/accq free again.

  // Head: gathers fused via ridx; qpre/rpre-first z-paired.
  float* qpre = (float*)acct;
  float* rpre = (float*)xrb;
  bf16_t* afh = accq;
  const int* gsrc = ei_gen;
  const int* gdst = ei_gen + E_GEN;

  gemmf2(hq_i, wqh, qh_b, qpre, gsrc, E_GEN,
         ht_i, wrh0, rh_b, rpre, gdst, E_GEN, 512, 256);    // q_emb | t_emb
  gemmf1(ha, wrh1, nullptr, rpre, E_GEN, 512, 256, 1, gdst); // + a_emb @ rh_W[1]
  af_hidden<<<(E_GEN * 64 + 255) / 256, 256, 0, stream>>>(af, afp_W1, afp_b1,
                                                          afh, E_GEN);
  gemm1(afh, wafp2, afp_b2, xlb, E_GEN, 64, 512);            // af_emb
  gemmf1(xlb, wrh2, nullptr, rpre, E_GEN, 512, 256, 1);      // + af_emb @ rh_W[2]
  head_final<<<(E_GEN + 3) / 4, 256, 0, stream>>>(
      qpre, rpre, qh_g, qh_beta, rh_g, rh_beta, score_b, (float*)d_out, E_GEN);
}

// Round 16
// 1573.210 us; speedup vs baseline: 1.0915x; 1.0224x over previous
//
#include <hip/hip_runtime.h>
#include <cstdio>
#include <type_traits>

#define NQ 10000
#define NT 50000
#define NA 50000
#define E_GR 50000
#define E_LT 50000
#define E_SIM 80000
#define E_COMP 100000
#define E_GEN 50000
#define MAXE 100000
#define NEG_SLOPE 0.2f

typedef unsigned short bf16_t;
typedef unsigned int u32;
typedef __attribute__((ext_vector_type(8))) short short8v;
typedef __attribute__((ext_vector_type(4))) float f32x4;

__device__ __forceinline__ float bf2f(u32 bits) { return __uint_as_float(bits << 16); }
__device__ __forceinline__ u32 f2bf(float f) {
  u32 u = __float_as_uint(f);
  return (u + 0x7FFFu + ((u >> 16) & 1u)) >> 16;   // RTNE
}
__device__ __forceinline__ u32 pack2(float a, float b) { return f2bf(a) | (f2bf(b) << 16); }
__device__ __forceinline__ void unpack8(uint4 u, float* f) {
  f[0] = bf2f(u.x & 0xffffu); f[1] = bf2f(u.x >> 16);
  f[2] = bf2f(u.y & 0xffffu); f[3] = bf2f(u.y >> 16);
  f[4] = bf2f(u.z & 0xffffu); f[5] = bf2f(u.z >> 16);
  f[6] = bf2f(u.w & 0xffffu); f[7] = bf2f(u.w >> 16);
}

// async global->LDS, 16B per lane; LDS dest = wave-uniform base + lane*16.
__device__ __forceinline__ void gload16(const void* g, void* l) {
  __builtin_amdgcn_global_load_lds(
      (const __attribute__((address_space(1))) void*)g,
      (__attribute__((address_space(3))) void*)l, 16, 0, 0);
}

// ---------------------------------------------------------------------------
// MFMA bf16 GEMM, z-paired (r12 banked winner — ~570 TF/GEMM at this shape).
// 128x256 tile, BK=32, 512 threads = 8 waves (2x4), wave tile 64x64,
// acc[4][4]. THREE 24KB buffers (72KB -> 2 blocks/CU), rotation s%3, ONE
// barrier per K-step:
//   stage buf[(s+1)%3] [3 loads/thr] ; vmcnt(3) [drain buf[s] only] ;
//   barrier ; ds_read buf[s] + 16 MFMA ; (no trailing barrier)
// Race safety: writes at step s hit buf[(s+1)%3]; laggard reads from step
// s-1 hit buf[(s-1)%3]; diff 2 mod 3 != 0; rewrite happens two steps later
// behind an intervening barrier.
// Both-sides octet XOR (rule #21): store oct=(c&3)^((row>>1)&3) via
// pre-swizzled global k-octet; read oct=fg^((fr>>1)&3) -> exact 2-way bank
// aliasing (free, m136).
// XCD-grouped band swizzle per z; optional ridx A-row indirection.
// M%256==0, K%32==0; N guarded; early exit uniform (before any barrier).
// ---------------------------------------------------------------------------
template <typename CT>
__global__ __launch_bounds__(512, 4) void bgemm(
    const bf16_t* __restrict__ A0, const bf16_t* __restrict__ Bt0,
    const float* __restrict__ bias0, CT* __restrict__ C0,
    const int* __restrict__ ridx0, int N0,
    const bf16_t* __restrict__ A1, const bf16_t* __restrict__ Bt1,
    const float* __restrict__ bias1, CT* __restrict__ C1,
    const int* __restrict__ ridx1, int N1,
    int K, int M, int accumulate)
{
  __shared__ short lds[3][12288];   // [buf][A: 0..4095 | B: 4096..12287]
  const int z = blockIdx.z;
  const bf16_t* A   = z ? A1 : A0;
  const bf16_t* Bt  = z ? Bt1 : Bt0;
  const float* bias = z ? bias1 : bias0;
  CT* C             = z ? C1 : C0;
  const int* ridx   = z ? ridx1 : ridx0;
  const int N       = z ? N1 : N0;

  const int tid = threadIdx.x;
  const int ncol = gridDim.x;
  const int nband = (N + 127) >> 7;         // per-z band count
  int lin = blockIdx.y * ncol + blockIdx.x;
  if (lin >= ncol * nband) return;          // uniform exit, before barriers

  // XCD-grouping swizzle (wg->XCD = id%8). Bijective incl. tail bands.
  int band, col;
  const int full = (nband >> 3) * 8 * ncol;
  if (lin < full) {
    int g = lin >> 3, x = lin & 7;
    band = x + 8 * (g / ncol);
    col  = g % ncol;
  } else {
    int r = lin - full;
    band = (nband & ~7) + r / ncol;
    col  = r % ncol;
  }
  const int bm = band * 128, bn = col * 256;

  const int lane = tid & 63;
  const int w = tid >> 6;          // 8 waves
  const int wr = w >> 2, wc = w & 3;
  const int fr = lane & 15, fg = lane >> 4;

  // staging: A 512 chunks (1/thread), B 1024 chunks (2/thread).
  // chunk c: row=c>>2, oct=c&3; global k-octet pre-swizzled (rule #21).
  const int kg = (((tid & 3) ^ ((tid >> 3) & 3)) << 3);
  const int rr = tid >> 2;
  int ra = min(bm + rr, N - 1);
  const bf16_t* gA0 = A + (size_t)(ridx ? ridx[ra] : ra) * K + kg;
  const bf16_t* gB0 = Bt + (size_t)(bn + rr) * K + kg;
  const bf16_t* gB1 = Bt + (size_t)(bn + 128 + rr) * K + kg;
  const int wb = w << 9;   // wave-uniform LDS short offset (64 chunks * 8)

  f32x4 acc[4][4];
#pragma unroll
  for (int i = 0; i < 4; ++i)
#pragma unroll
    for (int j = 0; j < 4; ++j) acc[i][j] = (f32x4){0.f, 0.f, 0.f, 0.f};

  auto stage = [&](int buf, int k0) {
    short* base = &lds[buf][0];
    gload16(gA0 + k0, base + wb);                  // A chunk t
    gload16(gB0 + k0, base + 4096 + wb);           // B chunk t
    gload16(gB1 + k0, base + 8192 + wb);           // B chunk t+512
  };

  const int nsteps = K >> 5;
  stage(0, 0);
  const int co = (fg ^ ((fr >> 1) & 3)) << 3;   // read-side XOR octet
  for (int s = 0; s < nsteps; ++s) {
    const int cur = s % 3;
    if (s + 1 < nsteps) {
      stage((s + 1) % 3, (s + 1) << 5);
      asm volatile("s_waitcnt vmcnt(3)" ::: "memory");  // drain buf[cur] only
    } else {
      asm volatile("s_waitcnt vmcnt(0)" ::: "memory");
    }
    __builtin_amdgcn_s_barrier();            // publish buf[cur]
    asm volatile("" ::: "memory");
    const short* LA = &lds[cur][0];
    const short* LB = &lds[cur][4096];
    short8v b[4];
#pragma unroll
    for (int j = 0; j < 4; ++j) {
      int R = wc * 64 + j * 16 + fr;
      b[j] = *(const short8v*)&LB[R * 32 + co];
    }
#pragma unroll
    for (int i = 0; i < 4; ++i) {
      int R = wr * 64 + i * 16 + fr;
      short8v a = *(const short8v*)&LA[R * 32 + co];
#pragma unroll
      for (int j = 0; j < 4; ++j)
        acc[i][j] = __builtin_amdgcn_mfma_f32_16x16x32_bf16(b[j], a,
                                                            acc[i][j], 0, 0, 0);
    }
    asm volatile("" ::: "memory");
    // no trailing barrier: 3-buffer rotation makes it safe (see header)
  }

  // epilogue: D cols (fr) = A rows; D row quad (fg*4+q) = C cols.
  float4 bv[4];
#pragma unroll
  for (int j = 0; j < 4; ++j) {
    bv[j] = make_float4(0.f, 0.f, 0.f, 0.f);
    if (!accumulate && bias)
      bv[j] = *(const float4*)(bias + bn + wc * 64 + j * 16 + fg * 4);
  }
#pragma unroll
  for (int i = 0; i < 4; ++i) {
    const int n = bm + wr * 64 + i * 16 + fr;
    if (n >= N) continue;
#pragma unroll
    for (int j = 0; j < 4; ++j) {
      const int m0 = bn + wc * 64 + j * 16 + fg * 4;
      f32x4 v = acc[i][j];
      if constexpr (std::is_same<CT, float>::value) {
        float* p = C + (size_t)n * M + m0;
        if (accumulate) {
          float4 o = *(float4*)p;
          o.x += v[0]; o.y += v[1]; o.z += v[2]; o.w += v[3];
          *(float4*)p = o;
        } else {
          *(float4*)p = make_float4(v[0] + bv[j].x, v[1] + bv[j].y,
                                    v[2] + bv[j].z, v[3] + bv[j].w);
        }
      } else {
        uint2 o;
        o.x = pack2(v[0] + bv[j].x, v[1] + bv[j].y);
        o.y = pack2(v[2] + bv[j].z, v[3] + bv[j].w);
        *(uint2*)(C + (size_t)n * M + m0) = o;
      }
    }
  }
}

// fp32 W[K][M] -> bf16 Wt[M][K] (transpose), 32x32 LDS tiles, z-batched.
__global__ __launch_bounds__(256) void convert_wT(
    const float* __restrict__ W, bf16_t* __restrict__ Wt, int K, int M)
{
  __shared__ float sm[32][33];
  W  += (size_t)blockIdx.z * K * M;
  Wt += (size_t)blockIdx.z * K * M;
  int mb = blockIdx.x * 32, kb = blockIdx.y * 32;
  int tx = threadIdx.x & 31, ty = threadIdx.x >> 5;
#pragma unroll
  for (int i = 0; i < 4; ++i)
    sm[ty + i * 8][tx] = W[(size_t)(kb + ty + i * 8) * M + mb + tx];
  __syncthreads();
#pragma unroll
  for (int i = 0; i < 4; ++i)
    Wt[(size_t)(mb + ty + i * 8) * K + kb + tx] = (bf16_t)f2bf(sm[tx][ty + i * 8]);
}

// fp32 -> bf16 flat cast, 4 elems/thread
__global__ __launch_bounds__(256) void f2bf_vec(
    const float* __restrict__ in, bf16_t* __restrict__ out, long n4)
{
  long t = (long)blockIdx.x * 256 + threadIdx.x;
  if (t >= n4) return;
  float4 v = ((const float4*)in)[t];
  uint2 o;
  o.x = pack2(v.x, v.y);
  o.y = pack2(v.z, v.w);
  ((uint2*)out)[t] = o;
}

// all six combined bias vectors in one launch.
// bcAll[l*3+0]=bc_t, +1=bc_q, +2=bc_a for layer l. conv_bias is [12][512].
__global__ __launch_bounds__(256) void combine_bias6(
    const float* __restrict__ cb, float* __restrict__ bcAll)
{
  int g = blockIdx.x * 256 + threadIdx.x;
  if (g >= 6 * 512) return;
  int row = g >> 9, j = g & 511;
  int l = row / 3, kind = row % 3;
  const float* b = cb + (size_t)l * 6 * 512;
  float v;
  if (kind == 0)      v = (b[0 * 512 + j] + b[3 * 512 + j] + b[5 * 512 + j]) / 3.f;
  else if (kind == 1) v = (b[1 * 512 + j] + b[4 * 512 + j]) * 0.5f;
  else                v = b[2 * 512 + j];
  bcAll[(size_t)row * 512 + j] = v;
}

// ---------------------------------------------------------------------------
// CSR build: histogram w/ slot assignment, 3-kernel exclusive scan, scatter.
// ---------------------------------------------------------------------------
__global__ __launch_bounds__(256) void csr_hist(
    const int* __restrict__ dst, int* __restrict__ deg, int* __restrict__ pos, int E)
{
  int e = blockIdx.x * 256 + threadIdx.x;
  if (e >= E) return;
  pos[e] = atomicAdd(&deg[dst[e]], 1);
}

__global__ __launch_bounds__(256) void scan1(
    const int* __restrict__ in, int* __restrict__ out, int* __restrict__ bsum, int n)
{
  __shared__ int sm[256];
  int t = threadIdx.x;
  int base = blockIdx.x * 1024 + t * 4;
  int v[4], sum = 0;
#pragma unroll
  for (int k = 0; k < 4; ++k) { v[k] = (base + k < n) ? in[base + k] : 0; sum += v[k]; }
  sm[t] = sum;
  __syncthreads();
  for (int off = 1; off < 256; off <<= 1) {
    int x = (t >= off) ? sm[t - off] : 0;
    __syncthreads();
    sm[t] += x;
    __syncthreads();
  }
  int run = (t > 0) ? sm[t - 1] : 0;
  if (t == 255) bsum[blockIdx.x] = sm[255];
#pragma unroll
  for (int k = 0; k < 4; ++k) {
    if (base + k < n) out[base + k] = run;
    run += v[k];
  }
}

__global__ __launch_bounds__(64) void scan2(int* __restrict__ bsum, int nb)
{
  __shared__ int sm[64];
  int t = threadIdx.x;
  int v = (t < nb) ? bsum[t] : 0;
  sm[t] = v;
  __syncthreads();
  for (int off = 1; off < 64; off <<= 1) {
    int x = (t >= off) ? sm[t - off] : 0;
    __syncthreads();
    sm[t] += x;
    __syncthreads();
  }
  if (t < nb) bsum[t] = sm[t] - v;   // exclusive
}

__global__ __launch_bounds__(256) void scan3(
    int* __restrict__ out, const int* __restrict__ bsum, int n)
{
  int g = blockIdx.x * 256 + threadIdx.x;
  if (g < n) out[g] += bsum[g >> 10];
}

__global__ __launch_bounds__(256) void csr_scatter(
    const int* __restrict__ dst, const int* __restrict__ start,
    const int* __restrict__ pos, int* __restrict__ eidx, int E)
{
  int e = blockIdx.x * 256 + threadIdx.x;
  if (e >= E) return;
  eidx[start[dst[e]] + pos[e]] = e;
}

// ---------------------------------------------------------------------------
// Fused GATv2 message+softmax+aggregate, one wave per dst node, no atomics.
// Wave-uniform fast paths (Poisson-sparse graphs):
//   deg==0 -> output 0 (skip xr/att/edges);
//   deg==1 -> softmax == 1 exactly -> output = xl[src] (skip xr/att/logit/
//             shuffle-reduce/exp).
// If bc != nullptr: also applies HeteroConv-mean + bias + relu (final
// relation for this node type) and writes the NEW h in place of acc.
// ---------------------------------------------------------------------------
__global__ __launch_bounds__(256) void gat_fused(
    const bf16_t* __restrict__ xl, const bf16_t* __restrict__ xr,
    const int* __restrict__ srcArr, const int* __restrict__ start,
    const int* __restrict__ deg, const int* __restrict__ eidx,
    const float* __restrict__ att, bf16_t* __restrict__ acc,
    int Nd, int accumulate, const float* __restrict__ bc, float inv_div)
{
  int d = blockIdx.x * 4 + (threadIdx.x >> 6);
  if (d >= Nd) return;
  int lane = threadIdx.x & 63;

  float acc8[8] = {0.f, 0.f, 0.f, 0.f, 0.f, 0.f, 0.f, 0.f};
  int n = deg[d], s0 = start[d];
  if (n == 1) {
    // alpha == 1 exactly; no logit/softmax needed
    int s = srcArr[eidx[s0]];
    unpack8(*(const uint4*)(xl + (size_t)s * 512 + lane * 8), acc8);
  } else if (n > 1) {
    float xrr[8];
    unpack8(*(const uint4*)(xr + (size_t)d * 512 + lane * 8), xrr);
    float at[8];
    *(float4*)(at)     = *(const float4*)(att + lane * 8);
    *(float4*)(at + 4) = *(const float4*)(att + lane * 8 + 4);
    float den = 0.f;
    for (int i = 0; i < n; ++i) {
      int e = eidx[s0 + i];
      int s = srcArr[e];
      float f[8];
      unpack8(*(const uint4*)(xl + (size_t)s * 512 + lane * 8), f);
      float p = 0.f;
#pragma unroll
      for (int k = 0; k < 8; ++k) {
        float x = f[k] + xrr[k];
        p = fmaf(at[k], x >= 0.f ? x : NEG_SLOPE * x, p);
      }
#pragma unroll
      for (int m = 8; m >= 1; m >>= 1) p += __shfl_xor(p, m);  // 16-lane grp = head
      float ex = __expf(p);
      den += ex;
#pragma unroll
      for (int k = 0; k < 8; ++k) acc8[k] = fmaf(ex, f[k], acc8[k]);
    }
    float inv = 1.f / (den + 1e-16f);
#pragma unroll
    for (int k = 0; k < 8; ++k) acc8[k] *= inv;
  }
  // n == 0: acc8 stays 0 (matches ref: empty segment_sum -> 0)

  bf16_t* out = acc + (size_t)d * 512 + lane * 8;
  if (accumulate) {
    float old[8];
    unpack8(*(const uint4*)out, old);
#pragma unroll
    for (int k = 0; k < 8; ++k) acc8[k] += old[k];
  }
  if (bc) {   // finalize: mean + combined bias + relu
    float bcv[8];
    *(float4*)(bcv)     = *(const float4*)(bc + lane * 8);
    *(float4*)(bcv + 4) = *(const float4*)(bc + lane * 8 + 4);
#pragma unroll
    for (int k = 0; k < 8; ++k)
      acc8[k] = fmaxf(fmaf(acc8[k], inv_div, bcv[k]), 0.f);
  }
  uint4 s;
  s.x = pack2(acc8[0], acc8[1]); s.y = pack2(acc8[2], acc8[3]);
  s.z = pack2(acc8[4], acc8[5]); s.w = pack2(acc8[6], acc8[7]);
  *(uint4*)out = s;
}

// afh = relu(answer_features @ W1 + b1) -> bf16, K=6, M=64
__global__ __launch_bounds__(256) void af_hidden(
    const float* __restrict__ af, const float* __restrict__ W1,
    const float* __restrict__ b1, bf16_t* __restrict__ out, int n)
{
  int t = blockIdx.x * blockDim.x + threadIdx.x;
  if (t >= n * 64) return;
  int i = t >> 6, j = t & 63;
  const float* a = af + (size_t)i * 6;
  float s = b1[j];
#pragma unroll
  for (int k = 0; k < 6; ++k) s = fmaf(a[k], W1[k * 64 + j], s);
  out[t] = (bf16_t)f2bf(fmaxf(s, 0.f));
}

__global__ __launch_bounds__(256) void build_sim(
    const int* __restrict__ ei, int* __restrict__ ss, int* __restrict__ sd)
{
  int t = blockIdx.x * blockDim.x + threadIdx.x;
  if (t >= E_SIM + NQ) return;
  if (t < E_SIM) { ss[t] = ei[t]; sd[t] = ei[E_SIM + t]; }
  else           { ss[t] = t - E_SIM; sd[t] = t - E_SIM; }
}

__global__ __launch_bounds__(256) void head_final(
    const float* __restrict__ qpre, const float* __restrict__ rpre,
    const float* __restrict__ qg, const float* __restrict__ qb,
    const float* __restrict__ rg, const float* __restrict__ rb,
    const float* __restrict__ score_bias, float* __restrict__ out, int E)
{
  int e = blockIdx.x * 4 + (threadIdx.x >> 6);
  if (e >= E) return;
  int lane = threadIdx.x & 63;

  float4 q = *(const float4*)(qpre + (size_t)e * 256 + lane * 4);
  float s = q.x + q.y + q.z + q.w;
#pragma unroll
  for (int m = 32; m >= 1; m >>= 1) s += __shfl_xor(s, m);
  float mu = s * (1.f / 256.f);
  float dq0 = q.x - mu, dq1 = q.y - mu, dq2 = q.z - mu, dq3 = q.w - mu;
  float v = dq0 * dq0 + dq1 * dq1 + dq2 * dq2 + dq3 * dq3;
#pragma unroll
  for (int m = 32; m >= 1; m >>= 1) v += __shfl_xor(v, m);
  float rstd = rsqrtf(v * (1.f / 256.f) + 1e-5f);
  float4 g4 = *(const float4*)(qg + lane * 4);
  float4 b4 = *(const float4*)(qb + lane * 4);
  float qn0 = dq0 * rstd * g4.x + b4.x, qn1 = dq1 * rstd * g4.y + b4.y;
  float qn2 = dq2 * rstd * g4.z + b4.z, qn3 = dq3 * rstd * g4.w + b4.w;

  float4 r = *(const float4*)(rpre + (size_t)e * 256 + lane * 4);
  s = r.x + r.y + r.z + r.w;
#pragma unroll
  for (int m = 32; m >= 1; m >>= 1) s += __shfl_xor(s, m);
  mu = s * (1.f / 256.f);
  float dr0 = r.x - mu, dr1 = r.y - mu, dr2 = r.z - mu, dr3 = r.w - mu;
  v = dr0 * dr0 + dr1 * dr1 + dr2 * dr2 + dr3 * dr3;
#pragma unroll
  for (int m = 32; m >= 1; m >>= 1) v += __shfl_xor(v, m);
  rstd = rsqrtf(v * (1.f / 256.f) + 1e-5f);
  g4 = *(const float4*)(rg + lane * 4);
  b4 = *(const float4*)(rb + lane * 4);
  float rn0 = dr0 * rstd * g4.x + b4.x, rn1 = dr1 * rstd * g4.y + b4.y;
  float rn2 = dr2 * rstd * g4.z + b4.z, rn3 = dr3 * rstd * g4.w + b4.w;

  float d = qn0 * rn0 + qn1 * rn1 + qn2 * rn2 + qn3 * rn3;
#pragma unroll
  for (int m = 32; m >= 1; m >>= 1) d += __shfl_xor(d, m);
  if (lane == 0) out[e] = d * 0.0625f + score_bias[0];
}

// ---------------------------------------------------------------------------
extern "C" void kernel_launch(void* const* d_in, const int* in_sizes, int n_in,
                              void* d_out, int out_size, void* d_ws, size_t ws_size,
                              hipStream_t stream) {
  (void)in_sizes; (void)n_in; (void)out_size;
  const float* xq      = (const float*)d_in[0];
  const float* xt      = (const float*)d_in[1];
  const float* xa      = (const float*)d_in[2];
  const float* af      = (const float*)d_in[3];
  const float* qp_W    = (const float*)d_in[4];
  const float* qp_b    = (const float*)d_in[5];
  const float* tp_W    = (const float*)d_in[6];
  const float* tp_b    = (const float*)d_in[7];
  const float* ap_W    = (const float*)d_in[8];
  const float* ap_b    = (const float*)d_in[9];
  const float* afp_W1  = (const float*)d_in[10];
  const float* afp_b1  = (const float*)d_in[11];
  const float* afp_W2  = (const float*)d_in[12];
  const float* afp_b2  = (const float*)d_in[13];
  const float* conv_Wl = (const float*)d_in[14];
  const float* conv_bl = (const float*)d_in[15];
  const float* conv_Wr = (const float*)d_in[16];
  const float* conv_br = (const float*)d_in[17];
  const float* conv_att  = (const float*)d_in[18];
  const float* conv_bias = (const float*)d_in[19];
  const float* qh_W    = (const float*)d_in[20];
  const float* qh_b    = (const float*)d_in[21];
  const float* qh_g    = (const float*)d_in[22];
  const float* qh_beta = (const float*)d_in[23];
  const float* rh_W    = (const float*)d_in[24];
  const float* rh_b    = (const float*)d_in[25];
  const float* rh_g    = (const float*)d_in[26];
  const float* rh_beta = (const float*)d_in[27];
  const float* score_b = (const float*)d_in[28];
  const int* ei_gr   = (const int*)d_in[29];
  const int* ei_lt   = (const int*)d_in[30];
  const int* ei_sim  = (const int*)d_in[31];
  const int* ei_comp = (const int*)d_in[32];
  const int* ei_gen  = (const int*)d_in[33];

  char* base = (char*)d_ws;
  size_t off = 0;
  auto alloc = [&](size_t bytes) {
    void* p = base + off;
    off = (off + bytes + 255) & ~(size_t)255;
    return p;
  };
  bf16_t* hq   = (bf16_t*)alloc((size_t)NQ * 512 * 2);
  bf16_t* ht   = (bf16_t*)alloc((size_t)NT * 512 * 2);
  bf16_t* ha   = (bf16_t*)alloc((size_t)NA * 512 * 2);
  bf16_t* acct = (bf16_t*)alloc((size_t)NT * 512 * 2);   // ht ping-pong; qpre f32
  bf16_t* accq = (bf16_t*)alloc((size_t)NQ * 512 * 2);   // hq ping-pong; afh bf16
  bf16_t* xlb  = (bf16_t*)alloc((size_t)50000 * 512 * 2);// staging/af_emb
  bf16_t* xrb  = (bf16_t*)alloc((size_t)50000 * 512 * 2);// also rpre f32
  int* simsrc  = (int*)alloc((size_t)(E_SIM + NQ) * 4);
  int* simdst  = (int*)alloc((size_t)(E_SIM + NQ) * 4);

  // bf16-transposed weights
  bf16_t* wqp  = (bf16_t*)alloc((size_t)512 * 384 * 2);
  bf16_t* wtp  = (bf16_t*)alloc((size_t)512 * 384 * 2);
  bf16_t* wap  = (bf16_t*)alloc((size_t)512 * 384 * 2);
  bf16_t* wl   = (bf16_t*)alloc((size_t)12 * 512 * 512 * 2);
  bf16_t* wr   = (bf16_t*)alloc((size_t)12 * 512 * 512 * 2);
  bf16_t* wafp2 = (bf16_t*)alloc((size_t)512 * 64 * 2);
  bf16_t* wqh  = (bf16_t*)alloc((size_t)256 * 512 * 2);
  bf16_t* wrh0 = (bf16_t*)alloc((size_t)256 * 512 * 2);
  bf16_t* wrh1 = (bf16_t*)alloc((size_t)256 * 512 * 2);
  bf16_t* wrh2 = (bf16_t*)alloc((size_t)256 * 512 * 2);
  float* bcAll = (float*)alloc(6 * 512 * 4);   // [l*3+{t,q,a}][512]

  // CSR topology. Order: 0=gr 1=rgr 2=rlt 3=sim 4=comp 5=lt (lt LAST)
  struct Topo { const int* src; const int* dst; int Nd, E; };
  Topo topo[6] = {
    {ei_gr,        ei_gr + E_GR,     NT, E_GR},
    {ei_gr + E_GR, ei_gr,            NQ, E_GR},
    {ei_lt + E_LT, ei_lt,            NT, E_LT},
    {simsrc,       simdst,           NQ, E_SIM + NQ},
    {ei_comp,      ei_comp + E_COMP, NT, E_COMP},
    {ei_lt,        ei_lt + E_LT,     NA, E_LT},
  };
  int *deg[6], *startp[6], *eidx[6];
  for (int r = 0; r < 6; ++r) {
    deg[r]    = (int*)alloc((size_t)topo[r].Nd * 4);
    startp[r] = (int*)alloc((size_t)topo[r].Nd * 4);
    eidx[r]   = (int*)alloc((size_t)topo[r].E * 4);
  }
  int* posb = (int*)alloc((size_t)MAXE * 4);
  int* bsum = (int*)alloc(64 * 4);
  if (off > ws_size) {
    fprintf(stderr, "kernel_launch: ws too small, need %zu have %zu\n", off, ws_size);
    return;
  }

  // --- weight conversion (fp32 [K][M] -> bf16 [M][K]) ---
  convert_wT<<<dim3(512 / 32, 512 / 32, 12), 256, 0, stream>>>(conv_Wl, wl, 512, 512);
  convert_wT<<<dim3(512 / 32, 512 / 32, 12), 256, 0, stream>>>(conv_Wr, wr, 512, 512);
  convert_wT<<<dim3(512 / 32, 384 / 32, 1), 256, 0, stream>>>(qp_W, wqp, 384, 512);
  convert_wT<<<dim3(512 / 32, 384 / 32, 1), 256, 0, stream>>>(tp_W, wtp, 384, 512);
  convert_wT<<<dim3(512 / 32, 384 / 32, 1), 256, 0, stream>>>(ap_W, wap, 384, 512);
  convert_wT<<<dim3(512 / 32, 64 / 32, 1), 256, 0, stream>>>(afp_W2, wafp2, 64, 512);
  convert_wT<<<dim3(256 / 32, 512 / 32, 1), 256, 0, stream>>>(qh_W, wqh, 512, 256);
  convert_wT<<<dim3(256 / 32, 512 / 32, 1), 256, 0, stream>>>(rh_W, wrh0, 512, 256);
  convert_wT<<<dim3(256 / 32, 512 / 32, 1), 256, 0, stream>>>(rh_W + 512 * 256, wrh1, 512, 256);
  convert_wT<<<dim3(256 / 32, 512 / 32, 1), 256, 0, stream>>>(rh_W + 1024 * 256, wrh2, 512, 256);
  combine_bias6<<<(6 * 512 + 255) / 256, 256, 0, stream>>>(conv_bias, bcAll);

  build_sim<<<(E_SIM + NQ + 255) / 256, 256, 0, stream>>>(ei_sim, simsrc, simdst);
  for (int r = 0; r < 6; ++r) {
    const Topo& T = topo[r];
    hipMemsetAsync(deg[r], 0, (size_t)T.Nd * 4, stream);
    csr_hist<<<(T.E + 255) / 256, 256, 0, stream>>>(T.dst, deg[r], posb, T.E);
    int nb = (T.Nd + 1023) / 1024;
    scan1<<<nb, 256, 0, stream>>>(deg[r], startp[r], bsum, T.Nd);
    scan2<<<1, 64, 0, stream>>>(bsum, nb);
    scan3<<<(T.Nd + 255) / 256, 256, 0, stream>>>(startp[r], bsum, T.Nd);
    csr_scatter<<<(T.E + 255) / 256, 256, 0, stream>>>(T.dst, startp[r], posb,
                                                       eidx[r], T.E);
  }

  // single-z launches
  auto gemm1 = [&](const bf16_t* A, const bf16_t* Bt, const float* bias, bf16_t* C,
                   int N_, int K_, int M_, const int* ridx = nullptr) {
    dim3 g(M_ / 256, (N_ + 127) / 128, 1);
    bgemm<bf16_t><<<g, 512, 0, stream>>>(A, Bt, bias, C, ridx, N_,
                                         A, Bt, bias, C, ridx, N_, K_, M_, 0);
  };
  auto gemmf1 = [&](const bf16_t* A, const bf16_t* Bt, const float* bias, float* C,
                    int N_, int K_, int M_, int acc_, const int* ridx = nullptr) {
    dim3 g(M_ / 256, (N_ + 127) / 128, 1);
    bgemm<float><<<g, 512, 0, stream>>>(A, Bt, bias, C, ridx, N_,
                                        A, Bt, bias, C, ridx, N_, K_, M_, acc_);
  };
  // z-paired launches (two independent GEMMs, same K/M/accum/CT)
  auto gemm2 = [&](const bf16_t* A0, const bf16_t* B0, const float* b0, bf16_t* C0, int N0_,
                   const bf16_t* A1, const bf16_t* B1, const float* b1, bf16_t* C1, int N1_,
                   int K_, int M_) {
    int nb0 = (N0_ + 127) / 128, nb1 = (N1_ + 127) / 128;
    dim3 g(M_ / 256, nb0 > nb1 ? nb0 : nb1, 2);
    bgemm<bf16_t><<<g, 512, 0, stream>>>(A0, B0, b0, C0, nullptr, N0_,
                                         A1, B1, b1, C1, nullptr, N1_, K_, M_, 0);
  };
  auto gemmf2 = [&](const bf16_t* A0, const bf16_t* B0, const float* b0, float* C0,
                    const int* r0, int N0_,
                    const bf16_t* A1, const bf16_t* B1, const float* b1, float* C1,
                    const int* r1, int N1_, int K_, int M_) {
    int nb0 = (N0_ + 127) / 128, nb1 = (N1_ + 127) / 128;
    dim3 g(M_ / 256, nb0 > nb1 ? nb0 : nb1, 2);
    bgemm<float><<<g, 512, 0, stream>>>(A0, B0, b0, C0, r0, N0_,
                                        A1, B1, b1, C1, r1, N1_, K_, M_, 0);
  };

  // Input projections: xq separate; xt/xa z-paired (xt->xlb, xa->xrb casts).
  f2bf_vec<<<((long)NQ * 96 + 255) / 256, 256, 0, stream>>>(xq, xlb, (long)NQ * 96);
  gemm1(xlb, wqp, qp_b, hq, NQ, 384, 512);
  f2bf_vec<<<((long)NT * 96 + 255) / 256, 256, 0, stream>>>(xt, xlb, (long)NT * 96);
  f2bf_vec<<<((long)NA * 96 + 255) / 256, 256, 0, stream>>>(xa, xrb, (long)NA * 96);
  gemm2(xlb, wtp, tp_b, ht, NT, xrb, wap, ap_b, ha, NA, 384, 512);

  // Layer loop with ping-pong h buffers; last relation per dst type carries
  // the fused mean+bias+relu (bc != null) and produces the new h in acc.
  bf16_t *hq_i = hq, *ht_i = ht, *hq_o = accq, *ht_o = acct;
  for (int l = 0; l < 2; ++l) {
    const float* bc_t = bcAll + (size_t)(l * 3 + 0) * 512;
    const float* bc_q = bcAll + (size_t)(l * 3 + 1) * 512;
    const float* bc_a = bcAll + (size_t)(l * 3 + 2) * 512;

    struct Rel { const bf16_t* xs; const bf16_t* xd; int Ns, po; bf16_t* acc;
                 int accum; const float* bc; float inv; };
    Rel rels[6] = {
      {hq_i, ht_i, NQ, 0, ht_o, 0, nullptr, 0.f},      // gr
      {ht_i, hq_i, NT, 1, hq_o, 0, nullptr, 0.f},      // rgr
      {ha,   ht_i, NA, 3, ht_o, 1, nullptr, 0.f},      // rlt
      {hq_i, hq_i, NQ, 4, hq_o, 1, bc_q, 0.5f},        // sim (final for q)
      {ht_i, ht_i, NT, 5, ht_o, 1, bc_t, 1.f / 3.f},   // comp (final for t)
      {ht_i, ha,   NT, 2, ha,   0, bc_a, 1.f},         // lt (final for a, in-place)
    };
    for (int r = 0; r < 6; ++r) {
      const Rel& R = rels[r];
      const Topo& T = topo[r];
      size_t po = (size_t)l * 6 + R.po;
      // z-paired: xs@Wl -> xlb  and  xd@Wr -> xrb in one dispatch
      gemm2(R.xs, wl + po * 512 * 512, conv_bl + po * 512, xlb, R.Ns,
            R.xd, wr + po * 512 * 512, conv_br + po * 512, xrb, T.Nd, 512, 512);
      int gb = (T.Nd + 3) / 4;
      gat_fused<<<gb, 256, 0, stream>>>(xlb, xrb, T.src, startp[r], deg[r],
                                        eidx[r], conv_att + po * 512, R.acc,
                                        T.Nd, R.accum, R.bc, R.inv);
    }
    bf16_t* t;
    t = hq_i; hq_i = hq_o; hq_o = t;
    t = ht_i; ht_i = ht_o; ht_o = t;
  }
  // after 2 swaps: hq_i==hq, ht_i==ht; scratch acct/accq free again.

  // Head: gathers fused via ridx; qpre/rpre-first z-paired.
  float* qpre = (float*)acct;
  float* rpre = (float*)xrb;
  bf16_t* afh = accq;
  const int* gsrc = ei_gen;
  const int* gdst = ei_gen + E_GEN;

  gemmf2(hq_i, wqh, qh_b, qpre, gsrc, E_GEN,
         ht_i, wrh0, rh_b, rpre, gdst, E_GEN, 512, 256);    // q_emb | t_emb
  gemmf1(ha, wrh1, nullptr, rpre, E_GEN, 512, 256, 1, gdst); // + a_emb @ rh_W[1]
  af_hidden<<<(E_GEN * 64 + 255) / 256, 256, 0, stream>>>(af, afp_W1, afp_b1,
                                                          afh, E_GEN);
  gemm1(afh, wafp2, afp_b2, xlb, E_GEN, 64, 512);            // af_emb
  gemmf1(xlb, wrh2, nullptr, rpre, E_GEN, 512, 256, 1);      // + af_emb @ rh_W[2]
  head_final<<<(E_GEN + 3) / 4, 256, 0, stream>>>(
      qpre, rpre, qh_g, qh_beta, rh_g, rh_beta, score_b, (float*)d_out, E_GEN);
}

// Round 17
// 1478.870 us; speedup vs baseline: 1.1611x; 1.0638x over previous
//
#include <hip/hip_runtime.h>
#include <cstdio>
#include <type_traits>

#define NQ 10000
#define NT 50000
#define NA 50000
#define E_GR 50000
#define E_LT 50000
#define E_SIM 80000
#define E_COMP 100000
#define E_GEN 50000
#define NEG_SLOPE 0.2f

// Concatenated CSR tables (compile-time). Rel order: gr, rgr, rlt, sim, comp, lt
// Nd:   50000, 10000, 50000, 10000, 50000, 50000  -> NDTOT 220000
// E:    50000, 50000, 50000, 90000,100000, 50000  -> ETOT  390000
#define NDTOT 220000
#define ETOT  390000
__device__ __constant__ const int c_degOff[7]  = {0, 50000, 60000, 110000, 120000, 170000, 220000};
__device__ __constant__ const int c_eOff[7]    = {0, 50000, 100000, 150000, 240000, 340000, 390000};
__device__ __constant__ const int c_nb[6]      = {49, 10, 49, 10, 49, 49};       // scan blocks/rel
__device__ __constant__ const int c_nbOff[7]   = {0, 49, 59, 108, 118, 167, 216};

typedef unsigned short bf16_t;
typedef unsigned int u32;
typedef __attribute__((ext_vector_type(8))) short short8v;
typedef __attribute__((ext_vector_type(4))) float f32x4;

__device__ __forceinline__ float bf2f(u32 bits) { return __uint_as_float(bits << 16); }
__device__ __forceinline__ u32 f2bf(float f) {
  u32 u = __float_as_uint(f);
  return (u + 0x7FFFu + ((u >> 16) & 1u)) >> 16;   // RTNE
}
__device__ __forceinline__ u32 pack2(float a, float b) { return f2bf(a) | (f2bf(b) << 16); }
__device__ __forceinline__ void unpack8(uint4 u, float* f) {
  f[0] = bf2f(u.x & 0xffffu); f[1] = bf2f(u.x >> 16);
  f[2] = bf2f(u.y & 0xffffu); f[3] = bf2f(u.y >> 16);
  f[4] = bf2f(u.z & 0xffffu); f[5] = bf2f(u.z >> 16);
  f[6] = bf2f(u.w & 0xffffu); f[7] = bf2f(u.w >> 16);
}

// async global->LDS, 16B per lane; LDS dest = wave-uniform base + lane*16.
__device__ __forceinline__ void gload16(const void* g, void* l) {
  __builtin_amdgcn_global_load_lds(
      (const __attribute__((address_space(1))) void*)g,
      (__attribute__((address_space(3))) void*)l, 16, 0, 0);
}

// ---------------------------------------------------------------------------
// MFMA bf16 GEMM, z-paired (r12 banked winner — ~570 TF/GEMM at this shape).
// 128x256 tile, BK=32, 512 threads = 8 waves (2x4), wave tile 64x64,
// acc[4][4]. THREE 24KB buffers (72KB -> 2 blocks/CU), rotation s%3, ONE
// barrier per K-step. Race-safe: writes at step s hit buf[(s+1)%3]; laggard
// reads from step s-1 hit buf[(s-1)%3]; diff 2 mod 3 != 0.
// Both-sides octet XOR (rule #21). XCD-grouped band swizzle; optional ridx.
// ---------------------------------------------------------------------------
template <typename CT>
__global__ __launch_bounds__(512, 4) void bgemm(
    const bf16_t* __restrict__ A0, const bf16_t* __restrict__ Bt0,
    const float* __restrict__ bias0, CT* __restrict__ C0,
    const int* __restrict__ ridx0, int N0,
    const bf16_t* __restrict__ A1, const bf16_t* __restrict__ Bt1,
    const float* __restrict__ bias1, CT* __restrict__ C1,
    const int* __restrict__ ridx1, int N1,
    int K, int M, int accumulate)
{
  __shared__ short lds[3][12288];   // [buf][A: 0..4095 | B: 4096..12287]
  const int z = blockIdx.z;
  const bf16_t* A   = z ? A1 : A0;
  const bf16_t* Bt  = z ? Bt1 : Bt0;
  const float* bias = z ? bias1 : bias0;
  CT* C             = z ? C1 : C0;
  const int* ridx   = z ? ridx1 : ridx0;
  const int N       = z ? N1 : N0;

  const int tid = threadIdx.x;
  const int ncol = gridDim.x;
  const int nband = (N + 127) >> 7;
  int lin = blockIdx.y * ncol + blockIdx.x;
  if (lin >= ncol * nband) return;

  int band, col;
  const int full = (nband >> 3) * 8 * ncol;
  if (lin < full) {
    int g = lin >> 3, x = lin & 7;
    band = x + 8 * (g / ncol);
    col  = g % ncol;
  } else {
    int r = lin - full;
    band = (nband & ~7) + r / ncol;
    col  = r % ncol;
  }
  const int bm = band * 128, bn = col * 256;

  const int lane = tid & 63;
  const int w = tid >> 6;
  const int wr = w >> 2, wc = w & 3;
  const int fr = lane & 15, fg = lane >> 4;

  const int kg = (((tid & 3) ^ ((tid >> 3) & 3)) << 3);
  const int rr = tid >> 2;
  int ra = min(bm + rr, N - 1);
  const bf16_t* gA0 = A + (size_t)(ridx ? ridx[ra] : ra) * K + kg;
  const bf16_t* gB0 = Bt + (size_t)(bn + rr) * K + kg;
  const bf16_t* gB1 = Bt + (size_t)(bn + 128 + rr) * K + kg;
  const int wb = w << 9;

  f32x4 acc[4][4];
#pragma unroll
  for (int i = 0; i < 4; ++i)
#pragma unroll
    for (int j = 0; j < 4; ++j) acc[i][j] = (f32x4){0.f, 0.f, 0.f, 0.f};

  auto stage = [&](int buf, int k0) {
    short* base = &lds[buf][0];
    gload16(gA0 + k0, base + wb);
    gload16(gB0 + k0, base + 4096 + wb);
    gload16(gB1 + k0, base + 8192 + wb);
  };

  const int nsteps = K >> 5;
  stage(0, 0);
  const int co = (fg ^ ((fr >> 1) & 3)) << 3;
  for (int s = 0; s < nsteps; ++s) {
    const int cur = s % 3;
    if (s + 1 < nsteps) {
      stage((s + 1) % 3, (s + 1) << 5);
      asm volatile("s_waitcnt vmcnt(3)" ::: "memory");
    } else {
      asm volatile("s_waitcnt vmcnt(0)" ::: "memory");
    }
    __builtin_amdgcn_s_barrier();
    asm volatile("" ::: "memory");
    const short* LA = &lds[cur][0];
    const short* LB = &lds[cur][4096];
    short8v b[4];
#pragma unroll
    for (int j = 0; j < 4; ++j) {
      int R = wc * 64 + j * 16 + fr;
      b[j] = *(const short8v*)&LB[R * 32 + co];
    }
#pragma unroll
    for (int i = 0; i < 4; ++i) {
      int R = wr * 64 + i * 16 + fr;
      short8v a = *(const short8v*)&LA[R * 32 + co];
#pragma unroll
      for (int j = 0; j < 4; ++j)
        acc[i][j] = __builtin_amdgcn_mfma_f32_16x16x32_bf16(b[j], a,
                                                            acc[i][j], 0, 0, 0);
    }
    asm volatile("" ::: "memory");
  }

  float4 bv[4];
#pragma unroll
  for (int j = 0; j < 4; ++j) {
    bv[j] = make_float4(0.f, 0.f, 0.f, 0.f);
    if (!accumulate && bias)
      bv[j] = *(const float4*)(bias + bn + wc * 64 + j * 16 + fg * 4);
  }
#pragma unroll
  for (int i = 0; i < 4; ++i) {
    const int n = bm + wr * 64 + i * 16 + fr;
    if (n >= N) continue;
#pragma unroll
    for (int j = 0; j < 4; ++j) {
      const int m0 = bn + wc * 64 + j * 16 + fg * 4;
      f32x4 v = acc[i][j];
      if constexpr (std::is_same<CT, float>::value) {
        float* p = C + (size_t)n * M + m0;
        if (accumulate) {
          float4 o = *(float4*)p;
          o.x += v[0]; o.y += v[1]; o.z += v[2]; o.w += v[3];
          *(float4*)p = o;
        } else {
          *(float4*)p = make_float4(v[0] + bv[j].x, v[1] + bv[j].y,
                                    v[2] + bv[j].z, v[3] + bv[j].w);
        }
      } else {
        uint2 o;
        o.x = pack2(v[0] + bv[j].x, v[1] + bv[j].y);
        o.y = pack2(v[2] + bv[j].z, v[3] + bv[j].w);
        *(uint2*)(C + (size_t)n * M + m0) = o;
      }
    }
  }
}

// fp32 W[K][M] -> bf16 Wt[M][K] (transpose), 32x32 LDS tiles, z-batched.
__global__ __launch_bounds__(256) void convert_wT(
    const float* __restrict__ W, bf16_t* __restrict__ Wt, int K, int M)
{
  __shared__ float sm[32][33];
  W  += (size_t)blockIdx.z * K * M;
  Wt += (size_t)blockIdx.z * K * M;
  int mb = blockIdx.x * 32, kb = blockIdx.y * 32;
  int tx = threadIdx.x & 31, ty = threadIdx.x >> 5;
#pragma unroll
  for (int i = 0; i < 4; ++i)
    sm[ty + i * 8][tx] = W[(size_t)(kb + ty + i * 8) * M + mb + tx];
  __syncthreads();
#pragma unroll
  for (int i = 0; i < 4; ++i)
    Wt[(size_t)(mb + ty + i * 8) * K + kb + tx] = (bf16_t)f2bf(sm[tx][ty + i * 8]);
}

// fp32 -> bf16 flat cast, 4 elems/thread
__global__ __launch_bounds__(256) void f2bf_vec(
    const float* __restrict__ in, bf16_t* __restrict__ out, long n4)
{
  long t = (long)blockIdx.x * 256 + threadIdx.x;
  if (t >= n4) return;
  float4 v = ((const float4*)in)[t];
  uint2 o;
  o.x = pack2(v.x, v.y);
  o.y = pack2(v.z, v.w);
  ((uint2*)out)[t] = o;
}

// all six combined bias vectors in one launch.
__global__ __launch_bounds__(256) void combine_bias6(
    const float* __restrict__ cb, float* __restrict__ bcAll)
{
  int g = blockIdx.x * 256 + threadIdx.x;
  if (g >= 6 * 512) return;
  int row = g >> 9, j = g & 511;
  int l = row / 3, kind = row % 3;
  const float* b = cb + (size_t)l * 6 * 512;
  float v;
  if (kind == 0)      v = (b[0 * 512 + j] + b[3 * 512 + j] + b[5 * 512 + j]) / 3.f;
  else if (kind == 1) v = (b[1 * 512 + j] + b[4 * 512 + j]) * 0.5f;
  else                v = b[2 * 512 + j];
  bcAll[(size_t)row * 512 + j] = v;
}

// ---------------------------------------------------------------------------
// Fused CSR build over all 6 relations (compile-time range tables).
// ---------------------------------------------------------------------------
__device__ __forceinline__ int find_rel(int g, const int* off) {
  int r = 0;
#pragma unroll
  for (int k = 1; k < 6; ++k) r += (g >= off[k]);
  return r;
}

__global__ __launch_bounds__(256) void hist6(
    const int* __restrict__ d0, const int* __restrict__ d1,
    const int* __restrict__ d2, const int* __restrict__ d3,
    const int* __restrict__ d4, const int* __restrict__ d5,
    int* __restrict__ degAll, int* __restrict__ pos)
{
  int g = blockIdx.x * 256 + threadIdx.x;
  if (g >= ETOT) return;
  int r = find_rel(g, c_eOff);
  int le = g - c_eOff[r];
  const int* dp = r == 0 ? d0 : r == 1 ? d1 : r == 2 ? d2 : r == 3 ? d3
                : r == 4 ? d4 : d5;
  pos[g] = atomicAdd(&degAll[c_degOff[r] + dp[le]], 1);
}

// per-relation exclusive scan, 1024 items/block; 216 blocks total.
__global__ __launch_bounds__(256) void scan1_6(
    const int* __restrict__ in, int* __restrict__ out, int* __restrict__ bsum)
{
  __shared__ int sm[256];
  int b = blockIdx.x;
  int r = 0;
#pragma unroll
  for (int k = 1; k < 6; ++k) r += (b >= c_nbOff[k]);
  int lb = b - c_nbOff[r];
  int base0 = c_degOff[r], n = c_degOff[r + 1] - base0;
  int t = threadIdx.x;
  int base = lb * 1024 + t * 4;
  int v[4], sum = 0;
#pragma unroll
  for (int k = 0; k < 4; ++k) {
    v[k] = (base + k < n) ? in[base0 + base + k] : 0;
    sum += v[k];
  }
  sm[t] = sum;
  __syncthreads();
  for (int off = 1; off < 256; off <<= 1) {
    int x = (t >= off) ? sm[t - off] : 0;
    __syncthreads();
    sm[t] += x;
    __syncthreads();
  }
  int run = (t > 0) ? sm[t - 1] : 0;
  if (t == 255) bsum[r * 64 + lb] = sm[255];
#pragma unroll
  for (int k = 0; k < 4; ++k) {
    if (base + k < n) out[base0 + base + k] = run;
    run += v[k];
  }
}

__global__ __launch_bounds__(64) void scan2_6(int* __restrict__ bsum)
{
  __shared__ int sm[64];
  int r = blockIdx.x;
  int nb = c_nb[r];
  int t = threadIdx.x;
  int v = (t < nb) ? bsum[r * 64 + t] : 0;
  sm[t] = v;
  __syncthreads();
  for (int off = 1; off < 64; off <<= 1) {
    int x = (t >= off) ? sm[t - off] : 0;
    __syncthreads();
    sm[t] += x;
    __syncthreads();
  }
  if (t < nb) bsum[r * 64 + t] = sm[t] - v;   // exclusive
}

__global__ __launch_bounds__(256) void scan3_6(
    int* __restrict__ out, const int* __restrict__ bsum)
{
  int g = blockIdx.x * 256 + threadIdx.x;
  if (g >= NDTOT) return;
  int r = find_rel(g, c_degOff);
  int ln = g - c_degOff[r];
  out[g] += bsum[r * 64 + (ln >> 10)];
}

__global__ __launch_bounds__(256) void scatter6(
    const int* __restrict__ d0, const int* __restrict__ d1,
    const int* __restrict__ d2, const int* __restrict__ d3,
    const int* __restrict__ d4, const int* __restrict__ d5,
    const int* __restrict__ startAll, const int* __restrict__ pos,
    int* __restrict__ eidxAll)
{
  int g = blockIdx.x * 256 + threadIdx.x;
  if (g >= ETOT) return;
  int r = find_rel(g, c_eOff);
  int le = g - c_eOff[r];
  const int* dp = r == 0 ? d0 : r == 1 ? d1 : r == 2 ? d2 : r == 3 ? d3
                : r == 4 ? d4 : d5;
  eidxAll[c_eOff[r] + startAll[c_degOff[r] + dp[le]] + pos[g]] = le;
}

// ---------------------------------------------------------------------------
// Fused GATv2 message+softmax+aggregate, one wave per dst node, no atomics.
// deg==0 -> 0; deg==1 -> alpha==1 -> output = xl[src].
// Edge-index software pipelining breaks the eidx->src->row dependent chain.
// ---------------------------------------------------------------------------
__global__ __launch_bounds__(256) void gat_fused(
    const bf16_t* __restrict__ xl, const bf16_t* __restrict__ xr,
    const int* __restrict__ srcArr, const int* __restrict__ start,
    const int* __restrict__ deg, const int* __restrict__ eidx,
    const float* __restrict__ att, bf16_t* __restrict__ acc,
    int Nd, int accumulate, const float* __restrict__ bc, float inv_div)
{
  int d = blockIdx.x * 4 + (threadIdx.x >> 6);
  if (d >= Nd) return;
  int lane = threadIdx.x & 63;

  float acc8[8] = {0.f, 0.f, 0.f, 0.f, 0.f, 0.f, 0.f, 0.f};
  int n = deg[d], s0 = start[d];
  if (n == 1) {
    int s = srcArr[eidx[s0]];
    unpack8(*(const uint4*)(xl + (size_t)s * 512 + lane * 8), acc8);
  } else if (n > 1) {
    float xrr[8];
    unpack8(*(const uint4*)(xr + (size_t)d * 512 + lane * 8), xrr);
    float at[8];
    *(float4*)(at)     = *(const float4*)(att + lane * 8);
    *(float4*)(at + 4) = *(const float4*)(att + lane * 8 + 4);
    float den = 0.f;
    int sN = srcArr[eidx[s0]];            // prefetched index chain
    for (int i = 0; i < n; ++i) {
      int s = sN;
      if (i + 1 < n) sN = srcArr[eidx[s0 + i + 1]];
      float f[8];
      unpack8(*(const uint4*)(xl + (size_t)s * 512 + lane * 8), f);
      float p = 0.f;
#pragma unroll
      for (int k = 0; k < 8; ++k) {
        float x = f[k] + xrr[k];
        p = fmaf(at[k], x >= 0.f ? x : NEG_SLOPE * x, p);
      }
#pragma unroll
      for (int m = 8; m >= 1; m >>= 1) p += __shfl_xor(p, m);
      float ex = __expf(p);
      den += ex;
#pragma unroll
      for (int k = 0; k < 8; ++k) acc8[k] = fmaf(ex, f[k], acc8[k]);
    }
    float inv = 1.f / (den + 1e-16f);
#pragma unroll
    for (int k = 0; k < 8; ++k) acc8[k] *= inv;
  }

  bf16_t* out = acc + (size_t)d * 512 + lane * 8;
  if (accumulate) {
    float old[8];
    unpack8(*(const uint4*)out, old);
#pragma unroll
    for (int k = 0; k < 8; ++k) acc8[k] += old[k];
  }
  if (bc) {
    float bcv[8];
    *(float4*)(bcv)     = *(const float4*)(bc + lane * 8);
    *(float4*)(bcv + 4) = *(const float4*)(bc + lane * 8 + 4);
#pragma unroll
    for (int k = 0; k < 8; ++k)
      acc8[k] = fmaxf(fmaf(acc8[k], inv_div, bcv[k]), 0.f);
  }
  uint4 s;
  s.x = pack2(acc8[0], acc8[1]); s.y = pack2(acc8[2], acc8[3]);
  s.z = pack2(acc8[4], acc8[5]); s.w = pack2(acc8[6], acc8[7]);
  *(uint4*)out = s;
}

// afh = relu(answer_features @ W1 + b1) -> bf16, K=6, M=64
__global__ __launch_bounds__(256) void af_hidden(
    const float* __restrict__ af, const float* __restrict__ W1,
    const float* __restrict__ b1, bf16_t* __restrict__ out, int n)
{
  int t = blockIdx.x * blockDim.x + threadIdx.x;
  if (t >= n * 64) return;
  int i = t >> 6, j = t & 63;
  const float* a = af + (size_t)i * 6;
  float s = b1[j];
#pragma unroll
  for (int k = 0; k < 6; ++k) s = fmaf(a[k], W1[k * 64 + j], s);
  out[t] = (bf16_t)f2bf(fmaxf(s, 0.f));
}

__global__ __launch_bounds__(256) void build_sim(
    const int* __restrict__ ei, int* __restrict__ ss, int* __restrict__ sd)
{
  int t = blockIdx.x * blockDim.x + threadIdx.x;
  if (t >= E_SIM + NQ) return;
  if (t < E_SIM) { ss[t] = ei[t]; sd[t] = ei[E_SIM + t]; }
  else           { ss[t] = t - E_SIM; sd[t] = t - E_SIM; }
}

__global__ __launch_bounds__(256) void head_final(
    const float* __restrict__ qpre, const float* __restrict__ rpre,
    const float* __restrict__ qg, const float* __restrict__ qb,
    const float* __restrict__ rg, const float* __restrict__ rb,
    const float* __restrict__ score_bias, float* __restrict__ out, int E)
{
  int e = blockIdx.x * 4 + (threadIdx.x >> 6);
  if (e >= E) return;
  int lane = threadIdx.x & 63;

  float4 q = *(const float4*)(qpre + (size_t)e * 256 + lane * 4);
  float s = q.x + q.y + q.z + q.w;
#pragma unroll
  for (int m = 32; m >= 1; m >>= 1) s += __shfl_xor(s, m);
  float mu = s * (1.f / 256.f);
  float dq0 = q.x - mu, dq1 = q.y - mu, dq2 = q.z - mu, dq3 = q.w - mu;
  float v = dq0 * dq0 + dq1 * dq1 + dq2 * dq2 + dq3 * dq3;
#pragma unroll
  for (int m = 32; m >= 1; m >>= 1) v += __shfl_xor(v, m);
  float rstd = rsqrtf(v * (1.f / 256.f) + 1e-5f);
  float4 g4 = *(const float4*)(qg + lane * 4);
  float4 b4 = *(const float4*)(qb + lane * 4);
  float qn0 = dq0 * rstd * g4.x + b4.x, qn1 = dq1 * rstd * g4.y + b4.y;
  float qn2 = dq2 * rstd * g4.z + b4.z, qn3 = dq3 * rstd * g4.w + b4.w;

  float4 r = *(const float4*)(rpre + (size_t)e * 256 + lane * 4);
  s = r.x + r.y + r.z + r.w;
#pragma unroll
  for (int m = 32; m >= 1; m >>= 1) s += __shfl_xor(s, m);
  mu = s * (1.f / 256.f);
  float dr0 = r.x - mu, dr1 = r.y - mu, dr2 = r.z - mu, dr3 = r.w - mu;
  v = dr0 * dr0 + dr1 * dr1 + dr2 * dr2 + dr3 * dr3;
#pragma unroll
  for (int m = 32; m >= 1; m >>= 1) v += __shfl_xor(v, m);
  rstd = rsqrtf(v * (1.f / 256.f) + 1e-5f);
  g4 = *(const float4*)(rg + lane * 4);
  b4 = *(const float4*)(rb + lane * 4);
  float rn0 = dr0 * rstd * g4.x + b4.x, rn1 = dr1 * rstd * g4.y + b4.y;
  float rn2 = dr2 * rstd * g4.z + b4.z, rn3 = dr3 * rstd * g4.w + b4.w;

  float d = qn0 * rn0 + qn1 * rn1 + qn2 * rn2 + qn3 * rn3;
#pragma unroll
  for (int m = 32; m >= 1; m >>= 1) d += __shfl_xor(d, m);
  if (lane == 0) out[e] = d * 0.0625f + score_bias[0];
}

// ---------------------------------------------------------------------------
extern "C" void kernel_launch(void* const* d_in, const int* in_sizes, int n_in,
                              void* d_out, int out_size, void* d_ws, size_t ws_size,
                              hipStream_t stream) {
  (void)in_sizes; (void)n_in; (void)out_size;
  const float* xq      = (const float*)d_in[0];
  const float* xt      = (const float*)d_in[1];
  const float* xa      = (const float*)d_in[2];
  const float* af      = (const float*)d_in[3];
  const float* qp_W    = (const float*)d_in[4];
  const float* qp_b    = (const float*)d_in[5];
  const float* tp_W    = (const float*)d_in[6];
  const float* tp_b    = (const float*)d_in[7];
  const float* ap_W    = (const float*)d_in[8];
  const float* ap_b    = (const float*)d_in[9];
  const float* afp_W1  = (const float*)d_in[10];
  const float* afp_b1  = (const float*)d_in[11];
  const float* afp_W2  = (const float*)d_in[12];
  const float* afp_b2  = (const float*)d_in[13];
  const float* conv_Wl = (const float*)d_in[14];
  const float* conv_bl = (const float*)d_in[15];
  const float* conv_Wr = (const float*)d_in[16];
  const float* conv_br = (const float*)d_in[17];
  const float* conv_att  = (const float*)d_in[18];
  const float* conv_bias = (const float*)d_in[19];
  const float* qh_W    = (const float*)d_in[20];
  const float* qh_b    = (const float*)d_in[21];
  const float* qh_g    = (const float*)d_in[22];
  const float* qh_beta = (const float*)d_in[23];
  const float* rh_W    = (const float*)d_in[24];
  const float* rh_b    = (const float*)d_in[25];
  const float* rh_g    = (const float*)d_in[26];
  const float* rh_beta = (const float*)d_in[27];
  const float* score_b = (const float*)d_in[28];
  const int* ei_gr   = (const int*)d_in[29];
  const int* ei_lt   = (const int*)d_in[30];
  const int* ei_sim  = (const int*)d_in[31];
  const int* ei_comp = (const int*)d_in[32];
  const int* ei_gen  = (const int*)d_in[33];

  char* base = (char*)d_ws;
  size_t off = 0;
  auto alloc = [&](size_t bytes) {
    void* p = base + off;
    off = (off + bytes + 255) & ~(size_t)255;
    return p;
  };
  bf16_t* hq   = (bf16_t*)alloc((size_t)NQ * 512 * 2);
  bf16_t* ht   = (bf16_t*)alloc((size_t)NT * 512 * 2);
  bf16_t* ha   = (bf16_t*)alloc((size_t)NA * 512 * 2);
  bf16_t* acct = (bf16_t*)alloc((size_t)NT * 512 * 2);   // ht ping-pong; qpre f32
  bf16_t* accq = (bf16_t*)alloc((size_t)NQ * 512 * 2);   // hq ping-pong; afh bf16
  bf16_t* xlb  = (bf16_t*)alloc((size_t)50000 * 512 * 2);// staging/af_emb
  bf16_t* xrb  = (bf16_t*)alloc((size_t)50000 * 512 * 2);// also rpre f32
  int* simsrc  = (int*)alloc((size_t)(E_SIM + NQ) * 4);
  int* simdst  = (int*)alloc((size_t)(E_SIM + NQ) * 4);

  // bf16-transposed weights
  bf16_t* wqp  = (bf16_t*)alloc((size_t)512 * 384 * 2);
  bf16_t* wtp  = (bf16_t*)alloc((size_t)512 * 384 * 2);
  bf16_t* wap  = (bf16_t*)alloc((size_t)512 * 384 * 2);
  bf16_t* wl   = (bf16_t*)alloc((size_t)12 * 512 * 512 * 2);
  bf16_t* wr   = (bf16_t*)alloc((size_t)12 * 512 * 512 * 2);
  bf16_t* wafp2 = (bf16_t*)alloc((size_t)512 * 64 * 2);
  bf16_t* wqh  = (bf16_t*)alloc((size_t)256 * 512 * 2);
  bf16_t* wrh0 = (bf16_t*)alloc((size_t)256 * 512 * 2);  // wrh0..2 contiguous
  bf16_t* wrh1 = (bf16_t*)alloc((size_t)256 * 512 * 2);
  bf16_t* wrh2 = (bf16_t*)alloc((size_t)256 * 512 * 2);
  float* bcAll = (float*)alloc(6 * 512 * 4);

  // Fused CSR arrays (concatenated per compile-time tables)
  int* degAll   = (int*)alloc((size_t)NDTOT * 4);
  int* startAll = (int*)alloc((size_t)NDTOT * 4);
  int* eidxAll  = (int*)alloc((size_t)ETOT * 4);
  int* posb     = (int*)alloc((size_t)ETOT * 4);
  int* bsum     = (int*)alloc(6 * 64 * 4);
  if (off > ws_size) {
    fprintf(stderr, "kernel_launch: ws too small, need %zu have %zu\n", off, ws_size);
    return;
  }

  // host-side copies of the tables (match device constants)
  const int degOff[6] = {0, 50000, 60000, 110000, 120000, 170000};
  const int eOff[6]   = {0, 50000, 100000, 150000, 240000, 340000};

  // --- weight conversion ---
  convert_wT<<<dim3(512 / 32, 512 / 32, 12), 256, 0, stream>>>(conv_Wl, wl, 512, 512);
  convert_wT<<<dim3(512 / 32, 512 / 32, 12), 256, 0, stream>>>(conv_Wr, wr, 512, 512);
  convert_wT<<<dim3(512 / 32, 384 / 32, 1), 256, 0, stream>>>(qp_W, wqp, 384, 512);
  convert_wT<<<dim3(512 / 32, 384 / 32, 1), 256, 0, stream>>>(tp_W, wtp, 384, 512);
  convert_wT<<<dim3(512 / 32, 384 / 32, 1), 256, 0, stream>>>(ap_W, wap, 384, 512);
  convert_wT<<<dim3(512 / 32, 64 / 32, 1), 256, 0, stream>>>(afp_W2, wafp2, 64, 512);
  convert_wT<<<dim3(256 / 32, 512 / 32, 1), 256, 0, stream>>>(qh_W, wqh, 512, 256);
  convert_wT<<<dim3(256 / 32, 512 / 32, 3), 256, 0, stream>>>(rh_W, wrh0, 512, 256);
  combine_bias6<<<(6 * 512 + 255) / 256, 256, 0, stream>>>(conv_bias, bcAll);

  // --- fused CSR build ---
  build_sim<<<(E_SIM + NQ + 255) / 256, 256, 0, stream>>>(ei_sim, simsrc, simdst);
  const int* dsts[6] = {ei_gr + E_GR, ei_gr, ei_lt, simdst,
                        ei_comp + E_COMP, ei_lt + E_LT};
  hipMemsetAsync(degAll, 0, (size_t)NDTOT * 4, stream);
  hist6<<<(ETOT + 255) / 256, 256, 0, stream>>>(dsts[0], dsts[1], dsts[2],
      dsts[3], dsts[4], dsts[5], degAll, posb);
  scan1_6<<<216, 256, 0, stream>>>(degAll, startAll, bsum);
  scan2_6<<<6, 64, 0, stream>>>(bsum);
  scan3_6<<<(NDTOT + 255) / 256, 256, 0, stream>>>(startAll, bsum);
  scatter6<<<(ETOT + 255) / 256, 256, 0, stream>>>(dsts[0], dsts[1], dsts[2],
      dsts[3], dsts[4], dsts[5], startAll, posb, eidxAll);

  // single-z launches
  auto gemm1 = [&](const bf16_t* A, const bf16_t* Bt, const float* bias, bf16_t* C,
                   int N_, int K_, int M_, const int* ridx = nullptr) {
    dim3 g(M_ / 256, (N_ + 127) / 128, 1);
    bgemm<bf16_t><<<g, 512, 0, stream>>>(A, Bt, bias, C, ridx, N_,
                                         A, Bt, bias, C, ridx, N_, K_, M_, 0);
  };
  auto gemmf1 = [&](const bf16_t* A, const bf16_t* Bt, const float* bias, float* C,
                    int N_, int K_, int M_, int acc_, const int* ridx = nullptr) {
    dim3 g(M_ / 256, (N_ + 127) / 128, 1);
    bgemm<float><<<g, 512, 0, stream>>>(A, Bt, bias, C, ridx, N_,
                                        A, Bt, bias, C, ridx, N_, K_, M_, acc_);
  };
  auto gemm2 = [&](const bf16_t* A0, const bf16_t* B0, const float* b0, bf16_t* C0, int N0_,
                   const bf16_t* A1, const bf16_t* B1, const float* b1, bf16_t* C1, int N1_,
                   int K_, int M_) {
    int nb0 = (N0_ + 127) / 128, nb1 = (N1_ + 127) / 128;
    dim3 g(M_ / 256, nb0 > nb1 ? nb0 : nb1, 2);
    bgemm<bf16_t><<<g, 512, 0, stream>>>(A0, B0, b0, C0, nullptr, N0_,
                                         A1, B1, b1, C1, nullptr, N1_, K_, M_, 0);
  };
  auto gemmf2 = [&](const bf16_t* A0, const bf16_t* B0, const float* b0, float* C0,
                    const int* r0, int N0_,
                    const bf16_t* A1, const bf16_t* B1, const float* b1, float* C1,
                    const int* r1, int N1_, int K_, int M_) {
    int nb0 = (N0_ + 127) / 128, nb1 = (N1_ + 127) / 128;
    dim3 g(M_ / 256, nb0 > nb1 ? nb0 : nb1, 2);
    bgemm<float><<<g, 512, 0, stream>>>(A0, B0, b0, C0, r0, N0_,
                                        A1, B1, b1, C1, r1, N1_, K_, M_, 0);
  };

  // Input projections
  f2bf_vec<<<((long)NQ * 96 + 255) / 256, 256, 0, stream>>>(xq, xlb, (long)NQ * 96);
  gemm1(xlb, wqp, qp_b, hq, NQ, 384, 512);
  f2bf_vec<<<((long)NT * 96 + 255) / 256, 256, 0, stream>>>(xt, xlb, (long)NT * 96);
  f2bf_vec<<<((long)NA * 96 + 255) / 256, 256, 0, stream>>>(xa, xrb, (long)NA * 96);
  gemm2(xlb, wtp, tp_b, ht, NT, xrb, wap, ap_b, ha, NA, 384, 512);

  // Layer loop with ping-pong h buffers; final relation per dst type carries
  // the fused mean+bias+relu and produces the new h in acc.
  // Rel order (CSR index r): 0=gr 1=rgr 2=rlt 3=sim 4=comp 5=lt
  const int* srcs[6] = {ei_gr, ei_gr + E_GR, ei_lt + E_LT, simsrc,
                        ei_comp, ei_lt};
  const int NdArr[6] = {NT, NQ, NT, NQ, NT, NA};
  bf16_t *hq_i = hq, *ht_i = ht, *hq_o = accq, *ht_o = acct;
  for (int l = 0; l < 2; ++l) {
    const float* bc_t = bcAll + (size_t)(l * 3 + 0) * 512;
    const float* bc_q = bcAll + (size_t)(l * 3 + 1) * 512;
    const float* bc_a = bcAll + (size_t)(l * 3 + 2) * 512;

    struct Rel { const bf16_t* xs; const bf16_t* xd; int Ns, po; bf16_t* acc;
                 int accum; const float* bc; float inv; };
    Rel rels[6] = {
      {hq_i, ht_i, NQ, 0, ht_o, 0, nullptr, 0.f},      // gr
      {ht_i, hq_i, NT, 1, hq_o, 0, nullptr, 0.f},      // rgr
      {ha,   ht_i, NA, 3, ht_o, 1, nullptr, 0.f},      // rlt
      {hq_i, hq_i, NQ, 4, hq_o, 1, bc_q, 0.5f},        // sim (final for q)
      {ht_i, ht_i, NT, 5, ht_o, 1, bc_t, 1.f / 3.f},   // comp (final for t)
      {ht_i, ha,   NT, 2, ha,   0, bc_a, 1.f},         // lt (final for a)
    };
    for (int r = 0; r < 6; ++r) {
      const Rel& R = rels[r];
      int Nd_ = NdArr[r];
      size_t po = (size_t)l * 6 + R.po;
      gemm2(R.xs, wl + po * 512 * 512, conv_bl + po * 512, xlb, R.Ns,
            R.xd, wr + po * 512 * 512, conv_br + po * 512, xrb, Nd_, 512, 512);
      int gb = (Nd_ + 3) / 4;
      gat_fused<<<gb, 256, 0, stream>>>(xlb, xrb, srcs[r],
                                        startAll + degOff[r], degAll + degOff[r],
                                        eidxAll + eOff[r], conv_att + po * 512,
                                        R.acc, Nd_, R.accum, R.bc, R.inv);
    }
    bf16_t* t;
    t = hq_i; hq_i = hq_o; hq_o = t;
    t = ht_i; ht_i = ht_o; ht_o = t;
  }

  // Head: gathers fused via ridx; qpre/rpre-first z-paired.
  float* qpre = (float*)acct;
  float* rpre = (float*)xrb;
  bf16_t* afh = accq;
  const int* gsrc = ei_gen;
  const int* gdst = ei_gen + E_GEN;

  gemmf2(hq_i, wqh, qh_b, qpre, gsrc, E_GEN,
         ht_i, wrh0, rh_b, rpre, gdst, E_GEN, 512, 256);    // q_emb | t_emb
  gemmf1(ha, wrh1, nullptr, rpre, E_GEN, 512, 256, 1, gdst); // + a_emb
  af_hidden<<<(E_GEN * 64 + 255) / 256, 256, 0, stream>>>(af, afp_W1, afp_b1,
                                                          afh, E_GEN);
  gemm1(afh, wafp2, afp_b2, xlb, E_GEN, 64, 512);            // af_emb
  gemmf1(xlb, wrh2, nullptr, rpre, E_GEN, 512, 256, 1);      // + af_emb
  head_final<<<(E_GEN + 3) / 4, 256, 0, stream>>>(
      qpre, rpre, qh_g, qh_beta, rh_g, rh_beta, score_b, (float*)d_out, E_GEN);
}

// Round 18
// 1471.897 us; speedup vs baseline: 1.1666x; 1.0047x over previous
//
#include <hip/hip_runtime.h>
#include <cstdio>
#include <type_traits>

#define NQ 10000
#define NT 50000
#define NA 50000
#define E_GR 50000
#define E_LT 50000
#define E_SIM 80000
#define E_COMP 100000
#define E_GEN 50000
#define NEG_SLOPE 0.2f

// Concatenated CSR tables (compile-time). Rel order: gr, rgr, rlt, sim, comp, lt
#define NDTOT 220000
#define ETOT  390000
__device__ __constant__ const int c_degOff[7]  = {0, 50000, 60000, 110000, 120000, 170000, 220000};
__device__ __constant__ const int c_eOff[7]    = {0, 50000, 100000, 150000, 240000, 340000, 390000};
__device__ __constant__ const int c_nb[6]      = {49, 10, 49, 10, 49, 49};
__device__ __constant__ const int c_nbOff[7]   = {0, 49, 59, 108, 118, 167, 216};

typedef unsigned short bf16_t;
typedef unsigned int u32;
typedef __attribute__((ext_vector_type(8))) short short8v;
typedef __attribute__((ext_vector_type(4))) float f32x4;

__device__ __forceinline__ float bf2f(u32 bits) { return __uint_as_float(bits << 16); }
__device__ __forceinline__ u32 f2bf(float f) {
  u32 u = __float_as_uint(f);
  return (u + 0x7FFFu + ((u >> 16) & 1u)) >> 16;   // RTNE
}
__device__ __forceinline__ u32 pack2(float a, float b) { return f2bf(a) | (f2bf(b) << 16); }
__device__ __forceinline__ void unpack8(uint4 u, float* f) {
  f[0] = bf2f(u.x & 0xffffu); f[1] = bf2f(u.x >> 16);
  f[2] = bf2f(u.y & 0xffffu); f[3] = bf2f(u.y >> 16);
  f[4] = bf2f(u.z & 0xffffu); f[5] = bf2f(u.z >> 16);
  f[6] = bf2f(u.w & 0xffffu); f[7] = bf2f(u.w >> 16);
}

// async global->LDS, 16B per lane; LDS dest = wave-uniform base + lane*16.
__device__ __forceinline__ void gload16(const void* g, void* l) {
  __builtin_amdgcn_global_load_lds(
      (const __attribute__((address_space(1))) void*)g,
      (__attribute__((address_space(3))) void*)l, 16, 0, 0);
}

// ---------------------------------------------------------------------------
// MFMA bf16 GEMM, z-paired (r12 banked winner — ~570 TF/GEMM at this shape).
// 128x256 tile, BK=32, 512 threads = 8 waves (2x4), wave tile 64x64,
// acc[4][4]. THREE 24KB buffers (72KB -> 2 blocks/CU), rotation s%3, ONE
// barrier per K-step. Race-safe: writes at step s hit buf[(s+1)%3]; laggard
// reads from step s-1 hit buf[(s-1)%3]; diff 2 mod 3 != 0.
// Both-sides octet XOR (rule #21). XCD-grouped band swizzle; optional ridx.
// ---------------------------------------------------------------------------
template <typename CT>
__global__ __launch_bounds__(512, 4) void bgemm(
    const bf16_t* __restrict__ A0, const bf16_t* __restrict__ Bt0,
    const float* __restrict__ bias0, CT* __restrict__ C0,
    const int* __restrict__ ridx0, int N0,
    const bf16_t* __restrict__ A1, const bf16_t* __restrict__ Bt1,
    const float* __restrict__ bias1, CT* __restrict__ C1,
    const int* __restrict__ ridx1, int N1,
    int K, int M, int accumulate)
{
  __shared__ short lds[3][12288];   // [buf][A: 0..4095 | B: 4096..12287]
  const int z = blockIdx.z;
  const bf16_t* A   = z ? A1 : A0;
  const bf16_t* Bt  = z ? Bt1 : Bt0;
  const float* bias = z ? bias1 : bias0;
  CT* C             = z ? C1 : C0;
  const int* ridx   = z ? ridx1 : ridx0;
  const int N       = z ? N1 : N0;

  const int tid = threadIdx.x;
  const int ncol = gridDim.x;
  const int nband = (N + 127) >> 7;
  int lin = blockIdx.y * ncol + blockIdx.x;
  if (lin >= ncol * nband) return;

  int band, col;
  const int full = (nband >> 3) * 8 * ncol;
  if (lin < full) {
    int g = lin >> 3, x = lin & 7;
    band = x + 8 * (g / ncol);
    col  = g % ncol;
  } else {
    int r = lin - full;
    band = (nband & ~7) + r / ncol;
    col  = r % ncol;
  }
  const int bm = band * 128, bn = col * 256;

  const int lane = tid & 63;
  const int w = tid >> 6;
  const int wr = w >> 2, wc = w & 3;
  const int fr = lane & 15, fg = lane >> 4;

  const int kg = (((tid & 3) ^ ((tid >> 3) & 3)) << 3);
  const int rr = tid >> 2;
  int ra = min(bm + rr, N - 1);
  const bf16_t* gA0 = A + (size_t)(ridx ? ridx[ra] : ra) * K + kg;
  const bf16_t* gB0 = Bt + (size_t)(bn + rr) * K + kg;
  const bf16_t* gB1 = Bt + (size_t)(bn + 128 + rr) * K + kg;
  const int wb = w << 9;

  f32x4 acc[4][4];
#pragma unroll
  for (int i = 0; i < 4; ++i)
#pragma unroll
    for (int j = 0; j < 4; ++j) acc[i][j] = (f32x4){0.f, 0.f, 0.f, 0.f};

  auto stage = [&](int buf, int k0) {
    short* base = &lds[buf][0];
    gload16(gA0 + k0, base + wb);
    gload16(gB0 + k0, base + 4096 + wb);
    gload16(gB1 + k0, base + 8192 + wb);
  };

  const int nsteps = K >> 5;
  stage(0, 0);
  const int co = (fg ^ ((fr >> 1) & 3)) << 3;
  for (int s = 0; s < nsteps; ++s) {
    const int cur = s % 3;
    if (s + 1 < nsteps) {
      stage((s + 1) % 3, (s + 1) << 5);
      asm volatile("s_waitcnt vmcnt(3)" ::: "memory");
    } else {
      asm volatile("s_waitcnt vmcnt(0)" ::: "memory");
    }
    __builtin_amdgcn_s_barrier();
    asm volatile("" ::: "memory");
    const short* LA = &lds[cur][0];
    const short* LB = &lds[cur][4096];
    short8v b[4];
#pragma unroll
    for (int j = 0; j < 4; ++j) {
      int R = wc * 64 + j * 16 + fr;
      b[j] = *(const short8v*)&LB[R * 32 + co];
    }
#pragma unroll
    for (int i = 0; i < 4; ++i) {
      int R = wr * 64 + i * 16 + fr;
      short8v a = *(const short8v*)&LA[R * 32 + co];
#pragma unroll
      for (int j = 0; j < 4; ++j)
        acc[i][j] = __builtin_amdgcn_mfma_f32_16x16x32_bf16(b[j], a,
                                                            acc[i][j], 0, 0, 0);
    }
    asm volatile("" ::: "memory");
  }

  float4 bv[4];
#pragma unroll
  for (int j = 0; j < 4; ++j) {
    bv[j] = make_float4(0.f, 0.f, 0.f, 0.f);
    if (!accumulate && bias)
      bv[j] = *(const float4*)(bias + bn + wc * 64 + j * 16 + fg * 4);
  }
#pragma unroll
  for (int i = 0; i < 4; ++i) {
    const int n = bm + wr * 64 + i * 16 + fr;
    if (n >= N) continue;
#pragma unroll
    for (int j = 0; j < 4; ++j) {
      const int m0 = bn + wc * 64 + j * 16 + fg * 4;
      f32x4 v = acc[i][j];
      if constexpr (std::is_same<CT, float>::value) {
        float* p = C + (size_t)n * M + m0;
        if (accumulate) {
          float4 o = *(float4*)p;
          o.x += v[0]; o.y += v[1]; o.z += v[2]; o.w += v[3];
          *(float4*)p = o;
        } else {
          *(float4*)p = make_float4(v[0] + bv[j].x, v[1] + bv[j].y,
                                    v[2] + bv[j].z, v[3] + bv[j].w);
        }
      } else {
        uint2 o;
        o.x = pack2(v[0] + bv[j].x, v[1] + bv[j].y);
        o.y = pack2(v[2] + bv[j].z, v[3] + bv[j].w);
        *(uint2*)(C + (size_t)n * M + m0) = o;
      }
    }
  }
}

// core transpose tile: fp32 W[K][M] slice -> bf16 Wt[M][K] slice
__device__ __forceinline__ void wT_tile(
    const float* __restrict__ W, bf16_t* __restrict__ Wt, int K, int M)
{
  __shared__ float sm[32][33];
  int mb = blockIdx.x * 32, kb = blockIdx.y * 32;
  int tx = threadIdx.x & 31, ty = threadIdx.x >> 5;
#pragma unroll
  for (int i = 0; i < 4; ++i)
    sm[ty + i * 8][tx] = W[(size_t)(kb + ty + i * 8) * M + mb + tx];
  __syncthreads();
#pragma unroll
  for (int i = 0; i < 4; ++i)
    Wt[(size_t)(mb + ty + i * 8) * K + kb + tx] = (bf16_t)f2bf(sm[tx][ty + i * 8]);
}

// z-batched converters
__global__ __launch_bounds__(256) void convert_wT(        // single tensor
    const float* __restrict__ W, bf16_t* __restrict__ Wt, int K, int M)
{
  wT_tile(W + (size_t)blockIdx.z * K * M, Wt + (size_t)blockIdx.z * K * M, K, M);
}
__global__ __launch_bounds__(256) void convert_wT24(      // conv Wl(12) + Wr(12)
    const float* __restrict__ Wl, bf16_t* __restrict__ wl,
    const float* __restrict__ Wr, bf16_t* __restrict__ wr)
{
  int z = blockIdx.z;
  size_t o = (size_t)(z < 12 ? z : z - 12) * 512 * 512;
  if (z < 12) wT_tile(Wl + o, wl + o, 512, 512);
  else        wT_tile(Wr + o, wr + o, 512, 512);
}
__global__ __launch_bounds__(256) void convert_wT3(       // qp/tp/ap (384->512)
    const float* __restrict__ W0, const float* __restrict__ W1,
    const float* __restrict__ W2, bf16_t* __restrict__ T0,
    bf16_t* __restrict__ T1, bf16_t* __restrict__ T2)
{
  int z = blockIdx.z;
  const float* W = z == 0 ? W0 : z == 1 ? W1 : W2;
  bf16_t* T = z == 0 ? T0 : z == 1 ? T1 : T2;
  wT_tile(W, T, 384, 512);
}
__global__ __launch_bounds__(256) void convert_wT4h(      // qh + 3 rh slices
    const float* __restrict__ qh, const float* __restrict__ rh,
    bf16_t* __restrict__ wqh, bf16_t* __restrict__ wrh)
{
  int z = blockIdx.z;
  if (z == 0) wT_tile(qh, wqh, 512, 256);
  else        wT_tile(rh + (size_t)(z - 1) * 512 * 256,
                      wrh + (size_t)(z - 1) * 256 * 512, 512, 256);
}

// fused input casts: xq->xqb, xt->xlb, xa->xrb (float4 granularity)
#define N4_XQ (NQ * 96)
#define N4_XT (NT * 96)
#define N4_XA (NA * 96)
__global__ __launch_bounds__(256) void cast3(
    const float* __restrict__ xq, const float* __restrict__ xt,
    const float* __restrict__ xa, bf16_t* __restrict__ xqb,
    bf16_t* __restrict__ xtb, bf16_t* __restrict__ xab)
{
  long g = (long)blockIdx.x * 256 + threadIdx.x;
  const float* in; bf16_t* out; long idx;
  if (g < N4_XQ)                { in = xq; out = xqb; idx = g; }
  else if (g < N4_XQ + N4_XT)   { in = xt; out = xtb; idx = g - N4_XQ; }
  else if (g < N4_XQ + N4_XT + N4_XA) { in = xa; out = xab; idx = g - N4_XQ - N4_XT; }
  else return;
  float4 v = ((const float4*)in)[idx];
  uint2 o;
  o.x = pack2(v.x, v.y);
  o.y = pack2(v.z, v.w);
  ((uint2*)out)[idx] = o;
}

// all six combined bias vectors in one launch.
__global__ __launch_bounds__(256) void combine_bias6(
    const float* __restrict__ cb, float* __restrict__ bcAll)
{
  int g = blockIdx.x * 256 + threadIdx.x;
  if (g >= 6 * 512) return;
  int row = g >> 9, j = g & 511;
  int l = row / 3, kind = row % 3;
  const float* b = cb + (size_t)l * 6 * 512;
  float v;
  if (kind == 0)      v = (b[0 * 512 + j] + b[3 * 512 + j] + b[5 * 512 + j]) / 3.f;
  else if (kind == 1) v = (b[1 * 512 + j] + b[4 * 512 + j]) * 0.5f;
  else                v = b[2 * 512 + j];
  bcAll[(size_t)row * 512 + j] = v;
}

// ---------------------------------------------------------------------------
// Fused CSR build over all 6 relations (compile-time range tables).
// ---------------------------------------------------------------------------
__device__ __forceinline__ int find_rel(int g, const int* off) {
  int r = 0;
#pragma unroll
  for (int k = 1; k < 6; ++k) r += (g >= off[k]);
  return r;
}

__global__ __launch_bounds__(256) void hist6(
    const int* __restrict__ d0, const int* __restrict__ d1,
    const int* __restrict__ d2, const int* __restrict__ d3,
    const int* __restrict__ d4, const int* __restrict__ d5,
    int* __restrict__ degAll, int* __restrict__ pos)
{
  int g = blockIdx.x * 256 + threadIdx.x;
  if (g >= ETOT) return;
  int r = find_rel(g, c_eOff);
  int le = g - c_eOff[r];
  const int* dp = r == 0 ? d0 : r == 1 ? d1 : r == 2 ? d2 : r == 3 ? d3
                : r == 4 ? d4 : d5;
  pos[g] = atomicAdd(&degAll[c_degOff[r] + dp[le]], 1);
}

__global__ __launch_bounds__(256) void scan1_6(
    const int* __restrict__ in, int* __restrict__ out, int* __restrict__ bsum)
{
  __shared__ int sm[256];
  int b = blockIdx.x;
  int r = 0;
#pragma unroll
  for (int k = 1; k < 6; ++k) r += (b >= c_nbOff[k]);
  int lb = b - c_nbOff[r];
  int base0 = c_degOff[r], n = c_degOff[r + 1] - base0;
  int t = threadIdx.x;
  int base = lb * 1024 + t * 4;
  int v[4], sum = 0;
#pragma unroll
  for (int k = 0; k < 4; ++k) {
    v[k] = (base + k < n) ? in[base0 + base + k] : 0;
    sum += v[k];
  }
  sm[t] = sum;
  __syncthreads();
  for (int off = 1; off < 256; off <<= 1) {
    int x = (t >= off) ? sm[t - off] : 0;
    __syncthreads();
    sm[t] += x;
    __syncthreads();
  }
  int run = (t > 0) ? sm[t - 1] : 0;
  if (t == 255) bsum[r * 64 + lb] = sm[255];
#pragma unroll
  for (int k = 0; k < 4; ++k) {
    if (base + k < n) out[base0 + base + k] = run;
    run += v[k];
  }
}

__global__ __launch_bounds__(64) void scan2_6(int* __restrict__ bsum)
{
  __shared__ int sm[64];
  int r = blockIdx.x;
  int nb = c_nb[r];
  int t = threadIdx.x;
  int v = (t < nb) ? bsum[r * 64 + t] : 0;
  sm[t] = v;
  __syncthreads();
  for (int off = 1; off < 64; off <<= 1) {
    int x = (t >= off) ? sm[t - off] : 0;
    __syncthreads();
    sm[t] += x;
    __syncthreads();
  }
  if (t < nb) bsum[r * 64 + t] = sm[t] - v;   // exclusive
}

__global__ __launch_bounds__(256) void scan3_6(
    int* __restrict__ out, const int* __restrict__ bsum)
{
  int g = blockIdx.x * 256 + threadIdx.x;
  if (g >= NDTOT) return;
  int r = find_rel(g, c_degOff);
  int ln = g - c_degOff[r];
  out[g] += bsum[r * 64 + (ln >> 10)];
}

__global__ __launch_bounds__(256) void scatter6(
    const int* __restrict__ d0, const int* __restrict__ d1,
    const int* __restrict__ d2, const int* __restrict__ d3,
    const int* __restrict__ d4, const int* __restrict__ d5,
    const int* __restrict__ startAll, const int* __restrict__ pos,
    int* __restrict__ eidxAll)
{
  int g = blockIdx.x * 256 + threadIdx.x;
  if (g >= ETOT) return;
  int r = find_rel(g, c_eOff);
  int le = g - c_eOff[r];
  const int* dp = r == 0 ? d0 : r == 1 ? d1 : r == 2 ? d2 : r == 3 ? d3
                : r == 4 ? d4 : d5;
  eidxAll[c_eOff[r] + startAll[c_degOff[r] + dp[le]] + pos[g]] = le;
}

// ---------------------------------------------------------------------------
// Fused GATv2 message+softmax+aggregate, one wave per dst node, no atomics.
// deg==0 -> 0; deg==1 -> alpha==1 -> output = xl[src]. Edge-index pipelined.
// ---------------------------------------------------------------------------
__global__ __launch_bounds__(256) void gat_fused(
    const bf16_t* __restrict__ xl, const bf16_t* __restrict__ xr,
    const int* __restrict__ srcArr, const int* __restrict__ start,
    const int* __restrict__ deg, const int* __restrict__ eidx,
    const float* __restrict__ att, bf16_t* __restrict__ acc,
    int Nd, int accumulate, const float* __restrict__ bc, float inv_div)
{
  int d = blockIdx.x * 4 + (threadIdx.x >> 6);
  if (d >= Nd) return;
  int lane = threadIdx.x & 63;

  float acc8[8] = {0.f, 0.f, 0.f, 0.f, 0.f, 0.f, 0.f, 0.f};
  int n = deg[d], s0 = start[d];
  if (n == 1) {
    int s = srcArr[eidx[s0]];
    unpack8(*(const uint4*)(xl + (size_t)s * 512 + lane * 8), acc8);
  } else if (n > 1) {
    float xrr[8];
    unpack8(*(const uint4*)(xr + (size_t)d * 512 + lane * 8), xrr);
    float at[8];
    *(float4*)(at)     = *(const float4*)(att + lane * 8);
    *(float4*)(at + 4) = *(const float4*)(att + lane * 8 + 4);
    float den = 0.f;
    int sN = srcArr[eidx[s0]];
    for (int i = 0; i < n; ++i) {
      int s = sN;
      if (i + 1 < n) sN = srcArr[eidx[s0 + i + 1]];
      float f[8];
      unpack8(*(const uint4*)(xl + (size_t)s * 512 + lane * 8), f);
      float p = 0.f;
#pragma unroll
      for (int k = 0; k < 8; ++k) {
        float x = f[k] + xrr[k];
        p = fmaf(at[k], x >= 0.f ? x : NEG_SLOPE * x, p);
      }
#pragma unroll
      for (int m = 8; m >= 1; m >>= 1) p += __shfl_xor(p, m);
      float ex = __expf(p);
      den += ex;
#pragma unroll
      for (int k = 0; k < 8; ++k) acc8[k] = fmaf(ex, f[k], acc8[k]);
    }
    float inv = 1.f / (den + 1e-16f);
#pragma unroll
    for (int k = 0; k < 8; ++k) acc8[k] *= inv;
  }

  bf16_t* out = acc + (size_t)d * 512 + lane * 8;
  if (accumulate) {
    float old[8];
    unpack8(*(const uint4*)out, old);
#pragma unroll
    for (int k = 0; k < 8; ++k) acc8[k] += old[k];
  }
  if (bc) {
    float bcv[8];
    *(float4*)(bcv)     = *(const float4*)(bc + lane * 8);
    *(float4*)(bcv + 4) = *(const float4*)(bc + lane * 8 + 4);
#pragma unroll
    for (int k = 0; k < 8; ++k)
      acc8[k] = fmaxf(fmaf(acc8[k], inv_div, bcv[k]), 0.f);
  }
  uint4 s;
  s.x = pack2(acc8[0], acc8[1]); s.y = pack2(acc8[2], acc8[3]);
  s.z = pack2(acc8[4], acc8[5]); s.w = pack2(acc8[6], acc8[7]);
  *(uint4*)out = s;
}

// afh = relu(answer_features @ W1 + b1) -> bf16, K=6, M=64
__global__ __launch_bounds__(256) void af_hidden(
    const float* __restrict__ af, const float* __restrict__ W1,
    const float* __restrict__ b1, bf16_t* __restrict__ out, int n)
{
  int t = blockIdx.x * blockDim.x + threadIdx.x;
  if (t >= n * 64) return;
  int i = t >> 6, j = t & 63;
  const float* a = af + (size_t)i * 6;
  float s = b1[j];
#pragma unroll
  for (int k = 0; k < 6; ++k) s = fmaf(a[k], W1[k * 64 + j], s);
  out[t] = (bf16_t)f2bf(fmaxf(s, 0.f));
}

__global__ __launch_bounds__(256) void build_sim(
    const int* __restrict__ ei, int* __restrict__ ss, int* __restrict__ sd)
{
  int t = blockIdx.x * blockDim.x + threadIdx.x;
  if (t >= E_SIM + NQ) return;
  if (t < E_SIM) { ss[t] = ei[t]; sd[t] = ei[E_SIM + t]; }
  else           { ss[t] = t - E_SIM; sd[t] = t - E_SIM; }
}

__global__ __launch_bounds__(256) void head_final(
    const float* __restrict__ qpre, const float* __restrict__ rpre,
    const float* __restrict__ qg, const float* __restrict__ qb,
    const float* __restrict__ rg, const float* __restrict__ rb,
    const float* __restrict__ score_bias, float* __restrict__ out, int E)
{
  int e = blockIdx.x * 4 + (threadIdx.x >> 6);
  if (e >= E) return;
  int lane = threadIdx.x & 63;

  float4 q = *(const float4*)(qpre + (size_t)e * 256 + lane * 4);
  float s = q.x + q.y + q.z + q.w;
#pragma unroll
  for (int m = 32; m >= 1; m >>= 1) s += __shfl_xor(s, m);
  float mu = s * (1.f / 256.f);
  float dq0 = q.x - mu, dq1 = q.y - mu, dq2 = q.z - mu, dq3 = q.w - mu;
  float v = dq0 * dq0 + dq1 * dq1 + dq2 * dq2 + dq3 * dq3;
#pragma unroll
  for (int m = 32; m >= 1; m >>= 1) v += __shfl_xor(v, m);
  float rstd = rsqrtf(v * (1.f / 256.f) + 1e-5f);
  float4 g4 = *(const float4*)(qg + lane * 4);
  float4 b4 = *(const float4*)(qb + lane * 4);
  float qn0 = dq0 * rstd * g4.x + b4.x, qn1 = dq1 * rstd * g4.y + b4.y;
  float qn2 = dq2 * rstd * g4.z + b4.z, qn3 = dq3 * rstd * g4.w + b4.w;

  float4 r = *(const float4*)(rpre + (size_t)e * 256 + lane * 4);
  s = r.x + r.y + r.z + r.w;
#pragma unroll
  for (int m = 32; m >= 1; m >>= 1) s += __shfl_xor(s, m);
  mu = s * (1.f / 256.f);
  float dr0 = r.x - mu, dr1 = r.y - mu, dr2 = r.z - mu, dr3 = r.w - mu;
  v = dr0 * dr0 + dr1 * dr1 + dr2 * dr2 + dr3 * dr3;
#pragma unroll
  for (int m = 32; m >= 1; m >>= 1) v += __shfl_xor(v, m);
  rstd = rsqrtf(v * (1.f / 256.f) + 1e-5f);
  g4 = *(const float4*)(rg + lane * 4);
  b4 = *(const float4*)(rb + lane * 4);
  float rn0 = dr0 * rstd * g4.x + b4.x, rn1 = dr1 * rstd * g4.y + b4.y;
  float rn2 = dr2 * rstd * g4.z + b4.z, rn3 = dr3 * rstd * g4.w + b4.w;

  float d = qn0 * rn0 + qn1 * rn1 + qn2 * rn2 + qn3 * rn3;
#pragma unroll
  for (int m = 32; m >= 1; m >>= 1) d += __shfl_xor(d, m);
  if (lane == 0) out[e] = d * 0.0625f + score_bias[0];
}

// ---------------------------------------------------------------------------
extern "C" void kernel_launch(void* const* d_in, const int* in_sizes, int n_in,
                              void* d_out, int out_size, void* d_ws, size_t ws_size,
                              hipStream_t stream) {
  (void)in_sizes; (void)n_in; (void)out_size;
  const float* xq      = (const float*)d_in[0];
  const float* xt      = (const float*)d_in[1];
  const float* xa      = (const float*)d_in[2];
  const float* af      = (const float*)d_in[3];
  const float* qp_W    = (const float*)d_in[4];
  const float* qp_b    = (const float*)d_in[5];
  const float* tp_W    = (const float*)d_in[6];
  const float* tp_b    = (const float*)d_in[7];
  const float* ap_W    = (const float*)d_in[8];
  const float* ap_b    = (const float*)d_in[9];
  const float* afp_W1  = (const float*)d_in[10];
  const float* afp_b1  = (const float*)d_in[11];
  const float* afp_W2  = (const float*)d_in[12];
  const float* afp_b2  = (const float*)d_in[13];
  const float* conv_Wl = (const float*)d_in[14];
  const float* conv_bl = (const float*)d_in[15];
  const float* conv_Wr = (const float*)d_in[16];
  const float* conv_br = (const float*)d_in[17];
  const float* conv_att  = (const float*)d_in[18];
  const float* conv_bias = (const float*)d_in[19];
  const float* qh_W    = (const float*)d_in[20];
  const float* qh_b    = (const float*)d_in[21];
  const float* qh_g    = (const float*)d_in[22];
  const float* qh_beta = (const float*)d_in[23];
  const float* rh_W    = (const float*)d_in[24];
  const float* rh_b    = (const float*)d_in[25];
  const float* rh_g    = (const float*)d_in[26];
  const float* rh_beta = (const float*)d_in[27];
  const float* score_b = (const float*)d_in[28];
  const int* ei_gr   = (const int*)d_in[29];
  const int* ei_lt   = (const int*)d_in[30];
  const int* ei_sim  = (const int*)d_in[31];
  const int* ei_comp = (const int*)d_in[32];
  const int* ei_gen  = (const int*)d_in[33];

  char* base = (char*)d_ws;
  size_t off = 0;
  auto alloc = [&](size_t bytes) {
    void* p = base + off;
    off = (off + bytes + 255) & ~(size_t)255;
    return p;
  };
  bf16_t* hq   = (bf16_t*)alloc((size_t)NQ * 512 * 2);
  bf16_t* ht   = (bf16_t*)alloc((size_t)NT * 512 * 2);
  bf16_t* ha   = (bf16_t*)alloc((size_t)NA * 512 * 2);
  bf16_t* acct = (bf16_t*)alloc((size_t)NT * 512 * 2);   // ht ping-pong; qpre f32
  bf16_t* accq = (bf16_t*)alloc((size_t)NQ * 512 * 2);   // xq-cast; hq ping-pong; afh
  bf16_t* xlb  = (bf16_t*)alloc((size_t)50000 * 512 * 2);// staging/af_emb
  bf16_t* xrb  = (bf16_t*)alloc((size_t)50000 * 512 * 2);// also rpre f32
  int* simsrc  = (int*)alloc((size_t)(E_SIM + NQ) * 4);
  int* simdst  = (int*)alloc((size_t)(E_SIM + NQ) * 4);

  // bf16-transposed weights
  bf16_t* wqp  = (bf16_t*)alloc((size_t)512 * 384 * 2);
  bf16_t* wtp  = (bf16_t*)alloc((size_t)512 * 384 * 2);
  bf16_t* wap  = (bf16_t*)alloc((size_t)512 * 384 * 2);
  bf16_t* wl   = (bf16_t*)alloc((size_t)12 * 512 * 512 * 2);
  bf16_t* wr   = (bf16_t*)alloc((size_t)12 * 512 * 512 * 2);
  bf16_t* wafp2 = (bf16_t*)alloc((size_t)512 * 64 * 2);
  bf16_t* wqh  = (bf16_t*)alloc((size_t)256 * 512 * 2);
  bf16_t* wrh0 = (bf16_t*)alloc((size_t)256 * 512 * 2);  // wrh0..2 contiguous
  bf16_t* wrh1 = (bf16_t*)alloc((size_t)256 * 512 * 2);
  bf16_t* wrh2 = (bf16_t*)alloc((size_t)256 * 512 * 2);
  float* bcAll = (float*)alloc(6 * 512 * 4);

  // Fused CSR arrays
  int* degAll   = (int*)alloc((size_t)NDTOT * 4);
  int* startAll = (int*)alloc((size_t)NDTOT * 4);
  int* eidxAll  = (int*)alloc((size_t)ETOT * 4);
  int* posb     = (int*)alloc((size_t)ETOT * 4);
  int* bsum     = (int*)alloc(6 * 64 * 4);
  if (off > ws_size) {
    fprintf(stderr, "kernel_launch: ws too small, need %zu have %zu\n", off, ws_size);
    return;
  }

  const int degOff[6] = {0, 50000, 60000, 110000, 120000, 170000};
  const int eOff[6]   = {0, 50000, 100000, 150000, 240000, 340000};

  // --- weight conversion (4 launches) ---
  convert_wT24<<<dim3(16, 16, 24), 256, 0, stream>>>(conv_Wl, wl, conv_Wr, wr);
  convert_wT3<<<dim3(16, 12, 3), 256, 0, stream>>>(qp_W, tp_W, ap_W, wqp, wtp, wap);
  convert_wT4h<<<dim3(8, 16, 4), 256, 0, stream>>>(qh_W, rh_W, wqh, wrh0);
  convert_wT<<<dim3(16, 2, 1), 256, 0, stream>>>(afp_W2, wafp2, 64, 512);
  combine_bias6<<<(6 * 512 + 255) / 256, 256, 0, stream>>>(conv_bias, bcAll);

  // --- fused CSR build ---
  build_sim<<<(E_SIM + NQ + 255) / 256, 256, 0, stream>>>(ei_sim, simsrc, simdst);
  const int* dsts[6] = {ei_gr + E_GR, ei_gr, ei_lt, simdst,
                        ei_comp + E_COMP, ei_lt + E_LT};
  hipMemsetAsync(degAll, 0, (size_t)NDTOT * 4, stream);
  hist6<<<(ETOT + 255) / 256, 256, 0, stream>>>(dsts[0], dsts[1], dsts[2],
      dsts[3], dsts[4], dsts[5], degAll, posb);
  scan1_6<<<216, 256, 0, stream>>>(degAll, startAll, bsum);
  scan2_6<<<6, 64, 0, stream>>>(bsum);
  scan3_6<<<(NDTOT + 255) / 256, 256, 0, stream>>>(startAll, bsum);
  scatter6<<<(ETOT + 255) / 256, 256, 0, stream>>>(dsts[0], dsts[1], dsts[2],
      dsts[3], dsts[4], dsts[5], startAll, posb, eidxAll);

  auto gemm1 = [&](const bf16_t* A, const bf16_t* Bt, const float* bias, bf16_t* C,
                   int N_, int K_, int M_, const int* ridx = nullptr) {
    dim3 g(M_ / 256, (N_ + 127) / 128, 1);
    bgemm<bf16_t><<<g, 512, 0, stream>>>(A, Bt, bias, C, ridx, N_,
                                         A, Bt, bias, C, ridx, N_, K_, M_, 0);
  };
  auto gemmf1 = [&](const bf16_t* A, const bf16_t* Bt, const float* bias, float* C,
                    int N_, int K_, int M_, int acc_, const int* ridx = nullptr) {
    dim3 g(M_ / 256, (N_ + 127) / 128, 1);
    bgemm<float><<<g, 512, 0, stream>>>(A, Bt, bias, C, ridx, N_,
                                        A, Bt, bias, C, ridx, N_, K_, M_, acc_);
  };
  auto gemm2 = [&](const bf16_t* A0, const bf16_t* B0, const float* b0, bf16_t* C0, int N0_,
                   const bf16_t* A1, const bf16_t* B1, const float* b1, bf16_t* C1, int N1_,
                   int K_, int M_) {
    int nb0 = (N0_ + 127) / 128, nb1 = (N1_ + 127) / 128;
    dim3 g(M_ / 256, nb0 > nb1 ? nb0 : nb1, 2);
    bgemm<bf16_t><<<g, 512, 0, stream>>>(A0, B0, b0, C0, nullptr, N0_,
                                         A1, B1, b1, C1, nullptr, N1_, K_, M_, 0);
  };
  auto gemmf2 = [&](const bf16_t* A0, const bf16_t* B0, const float* b0, float* C0,
                    const int* r0, int N0_,
                    const bf16_t* A1, const bf16_t* B1, const float* b1, float* C1,
                    const int* r1, int N1_, int K_, int M_) {
    int nb0 = (N0_ + 127) / 128, nb1 = (N1_ + 127) / 128;
    dim3 g(M_ / 256, nb0 > nb1 ? nb0 : nb1, 2);
    bgemm<float><<<g, 512, 0, stream>>>(A0, B0, b0, C0, r0, N0_,
                                        A1, B1, b1, C1, r1, N1_, K_, M_, 0);
  };

  // Input projections: ONE fused cast (xq->accq scratch, xt->xlb, xa->xrb).
  cast3<<<((long)(N4_XQ + N4_XT + N4_XA) + 255) / 256, 256, 0, stream>>>(
      xq, xt, xa, accq, xlb, xrb);
  gemm1(accq, wqp, qp_b, hq, NQ, 384, 512);
  gemm2(xlb, wtp, tp_b, ht, NT, xrb, wap, ap_b, ha, NA, 384, 512);

  // Layer loop. Rel order (CSR index r): 0=gr 1=rgr 2=rlt 3=sim 4=comp 5=lt
  const int* srcs[6] = {ei_gr, ei_gr + E_GR, ei_lt + E_LT, simsrc,
                        ei_comp, ei_lt};
  const int NdArr[6] = {NT, NQ, NT, NQ, NT, NA};
  bf16_t *hq_i = hq, *ht_i = ht, *hq_o = accq, *ht_o = acct;
  for (int l = 0; l < 2; ++l) {
    const float* bc_t = bcAll + (size_t)(l * 3 + 0) * 512;
    const float* bc_q = bcAll + (size_t)(l * 3 + 1) * 512;
    const float* bc_a = bcAll + (size_t)(l * 3 + 2) * 512;

    struct Rel { const bf16_t* xs; const bf16_t* xd; int Ns, po; bf16_t* acc;
                 int accum; const float* bc; float inv; };
    Rel rels[6] = {
      {hq_i, ht_i, NQ, 0, ht_o, 0, nullptr, 0.f},      // gr
      {ht_i, hq_i, NT, 1, hq_o, 0, nullptr, 0.f},      // rgr
      {ha,   ht_i, NA, 3, ht_o, 1, nullptr, 0.f},      // rlt
      {hq_i, hq_i, NQ, 4, hq_o, 1, bc_q, 0.5f},        // sim (final for q)
      {ht_i, ht_i, NT, 5, ht_o, 1, bc_t, 1.f / 3.f},   // comp (final for t)
      {ht_i, ha,   NT, 2, ha,   0, bc_a, 1.f},         // lt (final for a)
    };
    for (int r = 0; r < 6; ++r) {
      const Rel& R = rels[r];
      int Nd_ = NdArr[r];
      size_t po = (size_t)l * 6 + R.po;
      gemm2(R.xs, wl + po * 512 * 512, conv_bl + po * 512, xlb, R.Ns,
            R.xd, wr + po * 512 * 512, conv_br + po * 512, xrb, Nd_, 512, 512);
      int gb = (Nd_ + 3) / 4;
      gat_fused<<<gb, 256, 0, stream>>>(xlb, xrb, srcs[r],
                                        startAll + degOff[r], degAll + degOff[r],
                                        eidxAll + eOff[r], conv_att + po * 512,
                                        R.acc, Nd_, R.accum, R.bc, R.inv);
    }
    bf16_t* t;
    t = hq_i; hq_i = hq_o; hq_o = t;
    t = ht_i; ht_i = ht_o; ht_o = t;
  }

  // Head: gathers fused via ridx; qpre/rpre-first z-paired.
  float* qpre = (float*)acct;
  float* rpre = (float*)xrb;
  bf16_t* afh = accq;
  const int* gsrc = ei_gen;
  const int* gdst = ei_gen + E_GEN;

  gemmf2(hq_i, wqh, qh_b, qpre, gsrc, E_GEN,
         ht_i, wrh0, rh_b, rpre, gdst, E_GEN, 512, 256);    // q_emb | t_emb
  gemmf1(ha, wrh1, nullptr, rpre, E_GEN, 512, 256, 1, gdst); // + a_emb
  af_hidden<<<(E_GEN * 64 + 255) / 256, 256, 0, stream>>>(af, afp_W1, afp_b1,
                                                          afh, E_GEN);
  gemm1(afh, wafp2, afp_b2, xlb, E_GEN, 64, 512);            // af_emb
  gemmf1(xlb, wrh2, nullptr, rpre, E_GEN, 512, 256, 1);      // + af_emb
  head_final<<<(E_GEN + 3) / 4, 256, 0, stream>>>(
      qpre, rpre, qh_g, qh_beta, rh_g, rh_beta, score_b, (float*)d_out, E_GEN);
}

// Round 19
// 1268.661 us; speedup vs baseline: 1.3535x; 1.1602x over previous
//
#include <hip/hip_runtime.h>
#include <cstdio>
#include <type_traits>

#define NQ 10000
#define NT 50000
#define NA 50000
#define E_GR 50000
#define E_LT 50000
#define E_SIM 80000
#define E_COMP 100000
#define E_GEN 50000
#define NEG_SLOPE 0.2f

// Concatenated CSR tables (compile-time). Rel order: gr, rgr, rlt, sim, comp, lt
#define NDTOT 220000
#define ETOT  390000
__device__ __constant__ const int c_degOff[7]  = {0, 50000, 60000, 110000, 120000, 170000, 220000};
__device__ __constant__ const int c_eOff[7]    = {0, 50000, 100000, 150000, 240000, 340000, 390000};
__device__ __constant__ const int c_nb[6]      = {49, 10, 49, 10, 49, 49};
__device__ __constant__ const int c_nbOff[7]   = {0, 49, 59, 108, 118, 167, 216};

typedef unsigned short bf16_t;
typedef unsigned int u32;
typedef __attribute__((ext_vector_type(8))) short short8v;
typedef __attribute__((ext_vector_type(4))) float f32x4;

__device__ __forceinline__ float bf2f(u32 bits) { return __uint_as_float(bits << 16); }
__device__ __forceinline__ u32 f2bf(float f) {
  u32 u = __float_as_uint(f);
  return (u + 0x7FFFu + ((u >> 16) & 1u)) >> 16;   // RTNE
}
__device__ __forceinline__ u32 pack2(float a, float b) { return f2bf(a) | (f2bf(b) << 16); }
__device__ __forceinline__ void unpack8(uint4 u, float* f) {
  f[0] = bf2f(u.x & 0xffffu); f[1] = bf2f(u.x >> 16);
  f[2] = bf2f(u.y & 0xffffu); f[3] = bf2f(u.y >> 16);
  f[4] = bf2f(u.z & 0xffffu); f[5] = bf2f(u.z >> 16);
  f[6] = bf2f(u.w & 0xffffu); f[7] = bf2f(u.w >> 16);
}

// async global->LDS, 16B per lane; LDS dest = wave-uniform base + lane*16.
__device__ __forceinline__ void gload16(const void* g, void* l) {
  __builtin_amdgcn_global_load_lds(
      (const __attribute__((address_space(1))) void*)g,
      (__attribute__((address_space(3))) void*)l, 16, 0, 0);
}

// ---------------------------------------------------------------------------
// MFMA bf16 GEMM, z-paired (r12 banked structure, ~570 TF/GEMM).
// 128x256 tile, BK=32, 8 waves (2x4), acc[4][4]; 3x24KB LDS (2 blocks/CU),
// rotation s%3, ONE barrier/step (write (s+1)%3 vs laggard reads (s-1)%3).
// Both-sides octet XOR (rule #21). XCD-grouped band swizzle; optional ridx.
// NEW: optional device-side row count Nc (compacted xr GEMMs). Grid is sized
// for the static worst case; blocks beyond the dynamic band count exit
// uniformly before any barrier (N==0 -> all exit).
// ---------------------------------------------------------------------------
template <typename CT>
__global__ __launch_bounds__(512, 4) void bgemm(
    const bf16_t* __restrict__ A0, const bf16_t* __restrict__ Bt0,
    const float* __restrict__ bias0, CT* __restrict__ C0,
    const int* __restrict__ ridx0, int N0, const int* __restrict__ Nc0,
    const bf16_t* __restrict__ A1, const bf16_t* __restrict__ Bt1,
    const float* __restrict__ bias1, CT* __restrict__ C1,
    const int* __restrict__ ridx1, int N1, const int* __restrict__ Nc1,
    int K, int M, int accumulate)
{
  __shared__ short lds[3][12288];   // [buf][A: 0..4095 | B: 4096..12287]
  const int z = blockIdx.z;
  const bf16_t* A   = z ? A1 : A0;
  const bf16_t* Bt  = z ? Bt1 : Bt0;
  const float* bias = z ? bias1 : bias0;
  CT* C             = z ? C1 : C0;
  const int* ridx   = z ? ridx1 : ridx0;
  const int* Nc     = z ? Nc1 : Nc0;
  int N             = z ? N1 : N0;
  if (Nc) N = *Nc;                          // dynamic compacted row count

  const int tid = threadIdx.x;
  const int ncol = gridDim.x;
  const int nband = (N + 127) >> 7;
  int lin = blockIdx.y * ncol + blockIdx.x;
  if (lin >= ncol * nband) return;          // uniform exit, before barriers

  int band, col;
  const int full = (nband >> 3) * 8 * ncol;
  if (lin < full) {
    int g = lin >> 3, x = lin & 7;
    band = x + 8 * (g / ncol);
    col  = g % ncol;
  } else {
    int r = lin - full;
    band = (nband & ~7) + r / ncol;
    col  = r % ncol;
  }
  const int bm = band * 128, bn = col * 256;

  const int lane = tid & 63;
  const int w = tid >> 6;
  const int wr = w >> 2, wc = w & 3;
  const int fr = lane & 15, fg = lane >> 4;

  const int kg = (((tid & 3) ^ ((tid >> 3) & 3)) << 3);
  const int rr = tid >> 2;
  int ra = min(bm + rr, N - 1);
  const bf16_t* gA0 = A + (size_t)(ridx ? ridx[ra] : ra) * K + kg;
  const bf16_t* gB0 = Bt + (size_t)(bn + rr) * K + kg;
  const bf16_t* gB1 = Bt + (size_t)(bn + 128 + rr) * K + kg;
  const int wb = w << 9;

  f32x4 acc[4][4];
#pragma unroll
  for (int i = 0; i < 4; ++i)
#pragma unroll
    for (int j = 0; j < 4; ++j) acc[i][j] = (f32x4){0.f, 0.f, 0.f, 0.f};

  auto stage = [&](int buf, int k0) {
    short* base = &lds[buf][0];
    gload16(gA0 + k0, base + wb);
    gload16(gB0 + k0, base + 4096 + wb);
    gload16(gB1 + k0, base + 8192 + wb);
  };

  const int nsteps = K >> 5;
  stage(0, 0);
  const int co = (fg ^ ((fr >> 1) & 3)) << 3;
  for (int s = 0; s < nsteps; ++s) {
    const int cur = s % 3;
    if (s + 1 < nsteps) {
      stage((s + 1) % 3, (s + 1) << 5);
      asm volatile("s_waitcnt vmcnt(3)" ::: "memory");
    } else {
      asm volatile("s_waitcnt vmcnt(0)" ::: "memory");
    }
    __builtin_amdgcn_s_barrier();
    asm volatile("" ::: "memory");
    const short* LA = &lds[cur][0];
    const short* LB = &lds[cur][4096];
    short8v b[4];
#pragma unroll
    for (int j = 0; j < 4; ++j) {
      int R = wc * 64 + j * 16 + fr;
      b[j] = *(const short8v*)&LB[R * 32 + co];
    }
#pragma unroll
    for (int i = 0; i < 4; ++i) {
      int R = wr * 64 + i * 16 + fr;
      short8v a = *(const short8v*)&LA[R * 32 + co];
#pragma unroll
      for (int j = 0; j < 4; ++j)
        acc[i][j] = __builtin_amdgcn_mfma_f32_16x16x32_bf16(b[j], a,
                                                            acc[i][j], 0, 0, 0);
    }
    asm volatile("" ::: "memory");
  }

  float4 bv[4];
#pragma unroll
  for (int j = 0; j < 4; ++j) {
    bv[j] = make_float4(0.f, 0.f, 0.f, 0.f);
    if (!accumulate && bias)
      bv[j] = *(const float4*)(bias + bn + wc * 64 + j * 16 + fg * 4);
  }
#pragma unroll
  for (int i = 0; i < 4; ++i) {
    const int n = bm + wr * 64 + i * 16 + fr;
    if (n >= N) continue;
#pragma unroll
    for (int j = 0; j < 4; ++j) {
      const int m0 = bn + wc * 64 + j * 16 + fg * 4;
      f32x4 v = acc[i][j];
      if constexpr (std::is_same<CT, float>::value) {
        float* p = C + (size_t)n * M + m0;
        if (accumulate) {
          float4 o = *(float4*)p;
          o.x += v[0]; o.y += v[1]; o.z += v[2]; o.w += v[3];
          *(float4*)p = o;
        } else {
          *(float4*)p = make_float4(v[0] + bv[j].x, v[1] + bv[j].y,
                                    v[2] + bv[j].z, v[3] + bv[j].w);
        }
      } else {
        uint2 o;
        o.x = pack2(v[0] + bv[j].x, v[1] + bv[j].y);
        o.y = pack2(v[2] + bv[j].z, v[3] + bv[j].w);
        *(uint2*)(C + (size_t)n * M + m0) = o;
      }
    }
  }
}

// core transpose tile: fp32 W[K][M] slice -> bf16 Wt[M][K] slice
__device__ __forceinline__ void wT_tile(
    const float* __restrict__ W, bf16_t* __restrict__ Wt, int K, int M)
{
  __shared__ float sm[32][33];
  int mb = blockIdx.x * 32, kb = blockIdx.y * 32;
  int tx = threadIdx.x & 31, ty = threadIdx.x >> 5;
#pragma unroll
  for (int i = 0; i < 4; ++i)
    sm[ty + i * 8][tx] = W[(size_t)(kb + ty + i * 8) * M + mb + tx];
  __syncthreads();
#pragma unroll
  for (int i = 0; i < 4; ++i)
    Wt[(size_t)(mb + ty + i * 8) * K + kb + tx] = (bf16_t)f2bf(sm[tx][ty + i * 8]);
}

__global__ __launch_bounds__(256) void convert_wT(
    const float* __restrict__ W, bf16_t* __restrict__ Wt, int K, int M)
{
  wT_tile(W + (size_t)blockIdx.z * K * M, Wt + (size_t)blockIdx.z * K * M, K, M);
}
__global__ __launch_bounds__(256) void convert_wT24(
    const float* __restrict__ Wl, bf16_t* __restrict__ wl,
    const float* __restrict__ Wr, bf16_t* __restrict__ wr)
{
  int z = blockIdx.z;
  size_t o = (size_t)(z < 12 ? z : z - 12) * 512 * 512;
  if (z < 12) wT_tile(Wl + o, wl + o, 512, 512);
  else        wT_tile(Wr + o, wr + o, 512, 512);
}
__global__ __launch_bounds__(256) void convert_wT3(
    const float* __restrict__ W0, const float* __restrict__ W1,
    const float* __restrict__ W2, bf16_t* __restrict__ T0,
    bf16_t* __restrict__ T1, bf16_t* __restrict__ T2)
{
  int z = blockIdx.z;
  const float* W = z == 0 ? W0 : z == 1 ? W1 : W2;
  bf16_t* T = z == 0 ? T0 : z == 1 ? T1 : T2;
  wT_tile(W, T, 384, 512);
}
__global__ __launch_bounds__(256) void convert_wT4h(
    const float* __restrict__ qh, const float* __restrict__ rh,
    bf16_t* __restrict__ wqh, bf16_t* __restrict__ wrh)
{
  int z = blockIdx.z;
  if (z == 0) wT_tile(qh, wqh, 512, 256);
  else        wT_tile(rh + (size_t)(z - 1) * 512 * 256,
                      wrh + (size_t)(z - 1) * 256 * 512, 512, 256);
}

// fused input casts: xq->xqb, xt->xlb, xa->xrb (float4 granularity)
#define N4_XQ (NQ * 96)
#define N4_XT (NT * 96)
#define N4_XA (NA * 96)
__global__ __launch_bounds__(256) void cast3(
    const float* __restrict__ xq, const float* __restrict__ xt,
    const float* __restrict__ xa, bf16_t* __restrict__ xqb,
    bf16_t* __restrict__ xtb, bf16_t* __restrict__ xab)
{
  long g = (long)blockIdx.x * 256 + threadIdx.x;
  const float* in; bf16_t* out; long idx;
  if (g < N4_XQ)                { in = xq; out = xqb; idx = g; }
  else if (g < N4_XQ + N4_XT)   { in = xt; out = xtb; idx = g - N4_XQ; }
  else if (g < N4_XQ + N4_XT + N4_XA) { in = xa; out = xab; idx = g - N4_XQ - N4_XT; }
  else return;
  float4 v = ((const float4*)in)[idx];
  uint2 o;
  o.x = pack2(v.x, v.y);
  o.y = pack2(v.z, v.w);
  ((uint2*)out)[idx] = o;
}

__global__ __launch_bounds__(256) void combine_bias6(
    const float* __restrict__ cb, float* __restrict__ bcAll)
{
  int g = blockIdx.x * 256 + threadIdx.x;
  if (g >= 6 * 512) return;
  int row = g >> 9, j = g & 511;
  int l = row / 3, kind = row % 3;
  const float* b = cb + (size_t)l * 6 * 512;
  float v;
  if (kind == 0)      v = (b[0 * 512 + j] + b[3 * 512 + j] + b[5 * 512 + j]) / 3.f;
  else if (kind == 1) v = (b[1 * 512 + j] + b[4 * 512 + j]) * 0.5f;
  else                v = b[2 * 512 + j];
  bcAll[(size_t)row * 512 + j] = v;
}

// ---------------------------------------------------------------------------
// Fused CSR build + deg>=2 compaction over all 6 relations.
// ---------------------------------------------------------------------------
__device__ __forceinline__ int find_rel(int g, const int* off) {
  int r = 0;
#pragma unroll
  for (int k = 1; k < 6; ++k) r += (g >= off[k]);
  return r;
}

__global__ __launch_bounds__(256) void hist6(
    const int* __restrict__ d0, const int* __restrict__ d1,
    const int* __restrict__ d2, const int* __restrict__ d3,
    const int* __restrict__ d4, const int* __restrict__ d5,
    int* __restrict__ degAll, int* __restrict__ pos)
{
  int g = blockIdx.x * 256 + threadIdx.x;
  if (g >= ETOT) return;
  int r = find_rel(g, c_eOff);
  int le = g - c_eOff[r];
  const int* dp = r == 0 ? d0 : r == 1 ? d1 : r == 2 ? d2 : r == 3 ? d3
                : r == 4 ? d4 : d5;
  pos[g] = atomicAdd(&degAll[c_degOff[r] + dp[le]], 1);
}

// PRED==0: scan raw values (CSR starts). PRED==1: scan (deg>=2) predicate.
template <int PRED>
__global__ __launch_bounds__(256) void scan1_6(
    const int* __restrict__ in, int* __restrict__ out, int* __restrict__ bsum)
{
  __shared__ int sm[256];
  int b = blockIdx.x;
  int r = 0;
#pragma unroll
  for (int k = 1; k < 6; ++k) r += (b >= c_nbOff[k]);
  int lb = b - c_nbOff[r];
  int base0 = c_degOff[r], n = c_degOff[r + 1] - base0;
  int t = threadIdx.x;
  int base = lb * 1024 + t * 4;
  int v[4], sum = 0;
#pragma unroll
  for (int k = 0; k < 4; ++k) {
    int raw = (base + k < n) ? in[base0 + base + k] : 0;
    v[k] = PRED ? (raw >= 2 ? 1 : 0) : raw;
    sum += v[k];
  }
  sm[t] = sum;
  __syncthreads();
  for (int off = 1; off < 256; off <<= 1) {
    int x = (t >= off) ? sm[t - off] : 0;
    __syncthreads();
    sm[t] += x;
    __syncthreads();
  }
  int run = (t > 0) ? sm[t - 1] : 0;
  if (t == 255) bsum[r * 64 + lb] = sm[255];
#pragma unroll
  for (int k = 0; k < 4; ++k) {
    if (base + k < n) out[base0 + base + k] = run;
    run += v[k];
  }
}

// exclusive across blocks; optionally writes per-relation totals.
__global__ __launch_bounds__(64) void scan2_6(
    int* __restrict__ bsum, int* __restrict__ total)
{
  __shared__ int sm[64];
  int r = blockIdx.x;
  int nb = c_nb[r];
  int t = threadIdx.x;
  int v = (t < nb) ? bsum[r * 64 + t] : 0;
  sm[t] = v;
  __syncthreads();
  for (int off = 1; off < 64; off <<= 1) {
    int x = (t >= off) ? sm[t - off] : 0;
    __syncthreads();
    sm[t] += x;
    __syncthreads();
  }
  if (t < nb) bsum[r * 64 + t] = sm[t] - v;   // exclusive
  if (total && t == nb - 1) total[r] = sm[t]; // inclusive total
}

__global__ __launch_bounds__(256) void scan3_6(
    int* __restrict__ out, const int* __restrict__ bsum)
{
  int g = blockIdx.x * 256 + threadIdx.x;
  if (g >= NDTOT) return;
  int r = find_rel(g, c_degOff);
  int ln = g - c_degOff[r];
  out[g] += bsum[r * 64 + (ln >> 10)];
}

__global__ __launch_bounds__(256) void scatter6(
    const int* __restrict__ d0, const int* __restrict__ d1,
    const int* __restrict__ d2, const int* __restrict__ d3,
    const int* __restrict__ d4, const int* __restrict__ d5,
    const int* __restrict__ startAll, const int* __restrict__ pos,
    int* __restrict__ eidxAll)
{
  int g = blockIdx.x * 256 + threadIdx.x;
  if (g >= ETOT) return;
  int r = find_rel(g, c_eOff);
  int le = g - c_eOff[r];
  const int* dp = r == 0 ? d0 : r == 1 ? d1 : r == 2 ? d2 : r == 3 ? d3
                : r == 4 ? d4 : d5;
  eidxAll[c_eOff[r] + startAll[c_degOff[r] + dp[le]] + pos[g]] = le;
}

// cidxAll[degOff[r] + cpos] = local node index, for deg>=2 nodes.
__global__ __launch_bounds__(256) void compact6(
    const int* __restrict__ degAll, const int* __restrict__ cposAll,
    int* __restrict__ cidxAll)
{
  int g = blockIdx.x * 256 + threadIdx.x;
  if (g >= NDTOT) return;
  if (degAll[g] >= 2) {
    int r = find_rel(g, c_degOff);
    cidxAll[c_degOff[r] + cposAll[g]] = g - c_degOff[r];
  }
}

// ---------------------------------------------------------------------------
// Fused GATv2: one wave per dst node. deg==0 -> 0; deg==1 -> xl[src];
// deg>=2 reads COMPACTED xr at row cpos[d]. Edge-index pipelined.
// ---------------------------------------------------------------------------
__global__ __launch_bounds__(256) void gat_fused(
    const bf16_t* __restrict__ xl, const bf16_t* __restrict__ xr,
    const int* __restrict__ srcArr, const int* __restrict__ start,
    const int* __restrict__ deg, const int* __restrict__ eidx,
    const int* __restrict__ cpos, const float* __restrict__ att,
    bf16_t* __restrict__ acc, int Nd, int accumulate,
    const float* __restrict__ bc, float inv_div)
{
  int d = blockIdx.x * 4 + (threadIdx.x >> 6);
  if (d >= Nd) return;
  int lane = threadIdx.x & 63;

  float acc8[8] = {0.f, 0.f, 0.f, 0.f, 0.f, 0.f, 0.f, 0.f};
  int n = deg[d], s0 = start[d];
  if (n == 1) {
    int s = srcArr[eidx[s0]];
    unpack8(*(const uint4*)(xl + (size_t)s * 512 + lane * 8), acc8);
  } else if (n > 1) {
    float xrr[8];
    unpack8(*(const uint4*)(xr + (size_t)cpos[d] * 512 + lane * 8), xrr);
    float at[8];
    *(float4*)(at)     = *(const float4*)(att + lane * 8);
    *(float4*)(at + 4) = *(const float4*)(att + lane * 8 + 4);
    float den = 0.f;
    int sN = srcArr[eidx[s0]];
    for (int i = 0; i < n; ++i) {
      int s = sN;
      if (i + 1 < n) sN = srcArr[eidx[s0 + i + 1]];
      float f[8];
      unpack8(*(const uint4*)(xl + (size_t)s * 512 + lane * 8), f);
      float p = 0.f;
#pragma unroll
      for (int k = 0; k < 8; ++k) {
        float x = f[k] + xrr[k];
        p = fmaf(at[k], x >= 0.f ? x : NEG_SLOPE * x, p);
      }
#pragma unroll
      for (int m = 8; m >= 1; m >>= 1) p += __shfl_xor(p, m);
      float ex = __expf(p);
      den += ex;
#pragma unroll
      for (int k = 0; k < 8; ++k) acc8[k] = fmaf(ex, f[k], acc8[k]);
    }
    float inv = 1.f / (den + 1e-16f);
#pragma unroll
    for (int k = 0; k < 8; ++k) acc8[k] *= inv;
  }

  bf16_t* out = acc + (size_t)d * 512 + lane * 8;
  if (accumulate) {
    float old[8];
    unpack8(*(const uint4*)out, old);
#pragma unroll
    for (int k = 0; k < 8; ++k) acc8[k] += old[k];
  }
  if (bc) {
    float bcv[8];
    *(float4*)(bcv)     = *(const float4*)(bc + lane * 8);
    *(float4*)(bcv + 4) = *(const float4*)(bc + lane * 8 + 4);
#pragma unroll
    for (int k = 0; k < 8; ++k)
      acc8[k] = fmaxf(fmaf(acc8[k], inv_div, bcv[k]), 0.f);
  }
  uint4 s;
  s.x = pack2(acc8[0], acc8[1]); s.y = pack2(acc8[2], acc8[3]);
  s.z = pack2(acc8[4], acc8[5]); s.w = pack2(acc8[6], acc8[7]);
  *(uint4*)out = s;
}

// afh = relu(answer_features @ W1 + b1) -> bf16, K=6, M=64
__global__ __launch_bounds__(256) void af_hidden(
    const float* __restrict__ af, const float* __restrict__ W1,
    const float* __restrict__ b1, bf16_t* __restrict__ out, int n)
{
  int t = blockIdx.x * blockDim.x + threadIdx.x;
  if (t >= n * 64) return;
  int i = t >> 6, j = t & 63;
  const float* a = af + (size_t)i * 6;
  float s = b1[j];
#pragma unroll
  for (int k = 0; k < 6; ++k) s = fmaf(a[k], W1[k * 64 + j], s);
  out[t] = (bf16_t)f2bf(fmaxf(s, 0.f));
}

__global__ __launch_bounds__(256) void build_sim(
    const int* __restrict__ ei, int* __restrict__ ss, int* __restrict__ sd)
{
  int t = blockIdx.x * blockDim.x + threadIdx.x;
  if (t >= E_SIM + NQ) return;
  if (t < E_SIM) { ss[t] = ei[t]; sd[t] = ei[E_SIM + t]; }
  else           { ss[t] = t - E_SIM; sd[t] = t - E_SIM; }
}

__global__ __launch_bounds__(256) void head_final(
    const float* __restrict__ qpre, const float* __restrict__ rpre,
    const float* __restrict__ qg, const float* __restrict__ qb,
    const float* __restrict__ rg, const float* __restrict__ rb,
    const float* __restrict__ score_bias, float* __restrict__ out, int E)
{
  int e = blockIdx.x * 4 + (threadIdx.x >> 6);
  if (e >= E) return;
  int lane = threadIdx.x & 63;

  float4 q = *(const float4*)(qpre + (size_t)e * 256 + lane * 4);
  float s = q.x + q.y + q.z + q.w;
#pragma unroll
  for (int m = 32; m >= 1; m >>= 1) s += __shfl_xor(s, m);
  float mu = s * (1.f / 256.f);
  float dq0 = q.x - mu, dq1 = q.y - mu, dq2 = q.z - mu, dq3 = q.w - mu;
  float v = dq0 * dq0 + dq1 * dq1 + dq2 * dq2 + dq3 * dq3;
#pragma unroll
  for (int m = 32; m >= 1; m >>= 1) v += __shfl_xor(v, m);
  float rstd = rsqrtf(v * (1.f / 256.f) + 1e-5f);
  float4 g4 = *(const float4*)(qg + lane * 4);
  float4 b4 = *(const float4*)(qb + lane * 4);
  float qn0 = dq0 * rstd * g4.x + b4.x, qn1 = dq1 * rstd * g4.y + b4.y;
  float qn2 = dq2 * rstd * g4.z + b4.z, qn3 = dq3 * rstd * g4.w + b4.w;

  float4 r = *(const float4*)(rpre + (size_t)e * 256 + lane * 4);
  s = r.x + r.y + r.z + r.w;
#pragma unroll
  for (int m = 32; m >= 1; m >>= 1) s += __shfl_xor(s, m);
  mu = s * (1.f / 256.f);
  float dr0 = r.x - mu, dr1 = r.y - mu, dr2 = r.z - mu, dr3 = r.w - mu;
  v = dr0 * dr0 + dr1 * dr1 + dr2 * dr2 + dr3 * dr3;
#pragma unroll
  for (int m = 32; m >= 1; m >>= 1) v += __shfl_xor(v, m);
  rstd = rsqrtf(v * (1.f / 256.f) + 1e-5f);
  g4 = *(const float4*)(rg + lane * 4);
  b4 = *(const float4*)(rb + lane * 4);
  float rn0 = dr0 * rstd * g4.x + b4.x, rn1 = dr1 * rstd * g4.y + b4.y;
  float rn2 = dr2 * rstd * g4.z + b4.z, rn3 = dr3 * rstd * g4.w + b4.w;

  float d = qn0 * rn0 + qn1 * rn1 + qn2 * rn2 + qn3 * rn3;
#pragma unroll
  for (int m = 32; m >= 1; m >>= 1) d += __shfl_xor(d, m);
  if (lane == 0) out[e] = d * 0.0625f + score_bias[0];
}

// ---------------------------------------------------------------------------
extern "C" void kernel_launch(void* const* d_in, const int* in_sizes, int n_in,
                              void* d_out, int out_size, void* d_ws, size_t ws_size,
                              hipStream_t stream) {
  (void)in_sizes; (void)n_in; (void)out_size;
  const float* xq      = (const float*)d_in[0];
  const float* xt      = (const float*)d_in[1];
  const float* xa      = (const float*)d_in[2];
  const float* af      = (const float*)d_in[3];
  const float* qp_W    = (const float*)d_in[4];
  const float* qp_b    = (const float*)d_in[5];
  const float* tp_W    = (const float*)d_in[6];
  const float* tp_b    = (const float*)d_in[7];
  const float* ap_W    = (const float*)d_in[8];
  const float* ap_b    = (const float*)d_in[9];
  const float* afp_W1  = (const float*)d_in[10];
  const float* afp_b1  = (const float*)d_in[11];
  const float* afp_W2  = (const float*)d_in[12];
  const float* afp_b2  = (const float*)d_in[13];
  const float* conv_Wl = (const float*)d_in[14];
  const float* conv_bl = (const float*)d_in[15];
  const float* conv_Wr = (const float*)d_in[16];
  const float* conv_br = (const float*)d_in[17];
  const float* conv_att  = (const float*)d_in[18];
  const float* conv_bias = (const float*)d_in[19];
  const float* qh_W    = (const float*)d_in[20];
  const float* qh_b    = (const float*)d_in[21];
  const float* qh_g    = (const float*)d_in[22];
  const float* qh_beta = (const float*)d_in[23];
  const float* rh_W    = (const float*)d_in[24];
  const float* rh_b    = (const float*)d_in[25];
  const float* rh_g    = (const float*)d_in[26];
  const float* rh_beta = (const float*)d_in[27];
  const float* score_b = (const float*)d_in[28];
  const int* ei_gr   = (const int*)d_in[29];
  const int* ei_lt   = (const int*)d_in[30];
  const int* ei_sim  = (const int*)d_in[31];
  const int* ei_comp = (const int*)d_in[32];
  const int* ei_gen  = (const int*)d_in[33];

  char* base = (char*)d_ws;
  size_t off = 0;
  auto alloc = [&](size_t bytes) {
    void* p = base + off;
    off = (off + bytes + 255) & ~(size_t)255;
    return p;
  };
  bf16_t* hq   = (bf16_t*)alloc((size_t)NQ * 512 * 2);
  bf16_t* ht   = (bf16_t*)alloc((size_t)NT * 512 * 2);
  bf16_t* ha   = (bf16_t*)alloc((size_t)NA * 512 * 2);
  bf16_t* acct = (bf16_t*)alloc((size_t)NT * 512 * 2);   // ht ping-pong; qpre f32
  bf16_t* accq = (bf16_t*)alloc((size_t)NQ * 512 * 2);   // xq-cast; hq ping-pong; afh
  bf16_t* xlb  = (bf16_t*)alloc((size_t)50000 * 512 * 2);// staging/af_emb
  bf16_t* xrb  = (bf16_t*)alloc((size_t)50000 * 512 * 2);// compacted xr; rpre f32
  int* simsrc  = (int*)alloc((size_t)(E_SIM + NQ) * 4);
  int* simdst  = (int*)alloc((size_t)(E_SIM + NQ) * 4);

  // bf16-transposed weights
  bf16_t* wqp  = (bf16_t*)alloc((size_t)512 * 384 * 2);
  bf16_t* wtp  = (bf16_t*)alloc((size_t)512 * 384 * 2);
  bf16_t* wap  = (bf16_t*)alloc((size_t)512 * 384 * 2);
  bf16_t* wl   = (bf16_t*)alloc((size_t)12 * 512 * 512 * 2);
  bf16_t* wr   = (bf16_t*)alloc((size_t)12 * 512 * 512 * 2);
  bf16_t* wafp2 = (bf16_t*)alloc((size_t)512 * 64 * 2);
  bf16_t* wqh  = (bf16_t*)alloc((size_t)256 * 512 * 2);
  bf16_t* wrh0 = (bf16_t*)alloc((size_t)256 * 512 * 2);  // wrh0..2 contiguous
  bf16_t* wrh1 = (bf16_t*)alloc((size_t)256 * 512 * 2);
  bf16_t* wrh2 = (bf16_t*)alloc((size_t)256 * 512 * 2);
  float* bcAll = (float*)alloc(6 * 512 * 4);

  // Fused CSR + compaction arrays
  int* degAll   = (int*)alloc((size_t)NDTOT * 4);
  int* startAll = (int*)alloc((size_t)NDTOT * 4);
  int* cposAll  = (int*)alloc((size_t)NDTOT * 4);
  int* cidxAll  = (int*)alloc((size_t)NDTOT * 4);
  int* eidxAll  = (int*)alloc((size_t)ETOT * 4);
  int* posb     = (int*)alloc((size_t)ETOT * 4);
  int* bsum     = (int*)alloc(6 * 64 * 4);
  int* bsum2    = (int*)alloc(6 * 64 * 4);
  int* ccount   = (int*)alloc(6 * 4);
  if (off > ws_size) {
    fprintf(stderr, "kernel_launch: ws too small, need %zu have %zu\n", off, ws_size);
    return;
  }

  const int degOff[6] = {0, 50000, 60000, 110000, 120000, 170000};
  const int eOff[6]   = {0, 50000, 100000, 150000, 240000, 340000};

  // --- weight conversion (4 launches) ---
  convert_wT24<<<dim3(16, 16, 24), 256, 0, stream>>>(conv_Wl, wl, conv_Wr, wr);
  convert_wT3<<<dim3(16, 12, 3), 256, 0, stream>>>(qp_W, tp_W, ap_W, wqp, wtp, wap);
  convert_wT4h<<<dim3(8, 16, 4), 256, 0, stream>>>(qh_W, rh_W, wqh, wrh0);
  convert_wT<<<dim3(16, 2, 1), 256, 0, stream>>>(afp_W2, wafp2, 64, 512);
  combine_bias6<<<(6 * 512 + 255) / 256, 256, 0, stream>>>(conv_bias, bcAll);

  // --- fused CSR build + deg>=2 compaction ---
  build_sim<<<(E_SIM + NQ + 255) / 256, 256, 0, stream>>>(ei_sim, simsrc, simdst);
  const int* dsts[6] = {ei_gr + E_GR, ei_gr, ei_lt, simdst,
                        ei_comp + E_COMP, ei_lt + E_LT};
  hipMemsetAsync(degAll, 0, (size_t)NDTOT * 4, stream);
  hist6<<<(ETOT + 255) / 256, 256, 0, stream>>>(dsts[0], dsts[1], dsts[2],
      dsts[3], dsts[4], dsts[5], degAll, posb);
  scan1_6<0><<<216, 256, 0, stream>>>(degAll, startAll, bsum);
  scan1_6<1><<<216, 256, 0, stream>>>(degAll, cposAll, bsum2);
  scan2_6<<<6, 64, 0, stream>>>(bsum, nullptr);
  scan2_6<<<6, 64, 0, stream>>>(bsum2, ccount);
  scan3_6<<<(NDTOT + 255) / 256, 256, 0, stream>>>(startAll, bsum);
  scan3_6<<<(NDTOT + 255) / 256, 256, 0, stream>>>(cposAll, bsum2);
  scatter6<<<(ETOT + 255) / 256, 256, 0, stream>>>(dsts[0], dsts[1], dsts[2],
      dsts[3], dsts[4], dsts[5], startAll, posb, eidxAll);
  compact6<<<(NDTOT + 255) / 256, 256, 0, stream>>>(degAll, cposAll, cidxAll);

  auto gemm1 = [&](const bf16_t* A, const bf16_t* Bt, const float* bias, bf16_t* C,
                   int N_, int K_, int M_, const int* ridx = nullptr) {
    dim3 g(M_ / 256, (N_ + 127) / 128, 1);
    bgemm<bf16_t><<<g, 512, 0, stream>>>(A, Bt, bias, C, ridx, N_, nullptr,
                                         A, Bt, bias, C, ridx, N_, nullptr,
                                         K_, M_, 0);
  };
  auto gemmf1 = [&](const bf16_t* A, const bf16_t* Bt, const float* bias, float* C,
                    int N_, int K_, int M_, int acc_, const int* ridx = nullptr) {
    dim3 g(M_ / 256, (N_ + 127) / 128, 1);
    bgemm<float><<<g, 512, 0, stream>>>(A, Bt, bias, C, ridx, N_, nullptr,
                                        A, Bt, bias, C, ridx, N_, nullptr,
                                        K_, M_, acc_);
  };
  auto gemm2 = [&](const bf16_t* A0, const bf16_t* B0, const float* b0, bf16_t* C0, int N0_,
                   const bf16_t* A1, const bf16_t* B1, const float* b1, bf16_t* C1, int N1_,
                   int K_, int M_) {
    int nb0 = (N0_ + 127) / 128, nb1 = (N1_ + 127) / 128;
    dim3 g(M_ / 256, nb0 > nb1 ? nb0 : nb1, 2);
    bgemm<bf16_t><<<g, 512, 0, stream>>>(A0, B0, b0, C0, nullptr, N0_, nullptr,
                                         A1, B1, b1, C1, nullptr, N1_, nullptr,
                                         K_, M_, 0);
  };
  // z-paired conv GEMM: z0 = xl (static N), z1 = compacted xr (dynamic N)
  auto gemm2c = [&](const bf16_t* A0, const bf16_t* B0, const float* b0, bf16_t* C0, int N0_,
                    const bf16_t* A1, const bf16_t* B1, const float* b1, bf16_t* C1,
                    const int* cidx, int N1max, const int* Ncnt) {
    int nb0 = (N0_ + 127) / 128, nb1 = (N1max + 127) / 128;
    dim3 g(2, nb0 > nb1 ? nb0 : nb1, 2);
    bgemm<bf16_t><<<g, 512, 0, stream>>>(A0, B0, b0, C0, nullptr, N0_, nullptr,
                                         A1, B1, b1, C1, cidx, N1max, Ncnt,
                                         512, 512, 0);
  };
  auto gemmf2 = [&](const bf16_t* A0, const bf16_t* B0, const float* b0, float* C0,
                    const int* r0, int N0_,
                    const bf16_t* A1, const bf16_t* B1, const float* b1, float* C1,
                    const int* r1, int N1_, int K_, int M_) {
    int nb0 = (N0_ + 127) / 128, nb1 = (N1_ + 127) / 128;
    dim3 g(M_ / 256, nb0 > nb1 ? nb0 : nb1, 2);
    bgemm<float><<<g, 512, 0, stream>>>(A0, B0, b0, C0, r0, N0_, nullptr,
                                        A1, B1, b1, C1, r1, N1_, nullptr,
                                        K_, M_, 0);
  };

  // Input projections: ONE fused cast (xq->accq scratch, xt->xlb, xa->xrb).
  cast3<<<((long)(N4_XQ + N4_XT + N4_XA) + 255) / 256, 256, 0, stream>>>(
      xq, xt, xa, accq, xlb, xrb);
  gemm1(accq, wqp, qp_b, hq, NQ, 384, 512);
  gemm2(xlb, wtp, tp_b, ht, NT, xrb, wap, ap_b, ha, NA, 384, 512);

  // Layer loop. Rel order (CSR index r): 0=gr 1=rgr 2=rlt 3=sim 4=comp 5=lt
  const int* srcs[6] = {ei_gr, ei_gr + E_GR, ei_lt + E_LT, simsrc,
                        ei_comp, ei_lt};
  const int NdArr[6] = {NT, NQ, NT, NQ, NT, NA};
  bf16_t *hq_i = hq, *ht_i = ht, *hq_o = accq, *ht_o = acct;
  for (int l = 0; l < 2; ++l) {
    const float* bc_t = bcAll + (size_t)(l * 3 + 0) * 512;
    const float* bc_q = bcAll + (size_t)(l * 3 + 1) * 512;
    const float* bc_a = bcAll + (size_t)(l * 3 + 2) * 512;

    struct Rel { const bf16_t* xs; const bf16_t* xd; int Ns, po; bf16_t* acc;
                 int accum; const float* bc; float inv; };
    Rel rels[6] = {
      {hq_i, ht_i, NQ, 0, ht_o, 0, nullptr, 0.f},      // gr
      {ht_i, hq_i, NT, 1, hq_o, 0, nullptr, 0.f},      // rgr
      {ha,   ht_i, NA, 3, ht_o, 1, nullptr, 0.f},      // rlt
      {hq_i, hq_i, NQ, 4, hq_o, 1, bc_q, 0.5f},        // sim (final for q)
      {ht_i, ht_i, NT, 5, ht_o, 1, bc_t, 1.f / 3.f},   // comp (final for t)
      {ht_i, ha,   NT, 2, ha,   0, bc_a, 1.f},         // lt (final for a)
    };
    for (int r = 0; r < 6; ++r) {
      const Rel& R = rels[r];
      int Nd_ = NdArr[r];
      size_t po = (size_t)l * 6 + R.po;
      // z0: xl over all Ns rows; z1: xr over compacted deg>=2 rows only.
      gemm2c(R.xs, wl + po * 512 * 512, conv_bl + po * 512, xlb, R.Ns,
             R.xd, wr + po * 512 * 512, conv_br + po * 512, xrb,
             cidxAll + degOff[r], Nd_, ccount + r);
      int gb = (Nd_ + 3) / 4;
      gat_fused<<<gb, 256, 0, stream>>>(xlb, xrb, srcs[r],
                                        startAll + degOff[r], degAll + degOff[r],
                                        eidxAll + eOff[r], cposAll + degOff[r],
                                        conv_att + po * 512,
                                        R.acc, Nd_, R.accum, R.bc, R.inv);
    }
    bf16_t* t;
    t = hq_i; hq_i = hq_o; hq_o = t;
    t = ht_i; ht_i = ht_o; ht_o = t;
  }

  // Head: gathers fused via ridx; qpre/rpre-first z-paired.
  float* qpre = (float*)acct;
  float* rpre = (float*)xrb;
  bf16_t* afh = accq;
  const int* gsrc = ei_gen;
  const int* gdst = ei_gen + E_GEN;

  gemmf2(hq_i, wqh, qh_b, qpre, gsrc, E_GEN,
         ht_i, wrh0, rh_b, rpre, gdst, E_GEN, 512, 256);    // q_emb | t_emb
  gemmf1(ha, wrh1, nullptr, rpre, E_GEN, 512, 256, 1, gdst); // + a_emb
  af_hidden<<<(E_GEN * 64 + 255) / 256, 256, 0, stream>>>(af, afp_W1, afp_b1,
                                                          afh, E_GEN);
  gemm1(afh, wafp2, afp_b2, xlb, E_GEN, 64, 512);            // af_emb
  gemmf1(xlb, wrh2, nullptr, rpre, E_GEN, 512, 256, 1);      // + af_emb
  head_final<<<(E_GEN + 3) / 4, 256, 0, stream>>>(
      qpre, rpre, qh_g, qh_beta, rh_g, rh_beta, score_b, (float*)d_out, E_GEN);
}

// Round 20
// 1251.004 us; speedup vs baseline: 1.3726x; 1.0141x over previous
//
#include <hip/hip_runtime.h>
#include <cstdio>
#include <type_traits>

#define NQ 10000
#define NT 50000
#define NA 50000
#define E_GR 50000
#define E_LT 50000
#define E_SIM 80000
#define E_COMP 100000
#define E_GEN 50000
#define NEG_SLOPE 0.2f

// Concatenated CSR tables (compile-time). Rel order: gr, rgr, rlt, sim, comp, lt
#define NDTOT 220000
#define NSTOT 220000
#define ETOT  390000
__device__ __constant__ const int c_degOff[7]  = {0, 50000, 60000, 110000, 120000, 170000, 220000};
__device__ __constant__ const int c_sOff[7]    = {0, 10000, 60000, 110000, 120000, 170000, 220000};
__device__ __constant__ const int c_eOff[7]    = {0, 50000, 100000, 150000, 240000, 340000, 390000};
__device__ __constant__ const int c_nb[6]      = {49, 10, 49, 10, 49, 49};
__device__ __constant__ const int c_nbOff[7]   = {0, 49, 59, 108, 118, 167, 216};
__device__ __constant__ const int c_snb[6]     = {10, 49, 49, 10, 49, 49};
__device__ __constant__ const int c_snbOff[7]  = {0, 10, 59, 108, 118, 167, 216};

typedef unsigned short bf16_t;
typedef unsigned int u32;
typedef __attribute__((ext_vector_type(8))) short short8v;
typedef __attribute__((ext_vector_type(4))) float f32x4;

__device__ __forceinline__ float bf2f(u32 bits) { return __uint_as_float(bits << 16); }
__device__ __forceinline__ u32 f2bf(float f) {
  u32 u = __float_as_uint(f);
  return (u + 0x7FFFu + ((u >> 16) & 1u)) >> 16;   // RTNE
}
__device__ __forceinline__ u32 pack2(float a, float b) { return f2bf(a) | (f2bf(b) << 16); }
__device__ __forceinline__ void unpack8(uint4 u, float* f) {
  f[0] = bf2f(u.x & 0xffffu); f[1] = bf2f(u.x >> 16);
  f[2] = bf2f(u.y & 0xffffu); f[3] = bf2f(u.y >> 16);
  f[4] = bf2f(u.z & 0xffffu); f[5] = bf2f(u.z >> 16);
  f[6] = bf2f(u.w & 0xffffu); f[7] = bf2f(u.w >> 16);
}

// async global->LDS, 16B per lane; LDS dest = wave-uniform base + lane*16.
__device__ __forceinline__ void gload16(const void* g, void* l) {
  __builtin_amdgcn_global_load_lds(
      (const __attribute__((address_space(1))) void*)g,
      (__attribute__((address_space(3))) void*)l, 16, 0, 0);
}

// ---------------------------------------------------------------------------
// MFMA bf16 GEMM, z-paired (r12 banked structure, ~570 TF/GEMM).
// 128x256 tile, BK=32, 8 waves (2x4), acc[4][4]; 3x24KB LDS (2 blocks/CU),
// rotation s%3, ONE barrier/step. Both-sides octet XOR (rule #21).
// XCD-grouped band swizzle; optional ridx row gather; optional device-side
// row count Nc (grid sized for static worst case; excess blocks exit
// uniformly before any barrier; N==0 -> all exit).
// ---------------------------------------------------------------------------
template <typename CT>
__global__ __launch_bounds__(512, 4) void bgemm(
    const bf16_t* __restrict__ A0, const bf16_t* __restrict__ Bt0,
    const float* __restrict__ bias0, CT* __restrict__ C0,
    const int* __restrict__ ridx0, int N0, const int* __restrict__ Nc0,
    const bf16_t* __restrict__ A1, const bf16_t* __restrict__ Bt1,
    const float* __restrict__ bias1, CT* __restrict__ C1,
    const int* __restrict__ ridx1, int N1, const int* __restrict__ Nc1,
    int K, int M, int accumulate)
{
  __shared__ short lds[3][12288];   // [buf][A: 0..4095 | B: 4096..12287]
  const int z = blockIdx.z;
  const bf16_t* A   = z ? A1 : A0;
  const bf16_t* Bt  = z ? Bt1 : Bt0;
  const float* bias = z ? bias1 : bias0;
  CT* C             = z ? C1 : C0;
  const int* ridx   = z ? ridx1 : ridx0;
  const int* Nc     = z ? Nc1 : Nc0;
  int N             = z ? N1 : N0;
  if (Nc) N = *Nc;                          // dynamic compacted row count

  const int tid = threadIdx.x;
  const int ncol = gridDim.x;
  const int nband = (N + 127) >> 7;
  int lin = blockIdx.y * ncol + blockIdx.x;
  if (lin >= ncol * nband) return;          // uniform exit, before barriers

  int band, col;
  const int full = (nband >> 3) * 8 * ncol;
  if (lin < full) {
    int g = lin >> 3, x = lin & 7;
    band = x + 8 * (g / ncol);
    col  = g % ncol;
  } else {
    int r = lin - full;
    band = (nband & ~7) + r / ncol;
    col  = r % ncol;
  }
  const int bm = band * 128, bn = col * 256;

  const int lane = tid & 63;
  const int w = tid >> 6;
  const int wr = w >> 2, wc = w & 3;
  const int fr = lane & 15, fg = lane >> 4;

  const int kg = (((tid & 3) ^ ((tid >> 3) & 3)) << 3);
  const int rr = tid >> 2;
  int ra = min(bm + rr, N - 1);
  const bf16_t* gA0 = A + (size_t)(ridx ? ridx[ra] : ra) * K + kg;
  const bf16_t* gB0 = Bt + (size_t)(bn + rr) * K + kg;
  const bf16_t* gB1 = Bt + (size_t)(bn + 128 + rr) * K + kg;
  const int wb = w << 9;

  f32x4 acc[4][4];
#pragma unroll
  for (int i = 0; i < 4; ++i)
#pragma unroll
    for (int j = 0; j < 4; ++j) acc[i][j] = (f32x4){0.f, 0.f, 0.f, 0.f};

  auto stage = [&](int buf, int k0) {
    short* base = &lds[buf][0];
    gload16(gA0 + k0, base + wb);
    gload16(gB0 + k0, base + 4096 + wb);
    gload16(gB1 + k0, base + 8192 + wb);
  };

  const int nsteps = K >> 5;
  stage(0, 0);
  const int co = (fg ^ ((fr >> 1) & 3)) << 3;
  for (int s = 0; s < nsteps; ++s) {
    const int cur = s % 3;
    if (s + 1 < nsteps) {
      stage((s + 1) % 3, (s + 1) << 5);
      asm volatile("s_waitcnt vmcnt(3)" ::: "memory");
    } else {
      asm volatile("s_waitcnt vmcnt(0)" ::: "memory");
    }
    __builtin_amdgcn_s_barrier();
    asm volatile("" ::: "memory");
    const short* LA = &lds[cur][0];
    const short* LB = &lds[cur][4096];
    short8v b[4];
#pragma unroll
    for (int j = 0; j < 4; ++j) {
      int R = wc * 64 + j * 16 + fr;
      b[j] = *(const short8v*)&LB[R * 32 + co];
    }
#pragma unroll
    for (int i = 0; i < 4; ++i) {
      int R = wr * 64 + i * 16 + fr;
      short8v a = *(const short8v*)&LA[R * 32 + co];
#pragma unroll
      for (int j = 0; j < 4; ++j)
        acc[i][j] = __builtin_amdgcn_mfma_f32_16x16x32_bf16(b[j], a,
                                                            acc[i][j], 0, 0, 0);
    }
    asm volatile("" ::: "memory");
  }

  float4 bv[4];
#pragma unroll
  for (int j = 0; j < 4; ++j) {
    bv[j] = make_float4(0.f, 0.f, 0.f, 0.f);
    if (!accumulate && bias)
      bv[j] = *(const float4*)(bias + bn + wc * 64 + j * 16 + fg * 4);
  }
#pragma unroll
  for (int i = 0; i < 4; ++i) {
    const int n = bm + wr * 64 + i * 16 + fr;
    if (n >= N) continue;
#pragma unroll
    for (int j = 0; j < 4; ++j) {
      const int m0 = bn + wc * 64 + j * 16 + fg * 4;
      f32x4 v = acc[i][j];
      if constexpr (std::is_same<CT, float>::value) {
        float* p = C + (size_t)n * M + m0;
        if (accumulate) {
          float4 o = *(float4*)p;
          o.x += v[0]; o.y += v[1]; o.z += v[2]; o.w += v[3];
          *(float4*)p = o;
        } else {
          *(float4*)p = make_float4(v[0] + bv[j].x, v[1] + bv[j].y,
                                    v[2] + bv[j].z, v[3] + bv[j].w);
        }
      } else {
        uint2 o;
        o.x = pack2(v[0] + bv[j].x, v[1] + bv[j].y);
        o.y = pack2(v[2] + bv[j].z, v[3] + bv[j].w);
        *(uint2*)(C + (size_t)n * M + m0) = o;
      }
    }
  }
}

// core transpose tile: fp32 W[K][M] slice -> bf16 Wt[M][K] slice
__device__ __forceinline__ void wT_tile(
    const float* __restrict__ W, bf16_t* __restrict__ Wt, int K, int M)
{
  __shared__ float sm[32][33];
  int mb = blockIdx.x * 32, kb = blockIdx.y * 32;
  int tx = threadIdx.x & 31, ty = threadIdx.x >> 5;
#pragma unroll
  for (int i = 0; i < 4; ++i)
    sm[ty + i * 8][tx] = W[(size_t)(kb + ty + i * 8) * M + mb + tx];
  __syncthreads();
#pragma unroll
  for (int i = 0; i < 4; ++i)
    Wt[(size_t)(mb + ty + i * 8) * K + kb + tx] = (bf16_t)f2bf(sm[tx][ty + i * 8]);
}

__global__ __launch_bounds__(256) void convert_wT(
    const float* __restrict__ W, bf16_t* __restrict__ Wt, int K, int M)
{
  wT_tile(W + (size_t)blockIdx.z * K * M, Wt + (size_t)blockIdx.z * K * M, K, M);
}
__global__ __launch_bounds__(256) void convert_wT24(
    const float* __restrict__ Wl, bf16_t* __restrict__ wl,
    const float* __restrict__ Wr, bf16_t* __restrict__ wr)
{
  int z = blockIdx.z;
  size_t o = (size_t)(z < 12 ? z : z - 12) * 512 * 512;
  if (z < 12) wT_tile(Wl + o, wl + o, 512, 512);
  else        wT_tile(Wr + o, wr + o, 512, 512);
}
__global__ __launch_bounds__(256) void convert_wT3(
    const float* __restrict__ W0, const float* __restrict__ W1,
    const float* __restrict__ W2, bf16_t* __restrict__ T0,
    bf16_t* __restrict__ T1, bf16_t* __restrict__ T2)
{
  int z = blockIdx.z;
  const float* W = z == 0 ? W0 : z == 1 ? W1 : W2;
  bf16_t* T = z == 0 ? T0 : z == 1 ? T1 : T2;
  wT_tile(W, T, 384, 512);
}
__global__ __launch_bounds__(256) void convert_wT4h(
    const float* __restrict__ qh, const float* __restrict__ rh,
    bf16_t* __restrict__ wqh, bf16_t* __restrict__ wrh)
{
  int z = blockIdx.z;
  if (z == 0) wT_tile(qh, wqh, 512, 256);
  else        wT_tile(rh + (size_t)(z - 1) * 512 * 256,
                      wrh + (size_t)(z - 1) * 256 * 512, 512, 256);
}

// fused input casts: xq->xqb, xt->xlb, xa->xrb (float4 granularity)
#define N4_XQ (NQ * 96)
#define N4_XT (NT * 96)
#define N4_XA (NA * 96)
__global__ __launch_bounds__(256) void cast3(
    const float* __restrict__ xq, const float* __restrict__ xt,
    const float* __restrict__ xa, bf16_t* __restrict__ xqb,
    bf16_t* __restrict__ xtb, bf16_t* __restrict__ xab)
{
  long g = (long)blockIdx.x * 256 + threadIdx.x;
  const float* in; bf16_t* out; long idx;
  if (g < N4_XQ)                { in = xq; out = xqb; idx = g; }
  else if (g < N4_XQ + N4_XT)   { in = xt; out = xtb; idx = g - N4_XQ; }
  else if (g < N4_XQ + N4_XT + N4_XA) { in = xa; out = xab; idx = g - N4_XQ - N4_XT; }
  else return;
  float4 v = ((const float4*)in)[idx];
  uint2 o;
  o.x = pack2(v.x, v.y);
  o.y = pack2(v.z, v.w);
  ((uint2*)out)[idx] = o;
}

__global__ __launch_bounds__(256) void combine_bias6(
    const float* __restrict__ cb, float* __restrict__ bcAll)
{
  int g = blockIdx.x * 256 + threadIdx.x;
  if (g >= 6 * 512) return;
  int row = g >> 9, j = g & 511;
  int l = row / 3, kind = row % 3;
  const float* b = cb + (size_t)l * 6 * 512;
  float v;
  if (kind == 0)      v = (b[0 * 512 + j] + b[3 * 512 + j] + b[5 * 512 + j]) / 3.f;
  else if (kind == 1) v = (b[1 * 512 + j] + b[4 * 512 + j]) * 0.5f;
  else                v = b[2 * 512 + j];
  bcAll[(size_t)row * 512 + j] = v;
}

// ---------------------------------------------------------------------------
// Fused CSR build + dst deg>=2 compaction + src outdeg>=1 compaction.
// ---------------------------------------------------------------------------
__device__ __forceinline__ int find_rel6(int g, const int* off) {
  int r = 0;
#pragma unroll
  for (int k = 1; k < 6; ++k) r += (g >= off[k]);
  return r;
}

__global__ __launch_bounds__(256) void hist6(
    const int* __restrict__ d0, const int* __restrict__ d1,
    const int* __restrict__ d2, const int* __restrict__ d3,
    const int* __restrict__ d4, const int* __restrict__ d5,
    const int* __restrict__ s0p, const int* __restrict__ s1p,
    const int* __restrict__ s2p, const int* __restrict__ s3p,
    const int* __restrict__ s4p, const int* __restrict__ s5p,
    int* __restrict__ degAll, int* __restrict__ sdegAll, int* __restrict__ pos)
{
  int g = blockIdx.x * 256 + threadIdx.x;
  if (g >= ETOT) return;
  int r = find_rel6(g, c_eOff);
  int le = g - c_eOff[r];
  const int* dp = r == 0 ? d0 : r == 1 ? d1 : r == 2 ? d2 : r == 3 ? d3
                : r == 4 ? d4 : d5;
  const int* sp = r == 0 ? s0p : r == 1 ? s1p : r == 2 ? s2p : r == 3 ? s3p
                : r == 4 ? s4p : s5p;
  pos[g] = atomicAdd(&degAll[c_degOff[r] + dp[le]], 1);
  atomicAdd(&sdegAll[c_sOff[r] + sp[le]], 1);
}

// PRED==0: raw scan (CSR starts). PRED==1: deg>=2. PRED==2: deg>=1.
// SRC selects the src-space tables.
template <int PRED, int SRC>
__global__ __launch_bounds__(256) void scan1_6(
    const int* __restrict__ in, int* __restrict__ out, int* __restrict__ bsum)
{
  __shared__ int sm[256];
  int b = blockIdx.x;
  const int* nbOff = SRC ? c_snbOff : c_nbOff;
  const int* dOff  = SRC ? c_sOff : c_degOff;
  int r = 0;
#pragma unroll
  for (int k = 1; k < 6; ++k) r += (b >= nbOff[k]);
  int lb = b - nbOff[r];
  int base0 = dOff[r], n = dOff[r + 1] - base0;
  int t = threadIdx.x;
  int base = lb * 1024 + t * 4;
  int v[4], sum = 0;
#pragma unroll
  for (int k = 0; k < 4; ++k) {
    int raw = (base + k < n) ? in[base0 + base + k] : 0;
    v[k] = PRED == 0 ? raw : PRED == 1 ? (raw >= 2 ? 1 : 0) : (raw >= 1 ? 1 : 0);
    sum += v[k];
  }
  sm[t] = sum;
  __syncthreads();
  for (int off = 1; off < 256; off <<= 1) {
    int x = (t >= off) ? sm[t - off] : 0;
    __syncthreads();
    sm[t] += x;
    __syncthreads();
  }
  int run = (t > 0) ? sm[t - 1] : 0;
  if (t == 255) bsum[r * 64 + lb] = sm[255];
#pragma unroll
  for (int k = 0; k < 4; ++k) {
    if (base + k < n) out[base0 + base + k] = run;
    run += v[k];
  }
}

// exclusive across blocks; optional per-relation totals. SRC picks nb table.
template <int SRC>
__global__ __launch_bounds__(64) void scan2_6(
    int* __restrict__ bsum, int* __restrict__ total)
{
  __shared__ int sm[64];
  int r = blockIdx.x;
  int nb = SRC ? c_snb[r] : c_nb[r];
  int t = threadIdx.x;
  int v = (t < nb) ? bsum[r * 64 + t] : 0;
  sm[t] = v;
  __syncthreads();
  for (int off = 1; off < 64; off <<= 1) {
    int x = (t >= off) ? sm[t - off] : 0;
    __syncthreads();
    sm[t] += x;
    __syncthreads();
  }
  if (t < nb) bsum[r * 64 + t] = sm[t] - v;   // exclusive
  if (total && t == nb - 1) total[r] = sm[t]; // inclusive total
}

template <int SRC>
__global__ __launch_bounds__(256) void scan3_6(
    int* __restrict__ out, const int* __restrict__ bsum)
{
  int g = blockIdx.x * 256 + threadIdx.x;
  if (g >= (SRC ? NSTOT : NDTOT)) return;
  const int* dOff = SRC ? c_sOff : c_degOff;
  int r = find_rel6(g, dOff);
  int ln = g - dOff[r];
  out[g] += bsum[r * 64 + (ln >> 10)];
}

// scatter CSR edge ids AND remap edge srcs to compacted xl rows.
__global__ __launch_bounds__(256) void scatter6(
    const int* __restrict__ d0, const int* __restrict__ d1,
    const int* __restrict__ d2, const int* __restrict__ d3,
    const int* __restrict__ d4, const int* __restrict__ d5,
    const int* __restrict__ s0p, const int* __restrict__ s1p,
    const int* __restrict__ s2p, const int* __restrict__ s3p,
    const int* __restrict__ s4p, const int* __restrict__ s5p,
    const int* __restrict__ startAll, const int* __restrict__ pos,
    const int* __restrict__ sposAll,
    int* __restrict__ eidxAll, int* __restrict__ srcCAll)
{
  int g = blockIdx.x * 256 + threadIdx.x;
  if (g >= ETOT) return;
  int r = find_rel6(g, c_eOff);
  int le = g - c_eOff[r];
  const int* dp = r == 0 ? d0 : r == 1 ? d1 : r == 2 ? d2 : r == 3 ? d3
                : r == 4 ? d4 : d5;
  const int* sp = r == 0 ? s0p : r == 1 ? s1p : r == 2 ? s2p : r == 3 ? s3p
                : r == 4 ? s4p : s5p;
  eidxAll[c_eOff[r] + startAll[c_degOff[r] + dp[le]] + pos[g]] = le;
  srcCAll[g] = sposAll[c_sOff[r] + sp[le]];
}

// cidx[cpos] = local node index, for nodes passing threshold. SRC picks space.
template <int SRC, int THR>
__global__ __launch_bounds__(256) void compact6(
    const int* __restrict__ degA, const int* __restrict__ cposA,
    int* __restrict__ cidxA)
{
  int g = blockIdx.x * 256 + threadIdx.x;
  if (g >= (SRC ? NSTOT : NDTOT)) return;
  if (degA[g] >= THR) {
    const int* dOff = SRC ? c_sOff : c_degOff;
    int r = find_rel6(g, dOff);
    cidxA[dOff[r] + cposA[g]] = g - dOff[r];
  }
}

// ---------------------------------------------------------------------------
// Fused GATv2: one wave per dst node. deg==0 -> 0; deg==1 -> xl[srcC];
// deg>=2 reads compacted xr at cpos[d]. srcC is pre-remapped to compacted
// xl rows (zero extra latency in inner loop). Edge-index pipelined.
// ---------------------------------------------------------------------------
__global__ __launch_bounds__(256) void gat_fused(
    const bf16_t* __restrict__ xl, const bf16_t* __restrict__ xr,
    const int* __restrict__ srcC, const int* __restrict__ start,
    const int* __restrict__ deg, const int* __restrict__ eidx,
    const int* __restrict__ cpos, const float* __restrict__ att,
    bf16_t* __restrict__ acc, int Nd, int accumulate,
    const float* __restrict__ bc, float inv_div)
{
  int d = blockIdx.x * 4 + (threadIdx.x >> 6);
  if (d >= Nd) return;
  int lane = threadIdx.x & 63;

  float acc8[8] = {0.f, 0.f, 0.f, 0.f, 0.f, 0.f, 0.f, 0.f};
  int n = deg[d], s0 = start[d];
  if (n == 1) {
    int s = srcC[eidx[s0]];
    unpack8(*(const uint4*)(xl + (size_t)s * 512 + lane * 8), acc8);
  } else if (n > 1) {
    float xrr[8];
    unpack8(*(const uint4*)(xr + (size_t)cpos[d] * 512 + lane * 8), xrr);
    float at[8];
    *(float4*)(at)     = *(const float4*)(att + lane * 8);
    *(float4*)(at + 4) = *(const float4*)(att + lane * 8 + 4);
    float den = 0.f;
    int sN = srcC[eidx[s0]];
    for (int i = 0; i < n; ++i) {
      int s = sN;
      if (i + 1 < n) sN = srcC[eidx[s0 + i + 1]];
      float f[8];
      unpack8(*(const uint4*)(xl + (size_t)s * 512 + lane * 8), f);
      float p = 0.f;
#pragma unroll
      for (int k = 0; k < 8; ++k) {
        float x = f[k] + xrr[k];
        p = fmaf(at[k], x >= 0.f ? x : NEG_SLOPE * x, p);
      }
#pragma unroll
      for (int m = 8; m >= 1; m >>= 1) p += __shfl_xor(p, m);
      float ex = __expf(p);
      den += ex;
#pragma unroll
      for (int k = 0; k < 8; ++k) acc8[k] = fmaf(ex, f[k], acc8[k]);
    }
    float inv = 1.f / (den + 1e-16f);
#pragma unroll
    for (int k = 0; k < 8; ++k) acc8[k] *= inv;
  }

  bf16_t* out = acc + (size_t)d * 512 + lane * 8;
  if (accumulate) {
    float old[8];
    unpack8(*(const uint4*)out, old);
#pragma unroll
    for (int k = 0; k < 8; ++k) acc8[k] += old[k];
  }
  if (bc) {
    float bcv[8];
    *(float4*)(bcv)     = *(const float4*)(bc + lane * 8);
    *(float4*)(bcv + 4) = *(const float4*)(bc + lane * 8 + 4);
#pragma unroll
    for (int k = 0; k < 8; ++k)
      acc8[k] = fmaxf(fmaf(acc8[k], inv_div, bcv[k]), 0.f);
  }
  uint4 s;
  s.x = pack2(acc8[0], acc8[1]); s.y = pack2(acc8[2], acc8[3]);
  s.z = pack2(acc8[4], acc8[5]); s.w = pack2(acc8[6], acc8[7]);
  *(uint4*)out = s;
}

// afh = relu(answer_features @ W1 + b1) -> bf16, K=6, M=64
__global__ __launch_bounds__(256) void af_hidden(
    const float* __restrict__ af, const float* __restrict__ W1,
    const float* __restrict__ b1, bf16_t* __restrict__ out, int n)
{
  int t = blockIdx.x * blockDim.x + threadIdx.x;
  if (t >= n * 64) return;
  int i = t >> 6, j = t & 63;
  const float* a = af + (size_t)i * 6;
  float s = b1[j];
#pragma unroll
  for (int k = 0; k < 6; ++k) s = fmaf(a[k], W1[k * 64 + j], s);
  out[t] = (bf16_t)f2bf(fmaxf(s, 0.f));
}

__global__ __launch_bounds__(256) void build_sim(
    const int* __restrict__ ei, int* __restrict__ ss, int* __restrict__ sd)
{
  int t = blockIdx.x * blockDim.x + threadIdx.x;
  if (t >= E_SIM + NQ) return;
  if (t < E_SIM) { ss[t] = ei[t]; sd[t] = ei[E_SIM + t]; }
  else           { ss[t] = t - E_SIM; sd[t] = t - E_SIM; }
}

__global__ __launch_bounds__(256) void head_final(
    const float* __restrict__ qpre, const float* __restrict__ rpre,
    const float* __restrict__ qg, const float* __restrict__ qb,
    const float* __restrict__ rg, const float* __restrict__ rb,
    const float* __restrict__ score_bias, float* __restrict__ out, int E)
{
  int e = blockIdx.x * 4 + (threadIdx.x >> 6);
  if (e >= E) return;
  int lane = threadIdx.x & 63;

  float4 q = *(const float4*)(qpre + (size_t)e * 256 + lane * 4);
  float s = q.x + q.y + q.z + q.w;
#pragma unroll
  for (int m = 32; m >= 1; m >>= 1) s += __shfl_xor(s, m);
  float mu = s * (1.f / 256.f);
  float dq0 = q.x - mu, dq1 = q.y - mu, dq2 = q.z - mu, dq3 = q.w - mu;
  float v = dq0 * dq0 + dq1 * dq1 + dq2 * dq2 + dq3 * dq3;
#pragma unroll
  for (int m = 32; m >= 1; m >>= 1) v += __shfl_xor(v, m);
  float rstd = rsqrtf(v * (1.f / 256.f) + 1e-5f);
  float4 g4 = *(const float4*)(qg + lane * 4);
  float4 b4 = *(const float4*)(qb + lane * 4);
  float qn0 = dq0 * rstd * g4.x + b4.x, qn1 = dq1 * rstd * g4.y + b4.y;
  float qn2 = dq2 * rstd * g4.z + b4.z, qn3 = dq3 * rstd * g4.w + b4.w;

  float4 r = *(const float4*)(rpre + (size_t)e * 256 + lane * 4);
  s = r.x + r.y + r.z + r.w;
#pragma unroll
  for (int m = 32; m >= 1; m >>= 1) s += __shfl_xor(s, m);
  mu = s * (1.f / 256.f);
  float dr0 = r.x - mu, dr1 = r.y - mu, dr2 = r.z - mu, dr3 = r.w - mu;
  v = dr0 * dr0 + dr1 * dr1 + dr2 * dr2 + dr3 * dr3;
#pragma unroll
  for (int m = 32; m >= 1; m >>= 1) v += __shfl_xor(v, m);
  rstd = rsqrtf(v * (1.f / 256.f) + 1e-5f);
  g4 = *(const float4*)(rg + lane * 4);
  b4 = *(const float4*)(rb + lane * 4);
  float rn0 = dr0 * rstd * g4.x + b4.x, rn1 = dr1 * rstd * g4.y + b4.y;
  float rn2 = dr2 * rstd * g4.z + b4.z, rn3 = dr3 * rstd * g4.w + b4.w;

  float d = qn0 * rn0 + qn1 * rn1 + qn2 * rn2 + qn3 * rn3;
#pragma unroll
  for (int m = 32; m >= 1; m >>= 1) d += __shfl_xor(d, m);
  if (lane == 0) out[e] = d * 0.0625f + score_bias[0];
}

// ---------------------------------------------------------------------------
extern "C" void kernel_launch(void* const* d_in, const int* in_sizes, int n_in,
                              void* d_out, int out_size, void* d_ws, size_t ws_size,
                              hipStream_t stream) {
  (void)in_sizes; (void)n_in; (void)out_size;
  const float* xq      = (const float*)d_in[0];
  const float* xt      = (const float*)d_in[1];
  const float* xa      = (const float*)d_in[2];
  const float* af      = (const float*)d_in[3];
  const float* qp_W    = (const float*)d_in[4];
  const float* qp_b    = (const float*)d_in[5];
  const float* tp_W    = (const float*)d_in[6];
  const float* tp_b    = (const float*)d_in[7];
  const float* ap_W    = (const float*)d_in[8];
  const float* ap_b    = (const float*)d_in[9];
  const float* afp_W1  = (const float*)d_in[10];
  const float* afp_b1  = (const float*)d_in[11];
  const float* afp_W2  = (const float*)d_in[12];
  const float* afp_b2  = (const float*)d_in[13];
  const float* conv_Wl = (const float*)d_in[14];
  const float* conv_bl = (const float*)d_in[15];
  const float* conv_Wr = (const float*)d_in[16];
  const float* conv_br = (const float*)d_in[17];
  const float* conv_att  = (const float*)d_in[18];
  const float* conv_bias = (const float*)d_in[19];
  const float* qh_W    = (const float*)d_in[20];
  const float* qh_b    = (const float*)d_in[21];
  const float* qh_g    = (const float*)d_in[22];
  const float* qh_beta = (const float*)d_in[23];
  const float* rh_W    = (const float*)d_in[24];
  const float* rh_b    = (const float*)d_in[25];
  const float* rh_g    = (const float*)d_in[26];
  const float* rh_beta = (const float*)d_in[27];
  const float* score_b = (const float*)d_in[28];
  const int* ei_gr   = (const int*)d_in[29];
  const int* ei_lt   = (const int*)d_in[30];
  const int* ei_sim  = (const int*)d_in[31];
  const int* ei_comp = (const int*)d_in[32];
  const int* ei_gen  = (const int*)d_in[33];

  char* base = (char*)d_ws;
  size_t off = 0;
  auto alloc = [&](size_t bytes) {
    void* p = base + off;
    off = (off + bytes + 255) & ~(size_t)255;
    return p;
  };
  bf16_t* hq   = (bf16_t*)alloc((size_t)NQ * 512 * 2);
  bf16_t* ht   = (bf16_t*)alloc((size_t)NT * 512 * 2);
  bf16_t* ha   = (bf16_t*)alloc((size_t)NA * 512 * 2);
  bf16_t* acct = (bf16_t*)alloc((size_t)NT * 512 * 2);   // ht ping-pong; qpre f32
  bf16_t* accq = (bf16_t*)alloc((size_t)NQ * 512 * 2);   // xq-cast; hq ping-pong; afh
  bf16_t* xlb  = (bf16_t*)alloc((size_t)50000 * 512 * 2);// compacted xl; af_emb
  bf16_t* xrb  = (bf16_t*)alloc((size_t)50000 * 512 * 2);// compacted xr; rpre f32
  int* simsrc  = (int*)alloc((size_t)(E_SIM + NQ) * 4);
  int* simdst  = (int*)alloc((size_t)(E_SIM + NQ) * 4);

  // bf16-transposed weights
  bf16_t* wqp  = (bf16_t*)alloc((size_t)512 * 384 * 2);
  bf16_t* wtp  = (bf16_t*)alloc((size_t)512 * 384 * 2);
  bf16_t* wap  = (bf16_t*)alloc((size_t)512 * 384 * 2);
  bf16_t* wl   = (bf16_t*)alloc((size_t)12 * 512 * 512 * 2);
  bf16_t* wr   = (bf16_t*)alloc((size_t)12 * 512 * 512 * 2);
  bf16_t* wafp2 = (bf16_t*)alloc((size_t)512 * 64 * 2);
  bf16_t* wqh  = (bf16_t*)alloc((size_t)256 * 512 * 2);
  bf16_t* wrh0 = (bf16_t*)alloc((size_t)256 * 512 * 2);  // wrh0..2 contiguous
  bf16_t* wrh1 = (bf16_t*)alloc((size_t)256 * 512 * 2);
  bf16_t* wrh2 = (bf16_t*)alloc((size_t)256 * 512 * 2);
  float* bcAll = (float*)alloc(6 * 512 * 4);

  // Fused CSR + compaction arrays
  int* degAll   = (int*)alloc((size_t)NDTOT * 4);
  int* startAll = (int*)alloc((size_t)NDTOT * 4);
  int* cposAll  = (int*)alloc((size_t)NDTOT * 4);
  int* cidxAll  = (int*)alloc((size_t)NDTOT * 4);
  int* sdegAll  = (int*)alloc((size_t)NSTOT * 4);
  int* sposAll  = (int*)alloc((size_t)NSTOT * 4);
  int* sidxAll  = (int*)alloc((size_t)NSTOT * 4);
  int* eidxAll  = (int*)alloc((size_t)ETOT * 4);
  int* srcCAll  = (int*)alloc((size_t)ETOT * 4);
  int* posb     = (int*)alloc((size_t)ETOT * 4);
  int* bsum     = (int*)alloc(6 * 64 * 4);
  int* bsum2    = (int*)alloc(6 * 64 * 4);
  int* sbsum    = (int*)alloc(6 * 64 * 4);
  int* ccount   = (int*)alloc(6 * 4);
  int* scount   = (int*)alloc(6 * 4);
  if (off > ws_size) {
    fprintf(stderr, "kernel_launch: ws too small, need %zu have %zu\n", off, ws_size);
    return;
  }

  const int degOff[6] = {0, 50000, 60000, 110000, 120000, 170000};
  const int sOff[6]   = {0, 10000, 60000, 110000, 120000, 170000};
  const int eOff[6]   = {0, 50000, 100000, 150000, 240000, 340000};

  // --- weight conversion (4 launches) ---
  convert_wT24<<<dim3(16, 16, 24), 256, 0, stream>>>(conv_Wl, wl, conv_Wr, wr);
  convert_wT3<<<dim3(16, 12, 3), 256, 0, stream>>>(qp_W, tp_W, ap_W, wqp, wtp, wap);
  convert_wT4h<<<dim3(8, 16, 4), 256, 0, stream>>>(qh_W, rh_W, wqh, wrh0);
  convert_wT<<<dim3(16, 2, 1), 256, 0, stream>>>(afp_W2, wafp2, 64, 512);
  combine_bias6<<<(6 * 512 + 255) / 256, 256, 0, stream>>>(conv_bias, bcAll);

  // --- fused CSR build + both-side compaction ---
  build_sim<<<(E_SIM + NQ + 255) / 256, 256, 0, stream>>>(ei_sim, simsrc, simdst);
  const int* dsts[6]  = {ei_gr + E_GR, ei_gr, ei_lt, simdst,
                         ei_comp + E_COMP, ei_lt + E_LT};
  const int* srcsA[6] = {ei_gr, ei_gr + E_GR, ei_lt + E_LT, simsrc,
                         ei_comp, ei_lt};
  hipMemsetAsync(degAll, 0, (size_t)NDTOT * 4, stream);
  hipMemsetAsync(sdegAll, 0, (size_t)NSTOT * 4, stream);
  hist6<<<(ETOT + 255) / 256, 256, 0, stream>>>(
      dsts[0], dsts[1], dsts[2], dsts[3], dsts[4], dsts[5],
      srcsA[0], srcsA[1], srcsA[2], srcsA[3], srcsA[4], srcsA[5],
      degAll, sdegAll, posb);
  scan1_6<0, 0><<<216, 256, 0, stream>>>(degAll, startAll, bsum);
  scan1_6<1, 0><<<216, 256, 0, stream>>>(degAll, cposAll, bsum2);
  scan1_6<2, 1><<<216, 256, 0, stream>>>(sdegAll, sposAll, sbsum);
  scan2_6<0><<<6, 64, 0, stream>>>(bsum, nullptr);
  scan2_6<0><<<6, 64, 0, stream>>>(bsum2, ccount);
  scan2_6<1><<<6, 64, 0, stream>>>(sbsum, scount);
  scan3_6<0><<<(NDTOT + 255) / 256, 256, 0, stream>>>(startAll, bsum);
  scan3_6<0><<<(NDTOT + 255) / 256, 256, 0, stream>>>(cposAll, bsum2);
  scan3_6<1><<<(NSTOT + 255) / 256, 256, 0, stream>>>(sposAll, sbsum);
  scatter6<<<(ETOT + 255) / 256, 256, 0, stream>>>(
      dsts[0], dsts[1], dsts[2], dsts[3], dsts[4], dsts[5],
      srcsA[0], srcsA[1], srcsA[2], srcsA[3], srcsA[4], srcsA[5],
      startAll, posb, sposAll, eidxAll, srcCAll);
  compact6<0, 2><<<(NDTOT + 255) / 256, 256, 0, stream>>>(degAll, cposAll, cidxAll);
  compact6<1, 1><<<(NSTOT + 255) / 256, 256, 0, stream>>>(sdegAll, sposAll, sidxAll);

  auto gemm1 = [&](const bf16_t* A, const bf16_t* Bt, const float* bias, bf16_t* C,
                   int N_, int K_, int M_, const int* ridx = nullptr) {
    dim3 g(M_ / 256, (N_ + 127) / 128, 1);
    bgemm<bf16_t><<<g, 512, 0, stream>>>(A, Bt, bias, C, ridx, N_, nullptr,
                                         A, Bt, bias, C, ridx, N_, nullptr,
                                         K_, M_, 0);
  };
  auto gemmf1 = [&](const bf16_t* A, const bf16_t* Bt, const float* bias, float* C,
                    int N_, int K_, int M_, int acc_, const int* ridx = nullptr) {
    dim3 g(M_ / 256, (N_ + 127) / 128, 1);
    bgemm<float><<<g, 512, 0, stream>>>(A, Bt, bias, C, ridx, N_, nullptr,
                                        A, Bt, bias, C, ridx, N_, nullptr,
                                        K_, M_, acc_);
  };
  auto gemm2 = [&](const bf16_t* A0, const bf16_t* B0, const float* b0, bf16_t* C0, int N0_,
                   const bf16_t* A1, const bf16_t* B1, const float* b1, bf16_t* C1, int N1_,
                   int K_, int M_) {
    int nb0 = (N0_ + 127) / 128, nb1 = (N1_ + 127) / 128;
    dim3 g(M_ / 256, nb0 > nb1 ? nb0 : nb1, 2);
    bgemm<bf16_t><<<g, 512, 0, stream>>>(A0, B0, b0, C0, nullptr, N0_, nullptr,
                                         A1, B1, b1, C1, nullptr, N1_, nullptr,
                                         K_, M_, 0);
  };
  // z-paired conv GEMM: z0 = compacted xl, z1 = compacted xr (both dynamic)
  auto gemm2cc = [&](const bf16_t* A0, const bf16_t* B0, const float* b0, bf16_t* C0,
                     const int* sidx, int N0max, const int* Ns_,
                     const bf16_t* A1, const bf16_t* B1, const float* b1, bf16_t* C1,
                     const int* cidx, int N1max, const int* Ncnt) {
    int nb0 = (N0max + 127) / 128, nb1 = (N1max + 127) / 128;
    dim3 g(2, nb0 > nb1 ? nb0 : nb1, 2);
    bgemm<bf16_t><<<g, 512, 0, stream>>>(A0, B0, b0, C0, sidx, N0max, Ns_,
                                         A1, B1, b1, C1, cidx, N1max, Ncnt,
                                         512, 512, 0);
  };
  auto gemmf2 = [&](const bf16_t* A0, const bf16_t* B0, const float* b0, float* C0,
                    const int* r0, int N0_,
                    const bf16_t* A1, const bf16_t* B1, const float* b1, float* C1,
                    const int* r1, int N1_, int K_, int M_) {
    int nb0 = (N0_ + 127) / 128, nb1 = (N1_ + 127) / 128;
    dim3 g(M_ / 256, nb0 > nb1 ? nb0 : nb1, 2);
    bgemm<float><<<g, 512, 0, stream>>>(A0, B0, b0, C0, r0, N0_, nullptr,
                                        A1, B1, b1, C1, r1, N1_, nullptr,
                                        K_, M_, 0);
  };

  // Input projections: ONE fused cast (xq->accq scratch, xt->xlb, xa->xrb).
  cast3<<<((long)(N4_XQ + N4_XT + N4_XA) + 255) / 256, 256, 0, stream>>>(
      xq, xt, xa, accq, xlb, xrb);
  gemm1(accq, wqp, qp_b, hq, NQ, 384, 512);
  gemm2(xlb, wtp, tp_b, ht, NT, xrb, wap, ap_b, ha, NA, 384, 512);

  // Layer loop. Rel order (CSR index r): 0=gr 1=rgr 2=rlt 3=sim 4=comp 5=lt
  const int NdArr[6] = {NT, NQ, NT, NQ, NT, NA};
  const int NsArr[6] = {NQ, NT, NA, NQ, NT, NT};
  bf16_t *hq_i = hq, *ht_i = ht, *hq_o = accq, *ht_o = acct;
  for (int l = 0; l < 2; ++l) {
    const float* bc_t = bcAll + (size_t)(l * 3 + 0) * 512;
    const float* bc_q = bcAll + (size_t)(l * 3 + 1) * 512;
    const float* bc_a = bcAll + (size_t)(l * 3 + 2) * 512;

    struct Rel { const bf16_t* xs; const bf16_t* xd; int po; bf16_t* acc;
                 int accum; const float* bc; float inv; };
    Rel rels[6] = {
      {hq_i, ht_i, 0, ht_o, 0, nullptr, 0.f},      // gr
      {ht_i, hq_i, 1, hq_o, 0, nullptr, 0.f},      // rgr
      {ha,   ht_i, 3, ht_o, 1, nullptr, 0.f},      // rlt
      {hq_i, hq_i, 4, hq_o, 1, bc_q, 0.5f},        // sim (final for q)
      {ht_i, ht_i, 5, ht_o, 1, bc_t, 1.f / 3.f},   // comp (final for t)
      {ht_i, ha,   2, ha,   0, bc_a, 1.f},         // lt (final for a)
    };
    for (int r = 0; r < 6; ++r) {
      const Rel& R = rels[r];
      int Nd_ = NdArr[r];
      size_t po = (size_t)l * 6 + R.po;
      // z0: xl over compacted outdeg>=1 src rows; z1: xr over deg>=2 dst rows.
      gemm2cc(R.xs, wl + po * 512 * 512, conv_bl + po * 512, xlb,
              sidxAll + sOff[r], NsArr[r], scount + r,
              R.xd, wr + po * 512 * 512, conv_br + po * 512, xrb,
              cidxAll + degOff[r], Nd_, ccount + r);
      int gb = (Nd_ + 3) / 4;
      gat_fused<<<gb, 256, 0, stream>>>(xlb, xrb, srcCAll + eOff[r],
                                        startAll + degOff[r], degAll + degOff[r],
                                        eidxAll + eOff[r], cposAll + degOff[r],
                                        conv_att + po * 512,
                                        R.acc, Nd_, R.accum, R.bc, R.inv);
    }
    bf16_t* t;
    t = hq_i; hq_i = hq_o; hq_o = t;
    t = ht_i; ht_i = ht_o; ht_o = t;
  }

  // Head: gathers fused via ridx; qpre/rpre-first z-paired.
  float* qpre = (float*)acct;
  float* rpre = (float*)xrb;
  bf16_t* afh = accq;
  const int* gsrc = ei_gen;
  const int* gdst = ei_gen + E_GEN;

  gemmf2(hq_i, wqh, qh_b, qpre, gsrc, E_GEN,
         ht_i, wrh0, rh_b, rpre, gdst, E_GEN, 512, 256);    // q_emb | t_emb
  gemmf1(ha, wrh1, nullptr, rpre, E_GEN, 512, 256, 1, gdst); // + a_emb
  af_hidden<<<(E_GEN * 64 + 255) / 256, 256, 0, stream>>>(af, afp_W1, afp_b1,
                                                          afh, E_GEN);
  gemm1(afh, wafp2, afp_b2, xlb, E_GEN, 64, 512);            // af_emb
  gemmf1(xlb, wrh2, nullptr, rpre, E_GEN, 512, 256, 1);      // + af_emb
  head_final<<<(E_GEN + 3) / 4, 256, 0, stream>>>(
      qpre, rpre, qh_g, qh_beta, rh_g, rh_beta, score_b, (float*)d_out, E_GEN);
}

// Round 21
// 1206.970 us; speedup vs baseline: 1.4227x; 1.0365x over previous
//
#include <hip/hip_runtime.h>
#include <cstdio>
#include <type_traits>

#define NQ 10000
#define NT 50000
#define NA 50000
#define E_GR 50000
#define E_LT 50000
#define E_SIM 80000
#define E_COMP 100000
#define E_GEN 50000
#define NEG_SLOPE 0.2f

// Concatenated CSR tables (compile-time). Rel order: gr, rgr, rlt, sim, comp, lt
#define NDTOT 220000
#define NSTOT 220000
#define ETOT  390000
__device__ __constant__ const int c_degOff[7]  = {0, 50000, 60000, 110000, 120000, 170000, 220000};
__device__ __constant__ const int c_sOff[7]    = {0, 10000, 60000, 110000, 120000, 170000, 220000};
__device__ __constant__ const int c_eOff[7]    = {0, 50000, 100000, 150000, 240000, 340000, 390000};
__device__ __constant__ const int c_nb[6]      = {49, 10, 49, 10, 49, 49};
__device__ __constant__ const int c_nbOff[7]   = {0, 49, 59, 108, 118, 167, 216};
__device__ __constant__ const int c_snb[6]     = {10, 49, 49, 10, 49, 49};
__device__ __constant__ const int c_snbOff[7]  = {0, 10, 59, 108, 118, 167, 216};

typedef unsigned short bf16_t;
typedef unsigned int u32;
typedef __attribute__((ext_vector_type(8))) short short8v;
typedef __attribute__((ext_vector_type(4))) float f32x4;

__device__ __forceinline__ float bf2f(u32 bits) { return __uint_as_float(bits << 16); }
__device__ __forceinline__ u32 f2bf(float f) {
  u32 u = __float_as_uint(f);
  return (u + 0x7FFFu + ((u >> 16) & 1u)) >> 16;   // RTNE
}
__device__ __forceinline__ u32 pack2(float a, float b) { return f2bf(a) | (f2bf(b) << 16); }
__device__ __forceinline__ void unpack8(uint4 u, float* f) {
  f[0] = bf2f(u.x & 0xffffu); f[1] = bf2f(u.x >> 16);
  f[2] = bf2f(u.y & 0xffffu); f[3] = bf2f(u.y >> 16);
  f[4] = bf2f(u.z & 0xffffu); f[5] = bf2f(u.z >> 16);
  f[6] = bf2f(u.w & 0xffffu); f[7] = bf2f(u.w >> 16);
}

// async global->LDS, 16B per lane; LDS dest = wave-uniform base + lane*16.
__device__ __forceinline__ void gload16(const void* g, void* l) {
  __builtin_amdgcn_global_load_lds(
      (const __attribute__((address_space(1))) void*)g,
      (__attribute__((address_space(3))) void*)l, 16, 0, 0);
}

// ---------------------------------------------------------------------------
// MFMA bf16 GEMM, z-paired (r12 banked structure, ~570 TF/GEMM).
// 128x256 tile, BK=32, 8 waves (2x4), acc[4][4]; 3x24KB LDS (2 blocks/CU),
// rotation s%3, ONE barrier/step. Both-sides octet XOR (rule #21).
// XCD-grouped band swizzle; optional ridx row gather; optional device-side
// row count Nc (grid sized for static worst case; excess blocks exit
// uniformly before any barrier; N==0 -> all exit).
// ---------------------------------------------------------------------------
template <typename CT>
__global__ __launch_bounds__(512, 4) void bgemm(
    const bf16_t* __restrict__ A0, const bf16_t* __restrict__ Bt0,
    const float* __restrict__ bias0, CT* __restrict__ C0,
    const int* __restrict__ ridx0, int N0, const int* __restrict__ Nc0,
    const bf16_t* __restrict__ A1, const bf16_t* __restrict__ Bt1,
    const float* __restrict__ bias1, CT* __restrict__ C1,
    const int* __restrict__ ridx1, int N1, const int* __restrict__ Nc1,
    int K, int M, int accumulate)
{
  __shared__ short lds[3][12288];   // [buf][A: 0..4095 | B: 4096..12287]
  const int z = blockIdx.z;
  const bf16_t* A   = z ? A1 : A0;
  const bf16_t* Bt  = z ? Bt1 : Bt0;
  const float* bias = z ? bias1 : bias0;
  CT* C             = z ? C1 : C0;
  const int* ridx   = z ? ridx1 : ridx0;
  const int* Nc     = z ? Nc1 : Nc0;
  int N             = z ? N1 : N0;
  if (Nc) N = *Nc;                          // dynamic compacted row count

  const int tid = threadIdx.x;
  const int ncol = gridDim.x;
  const int nband = (N + 127) >> 7;
  int lin = blockIdx.y * ncol + blockIdx.x;
  if (lin >= ncol * nband) return;          // uniform exit, before barriers

  int band, col;
  const int full = (nband >> 3) * 8 * ncol;
  if (lin < full) {
    int g = lin >> 3, x = lin & 7;
    band = x + 8 * (g / ncol);
    col  = g % ncol;
  } else {
    int r = lin - full;
    band = (nband & ~7) + r / ncol;
    col  = r % ncol;
  }
  const int bm = band * 128, bn = col * 256;

  const int lane = tid & 63;
  const int w = tid >> 6;
  const int wr = w >> 2, wc = w & 3;
  const int fr = lane & 15, fg = lane >> 4;

  const int kg = (((tid & 3) ^ ((tid >> 3) & 3)) << 3);
  const int rr = tid >> 2;
  int ra = min(bm + rr, N - 1);
  const bf16_t* gA0 = A + (size_t)(ridx ? ridx[ra] : ra) * K + kg;
  const bf16_t* gB0 = Bt + (size_t)(bn + rr) * K + kg;
  const bf16_t* gB1 = Bt + (size_t)(bn + 128 + rr) * K + kg;
  const int wb = w << 9;

  f32x4 acc[4][4];
#pragma unroll
  for (int i = 0; i < 4; ++i)
#pragma unroll
    for (int j = 0; j < 4; ++j) acc[i][j] = (f32x4){0.f, 0.f, 0.f, 0.f};

  auto stage = [&](int buf, int k0) {
    short* base = &lds[buf][0];
    gload16(gA0 + k0, base + wb);
    gload16(gB0 + k0, base + 4096 + wb);
    gload16(gB1 + k0, base + 8192 + wb);
  };

  const int nsteps = K >> 5;
  stage(0, 0);
  const int co = (fg ^ ((fr >> 1) & 3)) << 3;
  for (int s = 0; s < nsteps; ++s) {
    const int cur = s % 3;
    if (s + 1 < nsteps) {
      stage((s + 1) % 3, (s + 1) << 5);
      asm volatile("s_waitcnt vmcnt(3)" ::: "memory");
    } else {
      asm volatile("s_waitcnt vmcnt(0)" ::: "memory");
    }
    __builtin_amdgcn_s_barrier();
    asm volatile("" ::: "memory");
    const short* LA = &lds[cur][0];
    const short* LB = &lds[cur][4096];
    short8v b[4];
#pragma unroll
    for (int j = 0; j < 4; ++j) {
      int R = wc * 64 + j * 16 + fr;
      b[j] = *(const short8v*)&LB[R * 32 + co];
    }
#pragma unroll
    for (int i = 0; i < 4; ++i) {
      int R = wr * 64 + i * 16 + fr;
      short8v a = *(const short8v*)&LA[R * 32 + co];
#pragma unroll
      for (int j = 0; j < 4; ++j)
        acc[i][j] = __builtin_amdgcn_mfma_f32_16x16x32_bf16(b[j], a,
                                                            acc[i][j], 0, 0, 0);
    }
    asm volatile("" ::: "memory");
  }

  float4 bv[4];
#pragma unroll
  for (int j = 0; j < 4; ++j) {
    bv[j] = make_float4(0.f, 0.f, 0.f, 0.f);
    if (!accumulate && bias)
      bv[j] = *(const float4*)(bias + bn + wc * 64 + j * 16 + fg * 4);
  }
#pragma unroll
  for (int i = 0; i < 4; ++i) {
    const int n = bm + wr * 64 + i * 16 + fr;
    if (n >= N) continue;
#pragma unroll
    for (int j = 0; j < 4; ++j) {
      const int m0 = bn + wc * 64 + j * 16 + fg * 4;
      f32x4 v = acc[i][j];
      if constexpr (std::is_same<CT, float>::value) {
        float* p = C + (size_t)n * M + m0;
        if (accumulate) {
          float4 o = *(float4*)p;
          o.x += v[0]; o.y += v[1]; o.z += v[2]; o.w += v[3];
          *(float4*)p = o;
        } else {
          *(float4*)p = make_float4(v[0] + bv[j].x, v[1] + bv[j].y,
                                    v[2] + bv[j].z, v[3] + bv[j].w);
        }
      } else {
        uint2 o;
        o.x = pack2(v[0] + bv[j].x, v[1] + bv[j].y);
        o.y = pack2(v[2] + bv[j].z, v[3] + bv[j].w);
        *(uint2*)(C + (size_t)n * M + m0) = o;
      }
    }
  }
}

// core transpose tile: fp32 W[K][M] slice -> bf16 Wt[M][K] slice
__device__ __forceinline__ void wT_tile(
    const float* __restrict__ W, bf16_t* __restrict__ Wt, int K, int M)
{
  __shared__ float sm[32][33];
  int mb = blockIdx.x * 32, kb = blockIdx.y * 32;
  int tx = threadIdx.x & 31, ty = threadIdx.x >> 5;
#pragma unroll
  for (int i = 0; i < 4; ++i)
    sm[ty + i * 8][tx] = W[(size_t)(kb + ty + i * 8) * M + mb + tx];
  __syncthreads();
#pragma unroll
  for (int i = 0; i < 4; ++i)
    Wt[(size_t)(mb + ty + i * 8) * K + kb + tx] = (bf16_t)f2bf(sm[tx][ty + i * 8]);
}

__global__ __launch_bounds__(256) void convert_wT(
    const float* __restrict__ W, bf16_t* __restrict__ Wt, int K, int M)
{
  wT_tile(W + (size_t)blockIdx.z * K * M, Wt + (size_t)blockIdx.z * K * M, K, M);
}
__global__ __launch_bounds__(256) void convert_wT24(
    const float* __restrict__ Wl, bf16_t* __restrict__ wl,
    const float* __restrict__ Wr, bf16_t* __restrict__ wr)
{
  int z = blockIdx.z;
  size_t o = (size_t)(z < 12 ? z : z - 12) * 512 * 512;
  if (z < 12) wT_tile(Wl + o, wl + o, 512, 512);
  else        wT_tile(Wr + o, wr + o, 512, 512);
}
__global__ __launch_bounds__(256) void convert_wT3(
    const float* __restrict__ W0, const float* __restrict__ W1,
    const float* __restrict__ W2, bf16_t* __restrict__ T0,
    bf16_t* __restrict__ T1, bf16_t* __restrict__ T2)
{
  int z = blockIdx.z;
  const float* W = z == 0 ? W0 : z == 1 ? W1 : W2;
  bf16_t* T = z == 0 ? T0 : z == 1 ? T1 : T2;
  wT_tile(W, T, 384, 512);
}
__global__ __launch_bounds__(256) void convert_wT4h(
    const float* __restrict__ qh, const float* __restrict__ rh,
    bf16_t* __restrict__ wqh, bf16_t* __restrict__ wrh)
{
  int z = blockIdx.z;
  if (z == 0) wT_tile(qh, wqh, 512, 256);
  else        wT_tile(rh + (size_t)(z - 1) * 512 * 256,
                      wrh + (size_t)(z - 1) * 256 * 512, 512, 256);
}

// flat fp32 -> bf16 cast (n4 float4s)
__global__ __launch_bounds__(256) void cast_flat(
    const float* __restrict__ in, bf16_t* __restrict__ out, int n4)
{
  int t = blockIdx.x * 256 + threadIdx.x;
  if (t >= n4) return;
  float4 v = ((const float4*)in)[t];
  uint2 o;
  o.x = pack2(v.x, v.y);
  o.y = pack2(v.z, v.w);
  ((uint2*)out)[t] = o;
}

// cvec[m] = sum_k afp_b2[k] * rh2[k][m]   (rh2 = rh_W + 1024*256, [512][256])
__global__ __launch_bounds__(256) void fold_cvec(
    const float* __restrict__ b2, const float* __restrict__ rh2,
    float* __restrict__ cvec)
{
  int m = threadIdx.x;
  float s = 0.f;
  for (int k = 0; k < 512; ++k) s = fmaf(b2[k], rh2[(size_t)k * 256 + m], s);
  cvec[m] = s;
}

// fused input casts: xq->xqb, xt->xlb, xa->xrb (float4 granularity)
#define N4_XQ (NQ * 96)
#define N4_XT (NT * 96)
#define N4_XA (NA * 96)
__global__ __launch_bounds__(256) void cast3(
    const float* __restrict__ xq, const float* __restrict__ xt,
    const float* __restrict__ xa, bf16_t* __restrict__ xqb,
    bf16_t* __restrict__ xtb, bf16_t* __restrict__ xab)
{
  long g = (long)blockIdx.x * 256 + threadIdx.x;
  const float* in; bf16_t* out; long idx;
  if (g < N4_XQ)                { in = xq; out = xqb; idx = g; }
  else if (g < N4_XQ + N4_XT)   { in = xt; out = xtb; idx = g - N4_XQ; }
  else if (g < N4_XQ + N4_XT + N4_XA) { in = xa; out = xab; idx = g - N4_XQ - N4_XT; }
  else return;
  float4 v = ((const float4*)in)[idx];
  uint2 o;
  o.x = pack2(v.x, v.y);
  o.y = pack2(v.z, v.w);
  ((uint2*)out)[idx] = o;
}

__global__ __launch_bounds__(256) void combine_bias6(
    const float* __restrict__ cb, float* __restrict__ bcAll)
{
  int g = blockIdx.x * 256 + threadIdx.x;
  if (g >= 6 * 512) return;
  int row = g >> 9, j = g & 511;
  int l = row / 3, kind = row % 3;
  const float* b = cb + (size_t)l * 6 * 512;
  float v;
  if (kind == 0)      v = (b[0 * 512 + j] + b[3 * 512 + j] + b[5 * 512 + j]) / 3.f;
  else if (kind == 1) v = (b[1 * 512 + j] + b[4 * 512 + j]) * 0.5f;
  else                v = b[2 * 512 + j];
  bcAll[(size_t)row * 512 + j] = v;
}

// ---------------------------------------------------------------------------
// Fused CSR build + dst deg>=2 compaction + src outdeg>=1 compaction.
// ---------------------------------------------------------------------------
__device__ __forceinline__ int find_rel6(int g, const int* off) {
  int r = 0;
#pragma unroll
  for (int k = 1; k < 6; ++k) r += (g >= off[k]);
  return r;
}

__global__ __launch_bounds__(256) void hist6(
    const int* __restrict__ d0, const int* __restrict__ d1,
    const int* __restrict__ d2, const int* __restrict__ d3,
    const int* __restrict__ d4, const int* __restrict__ d5,
    const int* __restrict__ s0p, const int* __restrict__ s1p,
    const int* __restrict__ s2p, const int* __restrict__ s3p,
    const int* __restrict__ s4p, const int* __restrict__ s5p,
    int* __restrict__ degAll, int* __restrict__ sdegAll, int* __restrict__ pos)
{
  int g = blockIdx.x * 256 + threadIdx.x;
  if (g >= ETOT) return;
  int r = find_rel6(g, c_eOff);
  int le = g - c_eOff[r];
  const int* dp = r == 0 ? d0 : r == 1 ? d1 : r == 2 ? d2 : r == 3 ? d3
                : r == 4 ? d4 : d5;
  const int* sp = r == 0 ? s0p : r == 1 ? s1p : r == 2 ? s2p : r == 3 ? s3p
                : r == 4 ? s4p : s5p;
  pos[g] = atomicAdd(&degAll[c_degOff[r] + dp[le]], 1);
  atomicAdd(&sdegAll[c_sOff[r] + sp[le]], 1);
}

// PRED==0: raw scan (CSR starts). PRED==1: deg>=2. PRED==2: deg>=1.
template <int PRED, int SRC>
__global__ __launch_bounds__(256) void scan1_6(
    const int* __restrict__ in, int* __restrict__ out, int* __restrict__ bsum)
{
  __shared__ int sm[256];
  int b = blockIdx.x;
  const int* nbOff = SRC ? c_snbOff : c_nbOff;
  const int* dOff  = SRC ? c_sOff : c_degOff;
  int r = 0;
#pragma unroll
  for (int k = 1; k < 6; ++k) r += (b >= nbOff[k]);
  int lb = b - nbOff[r];
  int base0 = dOff[r], n = dOff[r + 1] - base0;
  int t = threadIdx.x;
  int base = lb * 1024 + t * 4;
  int v[4], sum = 0;
#pragma unroll
  for (int k = 0; k < 4; ++k) {
    int raw = (base + k < n) ? in[base0 + base + k] : 0;
    v[k] = PRED == 0 ? raw : PRED == 1 ? (raw >= 2 ? 1 : 0) : (raw >= 1 ? 1 : 0);
    sum += v[k];
  }
  sm[t] = sum;
  __syncthreads();
  for (int off = 1; off < 256; off <<= 1) {
    int x = (t >= off) ? sm[t - off] : 0;
    __syncthreads();
    sm[t] += x;
    __syncthreads();
  }
  int run = (t > 0) ? sm[t - 1] : 0;
  if (t == 255) bsum[r * 64 + lb] = sm[255];
#pragma unroll
  for (int k = 0; k < 4; ++k) {
    if (base + k < n) out[base0 + base + k] = run;
    run += v[k];
  }
}

template <int SRC>
__global__ __launch_bounds__(64) void scan2_6(
    int* __restrict__ bsum, int* __restrict__ total)
{
  __shared__ int sm[64];
  int r = blockIdx.x;
  int nb = SRC ? c_snb[r] : c_nb[r];
  int t = threadIdx.x;
  int v = (t < nb) ? bsum[r * 64 + t] : 0;
  sm[t] = v;
  __syncthreads();
  for (int off = 1; off < 64; off <<= 1) {
    int x = (t >= off) ? sm[t - off] : 0;
    __syncthreads();
    sm[t] += x;
    __syncthreads();
  }
  if (t < nb) bsum[r * 64 + t] = sm[t] - v;   // exclusive
  if (total && t == nb - 1) total[r] = sm[t]; // inclusive total
}

template <int SRC>
__global__ __launch_bounds__(256) void scan3_6(
    int* __restrict__ out, const int* __restrict__ bsum)
{
  int g = blockIdx.x * 256 + threadIdx.x;
  if (g >= (SRC ? NSTOT : NDTOT)) return;
  const int* dOff = SRC ? c_sOff : c_degOff;
  int r = find_rel6(g, dOff);
  int ln = g - dOff[r];
  out[g] += bsum[r * 64 + (ln >> 10)];
}

__global__ __launch_bounds__(256) void scatter6(
    const int* __restrict__ d0, const int* __restrict__ d1,
    const int* __restrict__ d2, const int* __restrict__ d3,
    const int* __restrict__ d4, const int* __restrict__ d5,
    const int* __restrict__ s0p, const int* __restrict__ s1p,
    const int* __restrict__ s2p, const int* __restrict__ s3p,
    const int* __restrict__ s4p, const int* __restrict__ s5p,
    const int* __restrict__ startAll, const int* __restrict__ pos,
    const int* __restrict__ sposAll,
    int* __restrict__ eidxAll, int* __restrict__ srcCAll)
{
  int g = blockIdx.x * 256 + threadIdx.x;
  if (g >= ETOT) return;
  int r = find_rel6(g, c_eOff);
  int le = g - c_eOff[r];
  const int* dp = r == 0 ? d0 : r == 1 ? d1 : r == 2 ? d2 : r == 3 ? d3
                : r == 4 ? d4 : d5;
  const int* sp = r == 0 ? s0p : r == 1 ? s1p : r == 2 ? s2p : r == 3 ? s3p
                : r == 4 ? s4p : s5p;
  eidxAll[c_eOff[r] + startAll[c_degOff[r] + dp[le]] + pos[g]] = le;
  srcCAll[g] = sposAll[c_sOff[r] + sp[le]];
}

template <int SRC, int THR>
__global__ __launch_bounds__(256) void compact6(
    const int* __restrict__ degA, const int* __restrict__ cposA,
    int* __restrict__ cidxA)
{
  int g = blockIdx.x * 256 + threadIdx.x;
  if (g >= (SRC ? NSTOT : NDTOT)) return;
  if (degA[g] >= THR) {
    const int* dOff = SRC ? c_sOff : c_degOff;
    int r = find_rel6(g, dOff);
    cidxA[dOff[r] + cposA[g]] = g - dOff[r];
  }
}

// ---------------------------------------------------------------------------
// Fused GATv2: one wave per dst node. deg==0 -> 0; deg==1 -> xl[srcC];
// deg>=2 reads compacted xr at cpos[d]. srcC pre-remapped. Edge pipelined.
// ---------------------------------------------------------------------------
__global__ __launch_bounds__(256) void gat_fused(
    const bf16_t* __restrict__ xl, const bf16_t* __restrict__ xr,
    const int* __restrict__ srcC, const int* __restrict__ start,
    const int* __restrict__ deg, const int* __restrict__ eidx,
    const int* __restrict__ cpos, const float* __restrict__ att,
    bf16_t* __restrict__ acc, int Nd, int accumulate,
    const float* __restrict__ bc, float inv_div)
{
  int d = blockIdx.x * 4 + (threadIdx.x >> 6);
  if (d >= Nd) return;
  int lane = threadIdx.x & 63;

  float acc8[8] = {0.f, 0.f, 0.f, 0.f, 0.f, 0.f, 0.f, 0.f};
  int n = deg[d], s0 = start[d];
  if (n == 1) {
    int s = srcC[eidx[s0]];
    unpack8(*(const uint4*)(xl + (size_t)s * 512 + lane * 8), acc8);
  } else if (n > 1) {
    float xrr[8];
    unpack8(*(const uint4*)(xr + (size_t)cpos[d] * 512 + lane * 8), xrr);
    float at[8];
    *(float4*)(at)     = *(const float4*)(att + lane * 8);
    *(float4*)(at + 4) = *(const float4*)(att + lane * 8 + 4);
    float den = 0.f;
    int sN = srcC[eidx[s0]];
    for (int i = 0; i < n; ++i) {
      int s = sN;
      if (i + 1 < n) sN = srcC[eidx[s0 + i + 1]];
      float f[8];
      unpack8(*(const uint4*)(xl + (size_t)s * 512 + lane * 8), f);
      float p = 0.f;
#pragma unroll
      for (int k = 0; k < 8; ++k) {
        float x = f[k] + xrr[k];
        p = fmaf(at[k], x >= 0.f ? x : NEG_SLOPE * x, p);
      }
#pragma unroll
      for (int m = 8; m >= 1; m >>= 1) p += __shfl_xor(p, m);
      float ex = __expf(p);
      den += ex;
#pragma unroll
      for (int k = 0; k < 8; ++k) acc8[k] = fmaf(ex, f[k], acc8[k]);
    }
    float inv = 1.f / (den + 1e-16f);
#pragma unroll
    for (int k = 0; k < 8; ++k) acc8[k] *= inv;
  }

  bf16_t* out = acc + (size_t)d * 512 + lane * 8;
  if (accumulate) {
    float old[8];
    unpack8(*(const uint4*)out, old);
#pragma unroll
    for (int k = 0; k < 8; ++k) acc8[k] += old[k];
  }
  if (bc) {
    float bcv[8];
    *(float4*)(bcv)     = *(const float4*)(bc + lane * 8);
    *(float4*)(bcv + 4) = *(const float4*)(bc + lane * 8 + 4);
#pragma unroll
    for (int k = 0; k < 8; ++k)
      acc8[k] = fmaxf(fmaf(acc8[k], inv_div, bcv[k]), 0.f);
  }
  uint4 s;
  s.x = pack2(acc8[0], acc8[1]); s.y = pack2(acc8[2], acc8[3]);
  s.z = pack2(acc8[4], acc8[5]); s.w = pack2(acc8[6], acc8[7]);
  *(uint4*)out = s;
}

// afh = relu(answer_features @ W1 + b1) -> bf16, K=6, M=64
__global__ __launch_bounds__(256) void af_hidden(
    const float* __restrict__ af, const float* __restrict__ W1,
    const float* __restrict__ b1, bf16_t* __restrict__ out, int n)
{
  int t = blockIdx.x * blockDim.x + threadIdx.x;
  if (t >= n * 64) return;
  int i = t >> 6, j = t & 63;
  const float* a = af + (size_t)i * 6;
  float s = b1[j];
#pragma unroll
  for (int k = 0; k < 6; ++k) s = fmaf(a[k], W1[k * 64 + j], s);
  out[t] = (bf16_t)f2bf(fmaxf(s, 0.f));
}

__global__ __launch_bounds__(256) void build_sim(
    const int* __restrict__ ei, int* __restrict__ ss, int* __restrict__ sd)
{
  int t = blockIdx.x * blockDim.x + threadIdx.x;
  if (t >= E_SIM + NQ) return;
  if (t < E_SIM) { ss[t] = ei[t]; sd[t] = ei[E_SIM + t]; }
  else           { ss[t] = t - E_SIM; sd[t] = t - E_SIM; }
}

// Head: per edge e (wave-uniform): q = LN(qn[gsrc[e]]); r = LN(rn[gdst[e]]
// + afr[e] + cvec); out = dot(q,r)/16 + sb.
__global__ __launch_bounds__(256) void head_final(
    const float* __restrict__ qn, const float* __restrict__ rn,
    const float* __restrict__ afr, const float* __restrict__ cvec,
    const int* __restrict__ gsrc, const int* __restrict__ gdst,
    const float* __restrict__ qg, const float* __restrict__ qb,
    const float* __restrict__ rg, const float* __restrict__ rb,
    const float* __restrict__ score_bias, float* __restrict__ out, int E)
{
  int e = blockIdx.x * 4 + (threadIdx.x >> 6);
  if (e >= E) return;
  int lane = threadIdx.x & 63;

  float4 q = *(const float4*)(qn + (size_t)gsrc[e] * 256 + lane * 4);
  float s = q.x + q.y + q.z + q.w;
#pragma unroll
  for (int m = 32; m >= 1; m >>= 1) s += __shfl_xor(s, m);
  float mu = s * (1.f / 256.f);
  float dq0 = q.x - mu, dq1 = q.y - mu, dq2 = q.z - mu, dq3 = q.w - mu;
  float v = dq0 * dq0 + dq1 * dq1 + dq2 * dq2 + dq3 * dq3;
#pragma unroll
  for (int m = 32; m >= 1; m >>= 1) v += __shfl_xor(v, m);
  float rstd = rsqrtf(v * (1.f / 256.f) + 1e-5f);
  float4 g4 = *(const float4*)(qg + lane * 4);
  float4 b4 = *(const float4*)(qb + lane * 4);
  float qn0 = dq0 * rstd * g4.x + b4.x, qn1 = dq1 * rstd * g4.y + b4.y;
  float qn2 = dq2 * rstd * g4.z + b4.z, qn3 = dq3 * rstd * g4.w + b4.w;

  float4 r0 = *(const float4*)(rn + (size_t)gdst[e] * 256 + lane * 4);
  float4 r1 = *(const float4*)(afr + (size_t)e * 256 + lane * 4);
  float4 cv = *(const float4*)(cvec + lane * 4);
  float4 r;
  r.x = r0.x + r1.x + cv.x;
  r.y = r0.y + r1.y + cv.y;
  r.z = r0.z + r1.z + cv.z;
  r.w = r0.w + r1.w + cv.w;
  s = r.x + r.y + r.z + r.w;
#pragma unroll
  for (int m = 32; m >= 1; m >>= 1) s += __shfl_xor(s, m);
  mu = s * (1.f / 256.f);
  float dr0 = r.x - mu, dr1 = r.y - mu, dr2 = r.z - mu, dr3 = r.w - mu;
  v = dr0 * dr0 + dr1 * dr1 + dr2 * dr2 + dr3 * dr3;
#pragma unroll
  for (int m = 32; m >= 1; m >>= 1) v += __shfl_xor(v, m);
  rstd = rsqrtf(v * (1.f / 256.f) + 1e-5f);
  g4 = *(const float4*)(rg + lane * 4);
  b4 = *(const float4*)(rb + lane * 4);
  float rn0 = dr0 * rstd * g4.x + b4.x, rn1 = dr1 * rstd * g4.y + b4.y;
  float rn2 = dr2 * rstd * g4.z + b4.z, rn3 = dr3 * rstd * g4.w + b4.w;

  float d = qn0 * rn0 + qn1 * rn1 + qn2 * rn2 + qn3 * rn3;
#pragma unroll
  for (int m = 32; m >= 1; m >>= 1) d += __shfl_xor(d, m);
  if (lane == 0) out[e] = d * 0.0625f + score_bias[0];
}

// ---------------------------------------------------------------------------
extern "C" void kernel_launch(void* const* d_in, const int* in_sizes, int n_in,
                              void* d_out, int out_size, void* d_ws, size_t ws_size,
                              hipStream_t stream) {
  (void)in_sizes; (void)n_in; (void)out_size;
  const float* xq      = (const float*)d_in[0];
  const float* xt      = (const float*)d_in[1];
  const float* xa      = (const float*)d_in[2];
  const float* af      = (const float*)d_in[3];
  const float* qp_W    = (const float*)d_in[4];
  const float* qp_b    = (const float*)d_in[5];
  const float* tp_W    = (const float*)d_in[6];
  const float* tp_b    = (const float*)d_in[7];
  const float* ap_W    = (const float*)d_in[8];
  const float* ap_b    = (const float*)d_in[9];
  const float* afp_W1  = (const float*)d_in[10];
  const float* afp_b1  = (const float*)d_in[11];
  const float* afp_W2  = (const float*)d_in[12];
  const float* afp_b2  = (const float*)d_in[13];
  const float* conv_Wl = (const float*)d_in[14];
  const float* conv_bl = (const float*)d_in[15];
  const float* conv_Wr = (const float*)d_in[16];
  const float* conv_br = (const float*)d_in[17];
  const float* conv_att  = (const float*)d_in[18];
  const float* conv_bias = (const float*)d_in[19];
  const float* qh_W    = (const float*)d_in[20];
  const float* qh_b    = (const float*)d_in[21];
  const float* qh_g    = (const float*)d_in[22];
  const float* qh_beta = (const float*)d_in[23];
  const float* rh_W    = (const float*)d_in[24];
  const float* rh_b    = (const float*)d_in[25];
  const float* rh_g    = (const float*)d_in[26];
  const float* rh_beta = (const float*)d_in[27];
  const float* score_b = (const float*)d_in[28];
  const int* ei_gr   = (const int*)d_in[29];
  const int* ei_lt   = (const int*)d_in[30];
  const int* ei_sim  = (const int*)d_in[31];
  const int* ei_comp = (const int*)d_in[32];
  const int* ei_gen  = (const int*)d_in[33];

  char* base = (char*)d_ws;
  size_t off = 0;
  auto alloc = [&](size_t bytes) {
    void* p = base + off;
    off = (off + bytes + 255) & ~(size_t)255;
    return p;
  };
  bf16_t* hq   = (bf16_t*)alloc((size_t)NQ * 512 * 2);
  bf16_t* ht   = (bf16_t*)alloc((size_t)NT * 512 * 2);
  bf16_t* ha   = (bf16_t*)alloc((size_t)NA * 512 * 2);
  bf16_t* acct = (bf16_t*)alloc((size_t)NT * 512 * 2);   // ht ping-pong; rn f32
  bf16_t* accq = (bf16_t*)alloc((size_t)NQ * 512 * 2);   // xq-cast; hq ping-pong; qn f32
  bf16_t* xlb  = (bf16_t*)alloc((size_t)50000 * 512 * 2);// compacted xl; afh
  bf16_t* xrb  = (bf16_t*)alloc((size_t)50000 * 512 * 2);// compacted xr; afr f32
  int* simsrc  = (int*)alloc((size_t)(E_SIM + NQ) * 4);
  int* simdst  = (int*)alloc((size_t)(E_SIM + NQ) * 4);

  // bf16-transposed weights
  bf16_t* wqp  = (bf16_t*)alloc((size_t)512 * 384 * 2);
  bf16_t* wtp  = (bf16_t*)alloc((size_t)512 * 384 * 2);
  bf16_t* wap  = (bf16_t*)alloc((size_t)512 * 384 * 2);
  bf16_t* wl   = (bf16_t*)alloc((size_t)12 * 512 * 512 * 2);
  bf16_t* wr   = (bf16_t*)alloc((size_t)12 * 512 * 512 * 2);
  bf16_t* wqh  = (bf16_t*)alloc((size_t)256 * 512 * 2);
  bf16_t* wrh0 = (bf16_t*)alloc((size_t)256 * 512 * 2);  // wrh0..2 contiguous
  bf16_t* wrh1 = (bf16_t*)alloc((size_t)256 * 512 * 2);
  bf16_t* wrh2 = (bf16_t*)alloc((size_t)256 * 512 * 2);
  float* bcAll = (float*)alloc(6 * 512 * 4);
  // af-fold buffers
  bf16_t* a2b    = (bf16_t*)alloc((size_t)64 * 512 * 2);  // afp_W2 bf16 [64][512]
  float*  wfoldF = (float*)alloc((size_t)64 * 256 * 4);   // afp_W2@rh2 [64][256]
  bf16_t* wfoldT = (bf16_t*)alloc((size_t)256 * 64 * 2);  // transposed bf16
  float*  cvec   = (float*)alloc(256 * 4);                // afp_b2@rh2

  // Fused CSR + compaction arrays
  int* degAll   = (int*)alloc((size_t)NDTOT * 4);
  int* startAll = (int*)alloc((size_t)NDTOT * 4);
  int* cposAll  = (int*)alloc((size_t)NDTOT * 4);
  int* cidxAll  = (int*)alloc((size_t)NDTOT * 4);
  int* sdegAll  = (int*)alloc((size_t)NSTOT * 4);
  int* sposAll  = (int*)alloc((size_t)NSTOT * 4);
  int* sidxAll  = (int*)alloc((size_t)NSTOT * 4);
  int* eidxAll  = (int*)alloc((size_t)ETOT * 4);
  int* srcCAll  = (int*)alloc((size_t)ETOT * 4);
  int* posb     = (int*)alloc((size_t)ETOT * 4);
  int* bsum     = (int*)alloc(6 * 64 * 4);
  int* bsum2    = (int*)alloc(6 * 64 * 4);
  int* sbsum    = (int*)alloc(6 * 64 * 4);
  int* ccount   = (int*)alloc(6 * 4);
  int* scount   = (int*)alloc(6 * 4);
  if (off > ws_size) {
    fprintf(stderr, "kernel_launch: ws too small, need %zu have %zu\n", off, ws_size);
    return;
  }

  const int degOff[6] = {0, 50000, 60000, 110000, 120000, 170000};
  const int sOff[6]   = {0, 10000, 60000, 110000, 120000, 170000};
  const int eOff[6]   = {0, 50000, 100000, 150000, 240000, 340000};

  auto gemm1 = [&](const bf16_t* A, const bf16_t* Bt, const float* bias, bf16_t* C,
                   int N_, int K_, int M_, const int* ridx = nullptr) {
    dim3 g(M_ / 256, (N_ + 127) / 128, 1);
    bgemm<bf16_t><<<g, 512, 0, stream>>>(A, Bt, bias, C, ridx, N_, nullptr,
                                         A, Bt, bias, C, ridx, N_, nullptr,
                                         K_, M_, 0);
  };
  auto gemmf1 = [&](const bf16_t* A, const bf16_t* Bt, const float* bias, float* C,
                    int N_, int K_, int M_, int acc_, const int* ridx = nullptr) {
    dim3 g(M_ / 256, (N_ + 127) / 128, 1);
    bgemm<float><<<g, 512, 0, stream>>>(A, Bt, bias, C, ridx, N_, nullptr,
                                        A, Bt, bias, C, ridx, N_, nullptr,
                                        K_, M_, acc_);
  };
  auto gemm2 = [&](const bf16_t* A0, const bf16_t* B0, const float* b0, bf16_t* C0, int N0_,
                   const bf16_t* A1, const bf16_t* B1, const float* b1, bf16_t* C1, int N1_,
                   int K_, int M_) {
    int nb0 = (N0_ + 127) / 128, nb1 = (N1_ + 127) / 128;
    dim3 g(M_ / 256, nb0 > nb1 ? nb0 : nb1, 2);
    bgemm<bf16_t><<<g, 512, 0, stream>>>(A0, B0, b0, C0, nullptr, N0_, nullptr,
                                         A1, B1, b1, C1, nullptr, N1_, nullptr,
                                         K_, M_, 0);
  };
  auto gemm2cc = [&](const bf16_t* A0, const bf16_t* B0, const float* b0, bf16_t* C0,
                     const int* sidx, int N0max, const int* Ns_,
                     const bf16_t* A1, const bf16_t* B1, const float* b1, bf16_t* C1,
                     const int* cidx, int N1max, const int* Ncnt) {
    int nb0 = (N0max + 127) / 128, nb1 = (N1max + 127) / 128;
    dim3 g(2, nb0 > nb1 ? nb0 : nb1, 2);
    bgemm<bf16_t><<<g, 512, 0, stream>>>(A0, B0, b0, C0, sidx, N0max, Ns_,
                                         A1, B1, b1, C1, cidx, N1max, Ncnt,
                                         512, 512, 0);
  };
  auto gemmf2 = [&](const bf16_t* A0, const bf16_t* B0, const float* b0, float* C0, int N0_,
                    const bf16_t* A1, const bf16_t* B1, const float* b1, float* C1, int N1_,
                    int K_, int M_) {
    int nb0 = (N0_ + 127) / 128, nb1 = (N1_ + 127) / 128;
    dim3 g(M_ / 256, nb0 > nb1 ? nb0 : nb1, 2);
    bgemm<float><<<g, 512, 0, stream>>>(A0, B0, b0, C0, nullptr, N0_, nullptr,
                                        A1, B1, b1, C1, nullptr, N1_, nullptr,
                                        K_, M_, 0);
  };

  // --- weight conversion + af-fold (weights-only, prologue) ---
  convert_wT24<<<dim3(16, 16, 24), 256, 0, stream>>>(conv_Wl, wl, conv_Wr, wr);
  convert_wT3<<<dim3(16, 12, 3), 256, 0, stream>>>(qp_W, tp_W, ap_W, wqp, wtp, wap);
  convert_wT4h<<<dim3(8, 16, 4), 256, 0, stream>>>(qh_W, rh_W, wqh, wrh0);
  combine_bias6<<<(6 * 512 + 255) / 256, 256, 0, stream>>>(conv_bias, bcAll);
  cast_flat<<<(64 * 512 / 4 + 255) / 256, 256, 0, stream>>>(afp_W2, a2b, 64 * 512 / 4);
  gemmf1(a2b, wrh2, nullptr, wfoldF, 64, 512, 256, 0);      // Wfold = W2 @ rh2
  convert_wT<<<dim3(8, 2, 1), 256, 0, stream>>>(wfoldF, wfoldT, 64, 256);
  fold_cvec<<<1, 256, 0, stream>>>(afp_b2, rh_W + 1024 * 256, cvec);

  // --- fused CSR build + both-side compaction ---
  build_sim<<<(E_SIM + NQ + 255) / 256, 256, 0, stream>>>(ei_sim, simsrc, simdst);
  const int* dsts[6]  = {ei_gr + E_GR, ei_gr, ei_lt, simdst,
                         ei_comp + E_COMP, ei_lt + E_LT};
  const int* srcsA[6] = {ei_gr, ei_gr + E_GR, ei_lt + E_LT, simsrc,
                         ei_comp, ei_lt};
  hipMemsetAsync(degAll, 0, (size_t)NDTOT * 4, stream);
  hipMemsetAsync(sdegAll, 0, (size_t)NSTOT * 4, stream);
  hist6<<<(ETOT + 255) / 256, 256, 0, stream>>>(
      dsts[0], dsts[1], dsts[2], dsts[3], dsts[4], dsts[5],
      srcsA[0], srcsA[1], srcsA[2], srcsA[3], srcsA[4], srcsA[5],
      degAll, sdegAll, posb);
  scan1_6<0, 0><<<216, 256, 0, stream>>>(degAll, startAll, bsum);
  scan1_6<1, 0><<<216, 256, 0, stream>>>(degAll, cposAll, bsum2);
  scan1_6<2, 1><<<216, 256, 0, stream>>>(sdegAll, sposAll, sbsum);
  scan2_6<0><<<6, 64, 0, stream>>>(bsum, nullptr);
  scan2_6<0><<<6, 64, 0, stream>>>(bsum2, ccount);
  scan2_6<1><<<6, 64, 0, stream>>>(sbsum, scount);
  scan3_6<0><<<(NDTOT + 255) / 256, 256, 0, stream>>>(startAll, bsum);
  scan3_6<0><<<(NDTOT + 255) / 256, 256, 0, stream>>>(cposAll, bsum2);
  scan3_6<1><<<(NSTOT + 255) / 256, 256, 0, stream>>>(sposAll, sbsum);
  scatter6<<<(ETOT + 255) / 256, 256, 0, stream>>>(
      dsts[0], dsts[1], dsts[2], dsts[3], dsts[4], dsts[5],
      srcsA[0], srcsA[1], srcsA[2], srcsA[3], srcsA[4], srcsA[5],
      startAll, posb, sposAll, eidxAll, srcCAll);
  compact6<0, 2><<<(NDTOT + 255) / 256, 256, 0, stream>>>(degAll, cposAll, cidxAll);
  compact6<1, 1><<<(NSTOT + 255) / 256, 256, 0, stream>>>(sdegAll, sposAll, sidxAll);

  // Input projections: ONE fused cast (xq->accq scratch, xt->xlb, xa->xrb).
  cast3<<<((long)(N4_XQ + N4_XT + N4_XA) + 255) / 256, 256, 0, stream>>>(
      xq, xt, xa, accq, xlb, xrb);
  gemm1(accq, wqp, qp_b, hq, NQ, 384, 512);
  gemm2(xlb, wtp, tp_b, ht, NT, xrb, wap, ap_b, ha, NA, 384, 512);

  // Layer loop. Rel order (CSR index r): 0=gr 1=rgr 2=rlt 3=sim 4=comp 5=lt
  const int NdArr[6] = {NT, NQ, NT, NQ, NT, NA};
  const int NsArr[6] = {NQ, NT, NA, NQ, NT, NT};
  bf16_t *hq_i = hq, *ht_i = ht, *hq_o = accq, *ht_o = acct;
  for (int l = 0; l < 2; ++l) {
    const float* bc_t = bcAll + (size_t)(l * 3 + 0) * 512;
    const float* bc_q = bcAll + (size_t)(l * 3 + 1) * 512;
    const float* bc_a = bcAll + (size_t)(l * 3 + 2) * 512;

    struct Rel { const bf16_t* xs; const bf16_t* xd; int po; bf16_t* acc;
                 int accum; const float* bc; float inv; };
    Rel rels[6] = {
      {hq_i, ht_i, 0, ht_o, 0, nullptr, 0.f},      // gr
      {ht_i, hq_i, 1, hq_o, 0, nullptr, 0.f},      // rgr
      {ha,   ht_i, 3, ht_o, 1, nullptr, 0.f},      // rlt
      {hq_i, hq_i, 4, hq_o, 1, bc_q, 0.5f},        // sim (final for q)
      {ht_i, ht_i, 5, ht_o, 1, bc_t, 1.f / 3.f},   // comp (final for t)
      {ht_i, ha,   2, ha,   0, bc_a, 1.f},         // lt (final for a)
    };
    for (int r = 0; r < 6; ++r) {
      const Rel& R = rels[r];
      int Nd_ = NdArr[r];
      size_t po = (size_t)l * 6 + R.po;
      gemm2cc(R.xs, wl + po * 512 * 512, conv_bl + po * 512, xlb,
              sidxAll + sOff[r], NsArr[r], scount + r,
              R.xd, wr + po * 512 * 512, conv_br + po * 512, xrb,
              cidxAll + degOff[r], Nd_, ccount + r);
      int gb = (Nd_ + 3) / 4;
      gat_fused<<<gb, 256, 0, stream>>>(xlb, xrb, srcCAll + eOff[r],
                                        startAll + degOff[r], degAll + degOff[r],
                                        eidxAll + eOff[r], cposAll + degOff[r],
                                        conv_att + po * 512,
                                        R.acc, Nd_, R.accum, R.bc, R.inv);
    }
    bf16_t* t;
    t = hq_i; hq_i = hq_o; hq_o = t;
    t = ht_i; ht_i = ht_o; ht_o = t;
  }
  // after 2 swaps: hq_i==hq, ht_i==ht; acct/accq free.

  // Head (node-space + folded af path):
  // qn = hq@qh_W + qh_b  (NQ rows);  rn = ht@rh0 + rh_b + ha@rh1  (NA rows);
  // afr = afh @ Wfold  (E rows, K=64);  r = rn[gdst] + afr + cvec.
  float* qn  = (float*)accq;   // 10.24 MB
  float* rn  = (float*)acct;   // 51.2 MB
  float* afr = (float*)xrb;    // 51.2 MB
  bf16_t* afh = xlb;           // 6.4 MB
  const int* gsrc = ei_gen;
  const int* gdst = ei_gen + E_GEN;

  gemmf2(hq_i, wqh, qh_b, qn, NQ, ht_i, wrh0, rh_b, rn, NT, 512, 256);
  gemmf1(ha, wrh1, nullptr, rn, NA, 512, 256, 1);
  af_hidden<<<(E_GEN * 64 + 255) / 256, 256, 0, stream>>>(af, afp_W1, afp_b1,
                                                          afh, E_GEN);
  gemmf1(afh, wfoldT, nullptr, afr, E_GEN, 64, 256, 0);
  head_final<<<(E_GEN + 3) / 4, 256, 0, stream>>>(
      qn, rn, afr, cvec, gsrc, gdst,
      qh_g, qh_beta, rh_g, rh_beta, score_b, (float*)d_out, E_GEN);
}